// Round 12
// baseline (1013.695 us; speedup 1.0000x reference)
//
#include <hip/hip_runtime.h>
#include <hip/hip_bf16.h>
#include <math.h>

typedef __attribute__((ext_vector_type(8))) short short8;
typedef __attribute__((ext_vector_type(4))) float f32x4;

#define KTILE 32
#define LSTR 40    // BM=128 path: LDS row stride (bf16 elems): 80 B
#define LSTR64 72  // KT=64 path: 144 B row stride (16B-aligned rows)

__device__ __forceinline__ short8 cvt8(const float* x) {
    short8 r;
#pragma unroll
    for (int i = 0; i < 8; ++i) {
        __hip_bfloat16 b = __float2bfloat16(x[i]);
        r[i] = *reinterpret_cast<const short*>(&b);
    }
    return r;
}
__device__ __forceinline__ float bf2f(short s) {
    unsigned int u = ((unsigned int)(unsigned short)s) << 16;
    return __uint_as_float(u);
}

// ---------------- MFMA GEMM, 128x64 tile, KT=32 (large-M + attn mode 1) ----------------
template<int BM>
__global__ __launch_bounds__(256)
void mfma_gemm_t(const float* __restrict__ A1f, int lda1, int k1,
                 const short* __restrict__ W1, int ldw1,
                 const float* __restrict__ A2f, int lda2, int k2,
                 const short* __restrict__ W2, int ldw2,
                 const float* __restrict__ bias1,
                 const float* __restrict__ mulvec, const float* __restrict__ mul,
                 float* __restrict__ C, int ldc, int M, int N,
                 int do_relu, int mode, int abits, int c_bf16)
{
    __shared__ short sA[2][BM][LSTR];
    __shared__ short sB[2][64][LSTR];
    __shared__ float sred[BM][2];
    constexpr int MF = BM / 32;

    const int tid = threadIdx.x;
    int m0, n0, ch8 = 0;
    if (mode == 1) {
        const int xcd = blockIdx.x & 7;
        const int gi = xcd * 588 + (blockIdx.x >> 3);
        m0 = (gi >> 3) << 7;
        ch8 = gi & 7;
        n0 = ch8 << 6;
    } else {
        m0 = blockIdx.y * BM;
        n0 = blockIdx.x << 6;
    }
    const short* A1b = (const short*)A1f;
    const short* A2b = (const short*)A2f;
    const int Ktot = k1 + k2;
    const int nt = (Ktot + KTILE - 1) / KTILE;
    const int lane = tid & 63, wave = tid >> 6;
    const int wr = (wave >> 1) * (BM >> 1);
    const int wc = (wave & 1) << 5;
    const int l15 = lane & 15, lh = lane >> 4;
    const int rowA = (BM == 128) ? (tid >> 1) : (tid >> 2);
    const int kA   = (BM == 128) ? ((tid & 1) << 4) : ((tid & 3) << 3);
    const int rgA = min(m0 + rowA, M - 1);
    const int rowW = tid >> 2, kW = (tid & 3) << 3;
    const int ngW = min(n0 + rowW, N - 1);

    f32x4 acc[MF][2];
#pragma unroll
    for (int m = 0; m < MF; ++m)
#pragma unroll
        for (int n = 0; n < 2; ++n) acc[m][n] = (f32x4){0.f, 0.f, 0.f, 0.f};

    short8 aS0, aS1, wS;
    auto loadA = [&](int t) {
        constexpr int AE = (BM == 128) ? 16 : 8;
        const int k0 = t * KTILE + kA;
        if (k0 + AE <= k1) {
            if (abits & 1) {
                const short* p = A1b + (size_t)rgA * lda1 + k0;
                aS0 = *(const short8*)p;
                if constexpr (BM == 128) aS1 = *(const short8*)(p + 8);
            } else {
                const float* p = A1f + (size_t)rgA * lda1 + k0;
                float4 v0 = *(const float4*)p, v1 = *(const float4*)(p + 4);
                float t0[8] = {v0.x, v0.y, v0.z, v0.w, v1.x, v1.y, v1.z, v1.w};
                aS0 = cvt8(t0);
                if constexpr (BM == 128) {
                    float4 v2 = *(const float4*)(p + 8), v3 = *(const float4*)(p + 12);
                    float t1[8] = {v2.x, v2.y, v2.z, v2.w, v3.x, v3.y, v3.z, v3.w};
                    aS1 = cvt8(t1);
                }
            }
        } else if (k0 >= k1 && k0 + AE <= Ktot) {
            const int kk = k0 - k1;
            if (abits & 2) {
                const short* p = A2b + (size_t)rgA * lda2 + kk;
                aS0 = *(const short8*)p;
                if constexpr (BM == 128) aS1 = *(const short8*)(p + 8);
            } else {
                const float* p = A2f + (size_t)rgA * lda2 + kk;
                float4 v0 = *(const float4*)p, v1 = *(const float4*)(p + 4);
                float t0[8] = {v0.x, v0.y, v0.z, v0.w, v1.x, v1.y, v1.z, v1.w};
                aS0 = cvt8(t0);
                if constexpr (BM == 128) {
                    float4 v2 = *(const float4*)(p + 8), v3 = *(const float4*)(p + 12);
                    float t1[8] = {v2.x, v2.y, v2.z, v2.w, v3.x, v3.y, v3.z, v3.w};
                    aS1 = cvt8(t1);
                }
            }
        } else {
            float tmp[(BM == 128) ? 16 : 8];
#pragma unroll
            for (int e = 0; e < ((BM == 128) ? 16 : 8); ++e) {
                const int kg = k0 + e;
                float v = 0.f;
                if (kg < k1) v = (abits & 1) ? bf2f(A1b[(size_t)rgA * lda1 + kg]) : A1f[(size_t)rgA * lda1 + kg];
                else if (kg < Ktot) v = (abits & 2) ? bf2f(A2b[(size_t)rgA * lda2 + (kg - k1)]) : A2f[(size_t)rgA * lda2 + (kg - k1)];
                tmp[e] = v;
            }
            aS0 = cvt8(tmp);
            if constexpr (BM == 128) aS1 = cvt8(tmp + 8);
        }
    };
    auto loadW = [&](int t) {
        const int k0 = t * KTILE + kW;
        if (k0 + 8 <= k1) {
            wS = *(const short8*)&W1[(size_t)ngW * ldw1 + k0];
        } else if (k0 >= k1 && k0 + 8 <= Ktot) {
            wS = *(const short8*)&W2[(size_t)ngW * ldw2 + (k0 - k1)];
        } else {
            short8 w;
#pragma unroll
            for (int e = 0; e < 8; ++e) {
                const int kg = k0 + e;
                w[e] = (kg < k1) ? W1[(size_t)ngW * ldw1 + kg]
                                 : ((kg < Ktot) ? W2[(size_t)ngW * ldw2 + (kg - k1)] : (short)0);
            }
            wS = w;
        }
    };
    auto writeS = [&](int buf) {
        *(short8*)&sA[buf][rowA][kA] = aS0;
        if constexpr (BM == 128) *(short8*)&sA[buf][rowA][kA + 8] = aS1;
        *(short8*)&sB[buf][rowW][kW] = wS;
    };

    loadA(0); loadW(0); writeS(0);
    __syncthreads();
    for (int t = 0; t < nt; ++t) {
        const int cur = t & 1;
        if (t + 1 < nt) { loadA(t + 1); loadW(t + 1); }
        short8 af[MF], bfv[2];
#pragma unroll
        for (int m = 0; m < MF; ++m)
            af[m] = *(const short8*)&sA[cur][wr + (m << 4) + l15][lh << 3];
#pragma unroll
        for (int n = 0; n < 2; ++n)
            bfv[n] = *(const short8*)&sB[cur][wc + (n << 4) + l15][lh << 3];
#pragma unroll
        for (int m = 0; m < MF; ++m)
#pragma unroll
            for (int n = 0; n < 2; ++n)
                acc[m][n] = __builtin_amdgcn_mfma_f32_16x16x32_bf16(af[m], bfv[n], acc[m][n], 0, 0, 0);
        if (t + 1 < nt) writeS(cur ^ 1);
        __syncthreads();
    }

    if (mode == 0) {
#pragma unroll
        for (int m = 0; m < MF; ++m) {
#pragma unroll
            for (int j = 0; j < 4; ++j) {
                const int r = m0 + wr + (m << 4) + (lh << 2) + j;
                if (r >= M) continue;
#pragma unroll
                for (int n = 0; n < 2; ++n) {
                    const int c = n0 + wc + (n << 4) + l15;
                    if (c >= N) continue;
                    float v = acc[m][n][j];
                    if (bias1) v += bias1[c];
                    if (do_relu) v = fmaxf(v, 0.f);
                    if (mulvec) v *= mulvec[c];
                    if (mul) v *= mul[(size_t)r * ldc + c];
                    if (c_bf16) {
                        __hip_bfloat16 b = __float2bfloat16(v);
                        ((short*)C)[(size_t)r * ldc + c] = *(short*)&b;
                    } else {
                        C[(size_t)r * ldc + c] = v;
                    }
                }
            }
        }
    } else {
#pragma unroll
        for (int m = 0; m < MF; ++m) {
#pragma unroll
            for (int j = 0; j < 4; ++j) {
                const int rloc = wr + (m << 4) + (lh << 2) + j;
                const int r = m0 + rloc;
                const size_t sqbase = (size_t)(r / 49) * ldc;
                float s = 0.f;
#pragma unroll
                for (int n = 0; n < 2; ++n) {
                    const int c = n0 + wc + (n << 4) + l15;
                    float v = acc[m][n][j] + bias1[c];
                    v = fmaxf(v, 0.f);
                    s += v * mul[sqbase + c];
                }
                s += __shfl_xor(s, 1, 64);
                s += __shfl_xor(s, 2, 64);
                s += __shfl_xor(s, 4, 64);
                s += __shfl_xor(s, 8, 64);
                if (l15 == 0) sred[rloc][wc >> 5] = s;
            }
        }
        __syncthreads();
        if (tid < BM)
            C[(size_t)(m0 + tid) * 8 + ch8] = sred[tid][0] + sred[tid][1];
    }
}

// ---------------- MFMA GEMM, 64x64 tile, KT=64 (small-M path) ----------------
__global__ __launch_bounds__(256)
void mfma_gemm64_kernel(const float* __restrict__ A1f, int lda1, int k1,
                        const short* __restrict__ W1, int ldw1,
                        const float* __restrict__ A2f, int lda2, int k2,
                        const short* __restrict__ W2, int ldw2,
                        const float* __restrict__ bias1,
                        const float* __restrict__ mulvec, const float* __restrict__ mul,
                        float* __restrict__ C, int ldc, int M, int N,
                        int do_relu, int abits, int c_bf16)
{
    __shared__ short sA[2][64][LSTR64];
    __shared__ short sB[2][64][LSTR64];
    const int tid = threadIdx.x;
    const int m0 = blockIdx.y << 6, n0 = blockIdx.x << 6;
    const short* A1b = (const short*)A1f;
    const short* A2b = (const short*)A2f;
    const int Ktot = k1 + k2;
    const int nt = (Ktot + 63) >> 6;
    const int lane = tid & 63, wave = tid >> 6;
    const int wr = (wave >> 1) << 5, wc = (wave & 1) << 5;
    const int l15 = lane & 15, lh = lane >> 4;
    const int srow = tid >> 2, skq = (tid & 3) << 4;
    const int rgA = min(m0 + srow, M - 1);
    const int ngW = min(n0 + srow, N - 1);

    f32x4 acc[2][2];
#pragma unroll
    for (int m = 0; m < 2; ++m)
#pragma unroll
        for (int n = 0; n < 2; ++n) acc[m][n] = (f32x4){0.f, 0.f, 0.f, 0.f};

    short8 aS0, aS1, wS0, wS1;
    auto loadA = [&](int t) {
        const int k0 = (t << 6) + skq;
        if (k0 + 16 <= k1) {
            if (abits & 1) {
                const short* p = A1b + (size_t)rgA * lda1 + k0;
                aS0 = *(const short8*)p; aS1 = *(const short8*)(p + 8);
            } else {
                const float* p = A1f + (size_t)rgA * lda1 + k0;
                float4 v0 = *(const float4*)p, v1 = *(const float4*)(p + 4);
                float4 v2 = *(const float4*)(p + 8), v3 = *(const float4*)(p + 12);
                float t0[8] = {v0.x, v0.y, v0.z, v0.w, v1.x, v1.y, v1.z, v1.w};
                float t1[8] = {v2.x, v2.y, v2.z, v2.w, v3.x, v3.y, v3.z, v3.w};
                aS0 = cvt8(t0); aS1 = cvt8(t1);
            }
        } else if (k0 >= k1 && k0 + 16 <= Ktot) {
            const int kk = k0 - k1;
            if (abits & 2) {
                const short* p = A2b + (size_t)rgA * lda2 + kk;
                aS0 = *(const short8*)p; aS1 = *(const short8*)(p + 8);
            } else {
                const float* p = A2f + (size_t)rgA * lda2 + kk;
                float4 v0 = *(const float4*)p, v1 = *(const float4*)(p + 4);
                float4 v2 = *(const float4*)(p + 8), v3 = *(const float4*)(p + 12);
                float t0[8] = {v0.x, v0.y, v0.z, v0.w, v1.x, v1.y, v1.z, v1.w};
                float t1[8] = {v2.x, v2.y, v2.z, v2.w, v3.x, v3.y, v3.z, v3.w};
                aS0 = cvt8(t0); aS1 = cvt8(t1);
            }
        } else {
            float tmp[16];
#pragma unroll
            for (int e = 0; e < 16; ++e) {
                const int kg = k0 + e;
                float v = 0.f;
                if (kg < k1) v = (abits & 1) ? bf2f(A1b[(size_t)rgA * lda1 + kg]) : A1f[(size_t)rgA * lda1 + kg];
                else if (kg < Ktot) v = (abits & 2) ? bf2f(A2b[(size_t)rgA * lda2 + (kg - k1)]) : A2f[(size_t)rgA * lda2 + (kg - k1)];
                tmp[e] = v;
            }
            aS0 = cvt8(tmp); aS1 = cvt8(tmp + 8);
        }
    };
    auto loadW = [&](int t) {
        const int k0 = (t << 6) + skq;
        if (k0 + 16 <= k1) {
            const short* p = W1 + (size_t)ngW * ldw1 + k0;
            wS0 = *(const short8*)p; wS1 = *(const short8*)(p + 8);
        } else if (k0 >= k1 && k0 + 16 <= Ktot) {
            const short* p = W2 + (size_t)ngW * ldw2 + (k0 - k1);
            wS0 = *(const short8*)p; wS1 = *(const short8*)(p + 8);
        } else {
            short8 w0, w1;
#pragma unroll
            for (int e = 0; e < 16; ++e) {
                const int kg = k0 + e;
                short v = (kg < k1) ? W1[(size_t)ngW * ldw1 + kg]
                                    : ((kg < Ktot) ? W2[(size_t)ngW * ldw2 + (kg - k1)] : (short)0);
                if (e < 8) w0[e] = v; else w1[e - 8] = v;
            }
            wS0 = w0; wS1 = w1;
        }
    };
    auto writeS = [&](int buf) {
        *(short8*)&sA[buf][srow][skq] = aS0;
        *(short8*)&sA[buf][srow][skq + 8] = aS1;
        *(short8*)&sB[buf][srow][skq] = wS0;
        *(short8*)&sB[buf][srow][skq + 8] = wS1;
    };

    loadA(0); loadW(0); writeS(0);
    __syncthreads();
    for (int t = 0; t < nt; ++t) {
        const int cur = t & 1;
        if (t + 1 < nt) { loadA(t + 1); loadW(t + 1); }
#pragma unroll
        for (int kk = 0; kk < 2; ++kk) {
            short8 af[2], bfv[2];
#pragma unroll
            for (int m = 0; m < 2; ++m)
                af[m] = *(const short8*)&sA[cur][wr + (m << 4) + l15][(kk << 5) + (lh << 3)];
#pragma unroll
            for (int n = 0; n < 2; ++n)
                bfv[n] = *(const short8*)&sB[cur][wc + (n << 4) + l15][(kk << 5) + (lh << 3)];
#pragma unroll
            for (int m = 0; m < 2; ++m)
#pragma unroll
                for (int n = 0; n < 2; ++n)
                    acc[m][n] = __builtin_amdgcn_mfma_f32_16x16x32_bf16(af[m], bfv[n], acc[m][n], 0, 0, 0);
        }
        if (t + 1 < nt) writeS(cur ^ 1);
        __syncthreads();
    }

#pragma unroll
    for (int m = 0; m < 2; ++m) {
#pragma unroll
        for (int j = 0; j < 4; ++j) {
            const int r = m0 + wr + (m << 4) + (lh << 2) + j;
            if (r >= M) continue;
#pragma unroll
            for (int n = 0; n < 2; ++n) {
                const int c = n0 + wc + (n << 4) + l15;
                if (c >= N) continue;
                float v = acc[m][n][j];
                if (bias1) v += bias1[c];
                if (do_relu) v = fmaxf(v, 0.f);
                if (mulvec) v *= mulvec[c];
                if (mul) v *= mul[(size_t)r * ldc + c];
                if (c_bf16) {
                    __hip_bfloat16 b = __float2bfloat16(v);
                    ((short*)C)[(size_t)r * ldc + c] = *(short*)&b;
                } else {
                    C[(size_t)r * ldc + c] = v;
                }
            }
        }
    }
}

// ---------------- weight bf16 pre-conversion (all GEMM weights, one pass) ----------------
__global__ __launch_bounds__(256)
void wcvt_kernel(const float* __restrict__ proj, const float* __restrict__ qW,
                 const float* __restrict__ vW, const float* __restrict__ qnet,
                 const float* __restrict__ vnet, const float* __restrict__ cls1,
                 const float* __restrict__ cls2, const float* __restrict__ g0,
                 const float* __restrict__ g1, const float* __restrict__ g2,
                 const float* __restrict__ g3, const float* __restrict__ f0,
                 const float* __restrict__ f1, short* __restrict__ dst)
{
    size_t idx = ((size_t)blockIdx.x * 256 + threadIdx.x) * 8;
    if (idx >= 5981184) return;
    const float* s;
    if (idx < 524288) s = proj + idx;
    else if (idx < 786432) s = qW + (idx - 524288);
    else if (idx < 1048576) s = vW + (idx - 786432);
    else if (idx < 1310720) s = qnet + (idx - 1048576);
    else if (idx < 1572864) s = vnet + (idx - 1310720);
    else if (idx < 2097152) s = cls1 + (idx - 1572864);
    else if (idx < 4146176) s = cls2 + (idx - 2097152);
    else if (idx < 4670464) {
        size_t li = idx - 4146176;
        int c = (int)(li >> 9), k = (int)(li & 511);
        s = (c < 512) ? g0 + (size_t)c * 1024 + k
                      : g0 + (size_t)(c - 512) * 1024 + 512 + k;
    }
    else if (idx < 4932608) s = g1 + (idx - 4670464);
    else if (idx < 5194752) s = g2 + (idx - 4932608);
    else if (idx < 5456896) s = g3 + (idx - 5194752);
    else if (idx < 5719040) s = f0 + (idx - 5456896);
    else s = f1 + (idx - 5719040);
    float4 a = *(const float4*)s, b = *(const float4*)(s + 4);
    float t[8] = {a.x, a.y, a.z, a.w, b.x, b.y, b.z, b.w};
    *(short8*)(dst + idx) = cvt8(t);
}

// ---------------- LSTM weight reorder -> MFMA fragment order ----------------
// Gate-permuted col c (unit u=c>>2, gate g=c&3; src row g*512+u). Fragment pack:
// slot s = (cb*2+wc2)*52 + t*2 + n2; WP[s*512 + lane*8 + e] =
//   Wrow(cb*64+wc2*32+n2*16+(lane&15)) col(t*32+(lane>>4)*8+e), cols: [Whh|Wih|0pad].
__global__ __launch_bounds__(256)
void lstm_reorder2_kernel(const float* __restrict__ Wih, const float* __restrict__ Whh,
                          const float* __restrict__ bih, const float* __restrict__ bhh,
                          short* __restrict__ WP, float* __restrict__ bias_perm)
{
    int id = blockIdx.x * 256 + threadIdx.x;   // < 2048*832
    int c = id / 832, k = id % 832;
    int src = (c & 3) * 512 + (c >> 2);
    float v = 0.f;
    if (k < 512) v = Whh[(size_t)src * 512 + k];
    else if (k < 812) v = Wih[(size_t)src * 300 + (k - 512)];
    __hip_bfloat16 b = __float2bfloat16(v);
    const int cb = c >> 6, rem = c & 63;
    const int wc2 = rem >> 5, n2 = (rem >> 4) & 1, l15 = rem & 15;
    const int t = k >> 5, kk = k & 31;
    const int lane = ((kk >> 3) << 4) + l15;
    const int s = (cb * 2 + wc2) * 52 + t * 2 + n2;
    WP[(size_t)s * 512 + lane * 8 + (kk & 7)] = *(short*)&b;
    if (k == 0) bias_perm[c] = bih[src] + bhh[src];
}

// ---------------- barrier-free fragment-direct LSTM step ----------------
// grid (32, 24, 2); 4 independent waves/block (no LDS, no __syncthreads).
// W fragment-packed (coalesced 16B/lane); A (h bf16 | emb fp32 gather) per-lane.
__global__ __launch_bounds__(256)
void lstm_step5_kernel(const short* __restrict__ hF_in, const short* __restrict__ hB_in,
                       const short* __restrict__ WPF, const short* __restrict__ WPB,
                       const float* __restrict__ biasF, const float* __restrict__ biasB,
                       const float* __restrict__ emb, const int* __restrict__ toks,
                       int tF, int tB, int first,
                       short* __restrict__ hF_out, short* __restrict__ hB_out,
                       float* __restrict__ cF, float* __restrict__ cB)
{
    const int dir = blockIdx.z;
    const short* h_in = dir ? hB_in : hF_in;
    const short* WP   = dir ? WPB : WPF;
    const float* bias_perm = dir ? biasB : biasF;
    short* h_out  = dir ? hB_out : hF_out;
    float* cstate = dir ? cB : cF;
    const int tt = dir ? tB : tF;

    const int tid = threadIdx.x;
    const int lane = tid & 63, wave = tid >> 6;
    const int cb = blockIdx.x;               // col-block 0..31
    const int m0 = blockIdx.y << 6;          // row-block
    const int wr = (wave >> 1) << 5;         // 0 / 32
    const int wc2 = wave & 1;
    const int wc = wc2 << 5;
    const int n0 = cb << 6;
    const int l15 = lane & 15, lh = lane >> 4;

    const int row0 = m0 + wr + l15;
    const int row1 = row0 + 16;
    const int arow0 = toks[row0 * 10 + tt];
    const int arow1 = toks[row1 * 10 + tt];

    f32x4 acc[2][2];
#pragma unroll
    for (int m = 0; m < 2; ++m)
#pragma unroll
        for (int n = 0; n < 2; ++n) acc[m][n] = (f32x4){0.f, 0.f, 0.f, 0.f};

    const short* wp = WP + ((size_t)(cb * 2 + wc2) * 52) * 512 + (lane << 3);

    // Phase 1: recurrent K (t=0..15, cols 0..511) — skipped entirely on first step
    if (!first) {
        for (int t = 0; t < 16; ++t) {
            short8 af0 = *(const short8*)(h_in + (size_t)row0 * 512 + (t << 5) + (lh << 3));
            short8 af1 = *(const short8*)(h_in + (size_t)row1 * 512 + (t << 5) + (lh << 3));
            short8 bf0 = *(const short8*)(wp + (size_t)(t * 2) * 512);
            short8 bf1 = *(const short8*)(wp + (size_t)(t * 2 + 1) * 512);
            acc[0][0] = __builtin_amdgcn_mfma_f32_16x16x32_bf16(af0, bf0, acc[0][0], 0, 0, 0);
            acc[0][1] = __builtin_amdgcn_mfma_f32_16x16x32_bf16(af0, bf1, acc[0][1], 0, 0, 0);
            acc[1][0] = __builtin_amdgcn_mfma_f32_16x16x32_bf16(af1, bf0, acc[1][0], 0, 0, 0);
            acc[1][1] = __builtin_amdgcn_mfma_f32_16x16x32_bf16(af1, bf1, acc[1][1], 0, 0, 0);
        }
    }
    // Phase 2: embedding K (t=16..25, emb cols 0..299, zero-padded to 320)
    for (int t = 16; t < 26; ++t) {
        const int c0 = (t << 5) + (lh << 3) - 512;
        short8 af0, af1;
        if (c0 + 8 <= 300) {
            const float* p0 = emb + (size_t)arow0 * 300 + c0;
            float4 u0 = *(const float4*)p0, u1 = *(const float4*)(p0 + 4);
            float t0[8] = {u0.x, u0.y, u0.z, u0.w, u1.x, u1.y, u1.z, u1.w};
            af0 = cvt8(t0);
            const float* p1 = emb + (size_t)arow1 * 300 + c0;
            float4 v0 = *(const float4*)p1, v1 = *(const float4*)(p1 + 4);
            float t1[8] = {v0.x, v0.y, v0.z, v0.w, v1.x, v1.y, v1.z, v1.w};
            af1 = cvt8(t1);
        } else {
            float t0[8], t1[8];
#pragma unroll
            for (int e = 0; e < 8; ++e) {
                const int kg = c0 + e;
                t0[e] = (kg < 300) ? emb[(size_t)arow0 * 300 + kg] : 0.f;
                t1[e] = (kg < 300) ? emb[(size_t)arow1 * 300 + kg] : 0.f;
            }
            af0 = cvt8(t0); af1 = cvt8(t1);
        }
        short8 bf0 = *(const short8*)(wp + (size_t)(t * 2) * 512);
        short8 bf1 = *(const short8*)(wp + (size_t)(t * 2 + 1) * 512);
        acc[0][0] = __builtin_amdgcn_mfma_f32_16x16x32_bf16(af0, bf0, acc[0][0], 0, 0, 0);
        acc[0][1] = __builtin_amdgcn_mfma_f32_16x16x32_bf16(af0, bf1, acc[0][1], 0, 0, 0);
        acc[1][0] = __builtin_amdgcn_mfma_f32_16x16x32_bf16(af1, bf0, acc[1][0], 0, 0, 0);
        acc[1][1] = __builtin_amdgcn_mfma_f32_16x16x32_bf16(af1, bf1, acc[1][1], 0, 0, 0);
    }

    // fused cell epilogue: lanes base..base+3 hold i,f,g,o of unit ccol>>2
#pragma unroll
    for (int n = 0; n < 2; ++n) {
        const int ccol = n0 + wc + (n << 4) + l15;
        const float bb = bias_perm[ccol];
        const int u = ccol >> 2;
#pragma unroll
        for (int m = 0; m < 2; ++m) {
#pragma unroll
            for (int j = 0; j < 4; ++j) {
                const int r = m0 + wr + (m << 4) + (lh << 2) + j;
                float v = acc[m][n][j] + bb;
                const int base = lane & ~3;
                float gi = __shfl(v, base, 64);
                float gf = __shfl(v, base | 1, 64);
                float gg = __shfl(v, base | 2, 64);
                float go = __shfl(v, base | 3, 64);
                if ((lane & 3) == 0) {
                    float si = 1.f / (1.f + expf(-gi));
                    float sf = 1.f / (1.f + expf(-gf));
                    float so = 1.f / (1.f + expf(-go));
                    size_t idx = ((size_t)r << 9) + u;
                    float cold = first ? 0.f : cstate[idx];
                    float cv = sf * cold + si * tanhf(gg);
                    cstate[idx] = cv;
                    float hv = so * tanhf(cv);
                    __hip_bfloat16 b = __float2bfloat16(hv);
                    h_out[idx] = *(short*)&b;
                }
            }
        }
    }
}

// img fp32 -> bf16
__global__ __launch_bounds__(256)
void imgcvt_kernel(const float* __restrict__ img, short* __restrict__ out)
{
    size_t i = ((size_t)blockIdx.x * 256 + threadIdx.x) * 8;
    float4 a = *(const float4*)(img + i), b = *(const float4*)(img + i + 4);
    float t[8] = {a.x, a.y, a.z, a.w, b.x, b.y, b.z, b.w};
    *(short8*)(out + i) = cvt8(t);
}

// softmax over 49 per n from 8-way partials, then v_emb[n,h] = sum_k att[k]*img[n,k,h]
__global__ __launch_bounds__(256)
void attn_vemb_kernel(const float* __restrict__ partial, const float* __restrict__ img,
                      const short* __restrict__ imgb, float* __restrict__ v_emb)
{
    __shared__ float satt[49];
    const int n = blockIdx.x;
    const int tid = threadIdx.x;
    if (tid < 64) {
        float v = -1e30f;
        if (tid < 49) {
            const float* pp = partial + ((size_t)n * 49 + tid) * 8;
            v = ((pp[0] + pp[1]) + (pp[2] + pp[3])) + ((pp[4] + pp[5]) + (pp[6] + pp[7]));
        }
        float m = v;
#pragma unroll
        for (int off = 32; off; off >>= 1) m = fmaxf(m, __shfl_xor(m, off, 64));
        float e = (tid < 49) ? expf(v - m) : 0.f;
        float s = e;
#pragma unroll
        for (int off = 32; off; off >>= 1) s += __shfl_xor(s, off, 64);
        if (tid < 49) satt[tid] = e / s;
    }
    __syncthreads();
    float2 s2 = make_float2(0.f, 0.f);
    if (imgb) {
        const unsigned int* ip = (const unsigned int*)(imgb + (size_t)n * 49 * 512);
        for (int k = 0; k < 49; ++k) {
            unsigned int v = ip[k * 256 + tid];
            float a = satt[k];
            s2.x = fmaf(a, bf2f((short)(v & 0xffff)), s2.x);
            s2.y = fmaf(a, bf2f((short)(v >> 16)), s2.y);
        }
    } else {
        const float2* ip = (const float2*)(img + (size_t)n * 49 * 512);
        for (int k = 0; k < 49; ++k) {
            float2 v = ip[k * 256 + tid];
            float a = satt[k];
            s2.x = fmaf(a, v.x, s2.x);
            s2.y = fmaf(a, v.y, s2.y);
        }
    }
    ((float2*)(v_emb + (size_t)n * 512))[tid] = s2;
}

// g0[b,i,j,c] = relu(PQ[b*6+j, c] + PQ[b*6+i, 512+c] + b0[c]) -> bf16
__global__ __launch_bounds__(256)
void g0build_kernel(const float* __restrict__ PQ, const float* __restrict__ b0,
                    short* __restrict__ g0)
{
    int id = blockIdx.x * 256 + threadIdx.x;   // < 9216*512
    int cc = id & 511;
    int r = id >> 9;
    int j = r % 6;
    int t = r / 6;
    int i = t % 6;
    int b = t / 6;
    float v = PQ[(size_t)(b * 6 + j) * 1024 + cc] + PQ[(size_t)(b * 6 + i) * 1024 + 512 + cc] + b0[cc];
    v = fmaxf(v, 0.f);
    __hip_bfloat16 h = __float2bfloat16(v);
    g0[id] = *(short*)&h;
}

__global__ __launch_bounds__(256)
void gsum_kernel(const short* __restrict__ g, float* __restrict__ out)
{
    int id = blockIdx.x * 256 + threadIdx.x;   // < 256*512
    int b = id >> 9, hh = id & 511;
    const short* p = g + (size_t)b * 36 * 512 + hh;
    float s = 0.f;
#pragma unroll
    for (int i = 0; i < 36; ++i) s += bf2f(p[i * 512]);
    out[id] = s;
}

__global__ __launch_bounds__(256)
void l2norm_kernel(const float* __restrict__ in, float* __restrict__ out)
{
    int b = blockIdx.x;
    int tid = threadIdx.x;
    float v0 = in[(size_t)b * 512 + tid];
    float v1 = in[(size_t)b * 512 + 256 + tid];
    float s = v0 * v0 + v1 * v1;
#pragma unroll
    for (int off = 32; off; off >>= 1) s += __shfl_down(s, off, 64);
    __shared__ float ps[4];
    if ((tid & 63) == 0) ps[tid >> 6] = s;
    __syncthreads();
    float tot = ps[0] + ps[1] + ps[2] + ps[3];
    float inv = 1.f / sqrtf(tot);
    out[(size_t)b * 512 + tid] = v0 * inv;
    out[(size_t)b * 512 + 256 + tid] = v1 * inv;
}

extern "C" void kernel_launch(void* const* d_in, const int* in_sizes, int n_in,
                              void* d_out, int out_size, void* d_ws, size_t ws_size,
                              hipStream_t stream)
{
    (void)in_sizes; (void)n_in; (void)out_size;
    const float* img    = (const float*)d_in[0];
    const int*   toks   = (const int*)d_in[1];
    const float* qword  = (const float*)d_in[2];
    const float* Wih_f  = (const float*)d_in[3];
    const float* Whh_f  = (const float*)d_in[4];
    const float* bih_f  = (const float*)d_in[5];
    const float* bhh_f  = (const float*)d_in[6];
    const float* Wih_b  = (const float*)d_in[7];
    const float* Whh_b  = (const float*)d_in[8];
    const float* bih_b  = (const float*)d_in[9];
    const float* bhh_b  = (const float*)d_in[10];
    const float* proj_W = (const float*)d_in[11];
    const float* proj_b = (const float*)d_in[12];
    const float* vatt_vW = (const float*)d_in[13];
    const float* vatt_vb = (const float*)d_in[14];
    const float* vatt_qW = (const float*)d_in[15];
    const float* vatt_qb = (const float*)d_in[16];
    const float* vatt_oW = (const float*)d_in[17];
    const float* qnet_W = (const float*)d_in[19];
    const float* qnet_b = (const float*)d_in[20];
    const float* vnet_W = (const float*)d_in[21];
    const float* vnet_b = (const float*)d_in[22];
    const float* cls_W1 = (const float*)d_in[23];
    const float* cls_b1 = (const float*)d_in[24];
    const float* cls_W2 = (const float*)d_in[25];
    const float* cls_b2 = (const float*)d_in[26];
    const float* g0_W   = (const float*)d_in[27];
    const float* g0_b   = (const float*)d_in[28];
    const float* g1_W   = (const float*)d_in[29];
    const float* g1_b   = (const float*)d_in[30];
    const float* g2_W   = (const float*)d_in[31];
    const float* g2_b   = (const float*)d_in[32];
    const float* g3_W   = (const float*)d_in[33];
    const float* g3_b   = (const float*)d_in[34];
    const float* f0_W   = (const float*)d_in[35];
    const float* f0_b   = (const float*)d_in[36];
    const float* f1_W   = (const float*)d_in[37];
    const float* f1_b   = (const float*)d_in[38];

    float* out_logits = (float*)d_out;                  // [1536,2001]
    float* out_rec    = (float*)d_out + 1536 * 2001;    // [256,512]

    const size_t FB = 786432;  // 1536*512
    float* zone = (float*)d_ws;
    float* gA    = zone;                        // 4718592
    float* gB    = zone + 4718592;              // 4718592
    float* hid1  = zone + 9437184;              // 1572864 (bf16)
    float* PQb   = zone + 11010048;             // 1572864 (P|Q fp32 [1536,1024])
    float* gsumb = zone + 12582912;             // 131072
    float* f0o   = zone + 12713984;             // 131072
    float* rectb = zone + 12845056;             // 131072
    float* p = zone + 12976128;
    auto alloc = [&](size_t nf) { float* q = p; p += nf; return q; };
    float* hP0   = alloc(FB);       // h_f (bf16 in slot)
    float* hP2   = alloc(FB);       // h_b
    float* joint = alloc(FB);       // bf16
    float* partial = alloc(602112); // 75264*8 fp32
    short* WPF   = (short*)alloc(851968);   // fragment-packed LSTM weights (3328 slots x 512)
    short* WPB   = (short*)alloc(851968);
    float* biasF = alloc(2048);
    float* biasB = alloc(2048);
    const size_t TOPF = 17645568;
    // bf16 weight pack (5981184 shorts = 2990592 floats)
    short* wb = (short*)(zone + TOPF);
    short* projbf = wb;
    short* qWbf   = wb + 524288;
    short* vWbf   = wb + 786432;
    short* qnetbf = wb + 1048576;
    short* vnetbf = wb + 1310720;
    short* cls1bf = wb + 1572864;
    short* cls2bf = wb + 2097152;
    short* wpqbf  = wb + 4146176;
    short* g1bf   = wb + 4670464;
    short* g2bf   = wb + 4932608;
    short* g3bf   = wb + 5194752;
    short* f0bf   = wb + 5456896;
    short* f1bf   = wb + 5719040;
    const size_t WEND = TOPF + 2990592;
    const size_t IMGBF = 19267584;  // 75264*512 bf16 in float units
    const bool useimgbf = ws_size >= (WEND + IMGBF) * sizeof(float);
    short* imgbf = (short*)(zone + WEND);
    // LSTM-phase aliases inside gA (gA only used post-LSTM)
    short* hP1 = (short*)gA;
    short* hP3 = (short*)(gA + FB);
    float* cF  = gA + 2 * FB;
    float* cB  = gA + 3 * FB;
    // post-LSTM aliases
    float* q_emb  = PQb;         // bf16; dead after qnet (before PQ-GEMM)
    float* swq    = hid1;        // fp32; dead after attn logits (before cls1)
    float* q_repr = gA;          // fp32; dead after vnet (before g0build)
    float* v_emb  = gA + FB;     // fp32; dead after vnet

    auto gemm = [&](const float* A1, int lda1, int k1, const short* W1, int ldw1,
                    const float* A2, int lda2, int k2, const short* W2, int ldw2,
                    const float* b1, const float* mv, const float* mulp,
                    float* Cp, int ldc, int M, int N, int relu, int abits, int cbf) {
        if (M >= 4096) {
            dim3 g((N + 63) / 64, (M + 127) / 128);
            hipLaunchKernelGGL(HIP_KERNEL_NAME(mfma_gemm_t<128>), g, dim3(256), 0, stream,
                               A1, lda1, k1, W1, ldw1, A2, lda2, k2, W2, ldw2,
                               b1, mv, mulp, Cp, ldc, M, N, relu, 0, abits, cbf);
        } else {
            dim3 g((N + 63) / 64, (M + 63) / 64);
            hipLaunchKernelGGL(mfma_gemm64_kernel, g, dim3(256), 0, stream,
                               A1, lda1, k1, W1, ldw1, A2, lda2, k2, W2, ldw2,
                               b1, mv, mulp, Cp, ldc, M, N, relu, abits, cbf);
        }
    };

    const int NR = 1536;
    // ---- one-time weight conversions ----
    hipLaunchKernelGGL(lstm_reorder2_kernel, dim3(6656), dim3(256), 0, stream,
                       Wih_f, Whh_f, bih_f, bhh_f, WPF, biasF);
    hipLaunchKernelGGL(lstm_reorder2_kernel, dim3(6656), dim3(256), 0, stream,
                       Wih_b, Whh_b, bih_b, bhh_b, WPB, biasB);
    hipLaunchKernelGGL(wcvt_kernel, dim3(2921), dim3(256), 0, stream,
                       proj_W, vatt_qW, vatt_vW, qnet_W, vnet_W, cls_W1, cls_W2,
                       g0_W, g1_W, g2_W, g3_W, f0_W, f1_W, wb);
    if (useimgbf)
        hipLaunchKernelGGL(imgcvt_kernel, dim3(18816), dim3(256), 0, stream, img, imgbf);
    // ---- bidirectional LSTM: 10 barrier-free fragment-direct steps ----
    {
        short *fi = (short*)hP0, *fo = hP1, *bi = (short*)hP2, *bo = hP3;
        for (int t = 0; t < 10; ++t) {
            hipLaunchKernelGGL(lstm_step5_kernel, dim3(32, 24, 2), dim3(256), 0, stream,
                               fi, bi, WPF, WPB, biasF, biasB, qword, toks, t, 9 - t,
                               (t == 0) ? 1 : 0, fo, bo, cF, cB);
            short* tmp = fi; fi = fo; fo = tmp;
            tmp = bi; bi = bo; bo = tmp;
        }
    }   // final h_f in hP0, h_b in hP2 (bf16)

    // q_emb(bf16) = [h_f|h_b] @ proj_W^T + proj_b
    gemm(hP0, 512, 512, projbf, 1024, hP2, 512, 512, projbf + 512, 1024,
         proj_b, nullptr, nullptr, q_emb, 512, NR, 512, 0, 3, 1);
    // swq(fp32) = relu(q_emb @ qW^T + qb) * oW
    gemm(q_emb, 512, 512, qWbf, 512, nullptr, 0, 0, nullptr, 0,
         vatt_qb, vatt_oW, nullptr, swq, 512, NR, 512, 1, 1, 0);
    // attention logits: XCD-swizzled mode-1 grid -> 8-way partials
    hipLaunchKernelGGL(HIP_KERNEL_NAME(mfma_gemm_t<128>), dim3(4704), dim3(256), 0, stream,
                       useimgbf ? (const float*)imgbf : img, 512, 512, vWbf, 512,
                       (const float*)nullptr, 0, 0, (const short*)nullptr, 0,
                       vatt_vb, (const float*)nullptr, swq,
                       partial, 512, 75264, 512, 0, 1, useimgbf ? 1 : 0, 0);
    hipLaunchKernelGGL(attn_vemb_kernel, dim3(1536), dim3(256), 0, stream,
                       partial, img, useimgbf ? imgbf : (const short*)nullptr, v_emb);
    // joint(bf16) = relu(q_emb@qnet^T+b) * relu(v_emb@vnet^T+b)
    gemm(q_emb, 512, 512, qnetbf, 512, nullptr, 0, 0, nullptr, 0,
         qnet_b, nullptr, nullptr, q_repr, 512, NR, 512, 1, 1, 0);
    gemm(v_emb, 512, 512, vnetbf, 512, nullptr, 0, 0, nullptr, 0,
         vnet_b, nullptr, q_repr, joint, 512, NR, 512, 1, 0, 1);
    // classifier
    gemm(joint, 512, 512, cls1bf, 512, nullptr, 0, 0, nullptr, 0,
         cls_b1, nullptr, nullptr, hid1, 1024, NR, 1024, 1, 1, 1);
    gemm(hid1, 1024, 1024, cls2bf, 1024, nullptr, 0, 0, nullptr, 0,
         cls_b2, nullptr, nullptr, out_logits, 2001, NR, 2001, 0, 1, 0);
    // relation network: P|Q in one GEMM (wpq pack), then g-chain
    gemm(joint, 512, 512, wpqbf, 512, nullptr, 0, 0, nullptr, 0,
         nullptr, nullptr, nullptr, PQb, 1024, NR, 1024, 0, 1, 0);
    hipLaunchKernelGGL(g0build_kernel, dim3(18432), dim3(256), 0, stream,
                       PQb, g0_b, (short*)gA);
    gemm(gA, 512, 512, g1bf, 512, nullptr, 0, 0, nullptr, 0,
         g1_b, nullptr, nullptr, gB, 512, 9216, 512, 1, 1, 1);
    gemm(gB, 512, 512, g2bf, 512, nullptr, 0, 0, nullptr, 0,
         g2_b, nullptr, nullptr, gA, 512, 9216, 512, 1, 1, 1);
    gemm(gA, 512, 512, g3bf, 512, nullptr, 0, 0, nullptr, 0,
         g3_b, nullptr, nullptr, gB, 512, 9216, 512, 1, 1, 1);
    hipLaunchKernelGGL(gsum_kernel, dim3(512), dim3(256), 0, stream, (const short*)gB, gsumb);
    gemm(gsumb, 512, 512, f0bf, 512, nullptr, 0, 0, nullptr, 0,
         f0_b, nullptr, nullptr, f0o, 512, 256, 512, 1, 0, 0);
    gemm(f0o, 512, 512, f1bf, 512, nullptr, 0, 0, nullptr, 0,
         f1_b, nullptr, nullptr, rectb, 512, 256, 512, 0, 0, 0);
    hipLaunchKernelGGL(l2norm_kernel, dim3(256), dim3(256), 0, stream, rectb, out_rec);
}

// Round 13
// 826.294 us; speedup vs baseline: 1.2268x; 1.2268x over previous
//
#include <hip/hip_runtime.h>
#include <hip/hip_bf16.h>
#include <hip/hip_cooperative_groups.h>
#include <math.h>

namespace cg = cooperative_groups;

typedef __attribute__((ext_vector_type(8))) short short8;
typedef __attribute__((ext_vector_type(4))) float f32x4;

#define KTILE 32
#define LSTR 40    // KT=32 paths: LDS row stride (bf16 elems): 80 B
#define LSTR64 72  // KT=64 path: 144 B row stride

__device__ __forceinline__ short8 cvt8(const float* x) {
    short8 r;
#pragma unroll
    for (int i = 0; i < 8; ++i) {
        __hip_bfloat16 b = __float2bfloat16(x[i]);
        r[i] = *reinterpret_cast<const short*>(&b);
    }
    return r;
}
__device__ __forceinline__ float bf2f(short s) {
    unsigned int u = ((unsigned int)(unsigned short)s) << 16;
    return __uint_as_float(u);
}

// ---------------- MFMA GEMM, 128x64 tile, KT=32 (large-M + attn mode 1) ----------------
template<int BM>
__global__ __launch_bounds__(256)
void mfma_gemm_t(const float* __restrict__ A1f, int lda1, int k1,
                 const short* __restrict__ W1, int ldw1,
                 const float* __restrict__ A2f, int lda2, int k2,
                 const short* __restrict__ W2, int ldw2,
                 const float* __restrict__ bias1,
                 const float* __restrict__ mulvec, const float* __restrict__ mul,
                 float* __restrict__ C, int ldc, int M, int N,
                 int do_relu, int mode, int abits, int c_bf16)
{
    __shared__ short sA[2][BM][LSTR];
    __shared__ short sB[2][64][LSTR];
    __shared__ float sred[BM][2];
    constexpr int MF = BM / 32;

    const int tid = threadIdx.x;
    int m0, n0, ch8 = 0;
    if (mode == 1) {
        const int xcd = blockIdx.x & 7;
        const int gi = xcd * 588 + (blockIdx.x >> 3);
        m0 = (gi >> 3) << 7;
        ch8 = gi & 7;
        n0 = ch8 << 6;
    } else {
        m0 = blockIdx.y * BM;
        n0 = blockIdx.x << 6;
    }
    const short* A1b = (const short*)A1f;
    const short* A2b = (const short*)A2f;
    const int Ktot = k1 + k2;
    const int nt = (Ktot + KTILE - 1) / KTILE;
    const int lane = tid & 63, wave = tid >> 6;
    const int wr = (wave >> 1) * (BM >> 1);
    const int wc = (wave & 1) << 5;
    const int l15 = lane & 15, lh = lane >> 4;
    const int rowA = (BM == 128) ? (tid >> 1) : (tid >> 2);
    const int kA   = (BM == 128) ? ((tid & 1) << 4) : ((tid & 3) << 3);
    const int rgA = min(m0 + rowA, M - 1);
    const int rowW = tid >> 2, kW = (tid & 3) << 3;
    const int ngW = min(n0 + rowW, N - 1);

    f32x4 acc[MF][2];
#pragma unroll
    for (int m = 0; m < MF; ++m)
#pragma unroll
        for (int n = 0; n < 2; ++n) acc[m][n] = (f32x4){0.f, 0.f, 0.f, 0.f};

    short8 aS0, aS1, wS;
    auto loadA = [&](int t) {
        constexpr int AE = (BM == 128) ? 16 : 8;
        const int k0 = t * KTILE + kA;
        if (k0 + AE <= k1) {
            if (abits & 1) {
                const short* p = A1b + (size_t)rgA * lda1 + k0;
                aS0 = *(const short8*)p;
                if constexpr (BM == 128) aS1 = *(const short8*)(p + 8);
            } else {
                const float* p = A1f + (size_t)rgA * lda1 + k0;
                float4 v0 = *(const float4*)p, v1 = *(const float4*)(p + 4);
                float t0[8] = {v0.x, v0.y, v0.z, v0.w, v1.x, v1.y, v1.z, v1.w};
                aS0 = cvt8(t0);
                if constexpr (BM == 128) {
                    float4 v2 = *(const float4*)(p + 8), v3 = *(const float4*)(p + 12);
                    float t1[8] = {v2.x, v2.y, v2.z, v2.w, v3.x, v3.y, v3.z, v3.w};
                    aS1 = cvt8(t1);
                }
            }
        } else if (k0 >= k1 && k0 + AE <= Ktot) {
            const int kk = k0 - k1;
            if (abits & 2) {
                const short* p = A2b + (size_t)rgA * lda2 + kk;
                aS0 = *(const short8*)p;
                if constexpr (BM == 128) aS1 = *(const short8*)(p + 8);
            } else {
                const float* p = A2f + (size_t)rgA * lda2 + kk;
                float4 v0 = *(const float4*)p, v1 = *(const float4*)(p + 4);
                float t0[8] = {v0.x, v0.y, v0.z, v0.w, v1.x, v1.y, v1.z, v1.w};
                aS0 = cvt8(t0);
                if constexpr (BM == 128) {
                    float4 v2 = *(const float4*)(p + 8), v3 = *(const float4*)(p + 12);
                    float t1[8] = {v2.x, v2.y, v2.z, v2.w, v3.x, v3.y, v3.z, v3.w};
                    aS1 = cvt8(t1);
                }
            }
        } else {
            float tmp[(BM == 128) ? 16 : 8];
#pragma unroll
            for (int e = 0; e < ((BM == 128) ? 16 : 8); ++e) {
                const int kg = k0 + e;
                float v = 0.f;
                if (kg < k1) v = (abits & 1) ? bf2f(A1b[(size_t)rgA * lda1 + kg]) : A1f[(size_t)rgA * lda1 + kg];
                else if (kg < Ktot) v = (abits & 2) ? bf2f(A2b[(size_t)rgA * lda2 + (kg - k1)]) : A2f[(size_t)rgA * lda2 + (kg - k1)];
                tmp[e] = v;
            }
            aS0 = cvt8(tmp);
            if constexpr (BM == 128) aS1 = cvt8(tmp + 8);
        }
    };
    auto loadW = [&](int t) {
        const int k0 = t * KTILE + kW;
        if (k0 + 8 <= k1) {
            wS = *(const short8*)&W1[(size_t)ngW * ldw1 + k0];
        } else if (k0 >= k1 && k0 + 8 <= Ktot) {
            wS = *(const short8*)&W2[(size_t)ngW * ldw2 + (k0 - k1)];
        } else {
            short8 w;
#pragma unroll
            for (int e = 0; e < 8; ++e) {
                const int kg = k0 + e;
                w[e] = (kg < k1) ? W1[(size_t)ngW * ldw1 + kg]
                                 : ((kg < Ktot) ? W2[(size_t)ngW * ldw2 + (kg - k1)] : (short)0);
            }
            wS = w;
        }
    };
    auto writeS = [&](int buf) {
        *(short8*)&sA[buf][rowA][kA] = aS0;
        if constexpr (BM == 128) *(short8*)&sA[buf][rowA][kA + 8] = aS1;
        *(short8*)&sB[buf][rowW][kW] = wS;
    };

    loadA(0); loadW(0); writeS(0);
    __syncthreads();
    for (int t = 0; t < nt; ++t) {
        const int cur = t & 1;
        if (t + 1 < nt) { loadA(t + 1); loadW(t + 1); }
        short8 af[MF], bfv[2];
#pragma unroll
        for (int m = 0; m < MF; ++m)
            af[m] = *(const short8*)&sA[cur][wr + (m << 4) + l15][lh << 3];
#pragma unroll
        for (int n = 0; n < 2; ++n)
            bfv[n] = *(const short8*)&sB[cur][wc + (n << 4) + l15][lh << 3];
#pragma unroll
        for (int m = 0; m < MF; ++m)
#pragma unroll
            for (int n = 0; n < 2; ++n)
                acc[m][n] = __builtin_amdgcn_mfma_f32_16x16x32_bf16(af[m], bfv[n], acc[m][n], 0, 0, 0);
        if (t + 1 < nt) writeS(cur ^ 1);
        __syncthreads();
    }

    if (mode == 0) {
#pragma unroll
        for (int m = 0; m < MF; ++m) {
#pragma unroll
            for (int j = 0; j < 4; ++j) {
                const int r = m0 + wr + (m << 4) + (lh << 2) + j;
                if (r >= M) continue;
#pragma unroll
                for (int n = 0; n < 2; ++n) {
                    const int c = n0 + wc + (n << 4) + l15;
                    if (c >= N) continue;
                    float v = acc[m][n][j];
                    if (bias1) v += bias1[c];
                    if (do_relu) v = fmaxf(v, 0.f);
                    if (mulvec) v *= mulvec[c];
                    if (mul) v *= mul[(size_t)r * ldc + c];
                    if (c_bf16) {
                        __hip_bfloat16 b = __float2bfloat16(v);
                        ((short*)C)[(size_t)r * ldc + c] = *(short*)&b;
                    } else {
                        C[(size_t)r * ldc + c] = v;
                    }
                }
            }
        }
    } else {
#pragma unroll
        for (int m = 0; m < MF; ++m) {
#pragma unroll
            for (int j = 0; j < 4; ++j) {
                const int rloc = wr + (m << 4) + (lh << 2) + j;
                const int r = m0 + rloc;
                const size_t sqbase = (size_t)(r / 49) * ldc;
                float s = 0.f;
#pragma unroll
                for (int n = 0; n < 2; ++n) {
                    const int c = n0 + wc + (n << 4) + l15;
                    float v = acc[m][n][j] + bias1[c];
                    v = fmaxf(v, 0.f);
                    s += v * mul[sqbase + c];
                }
                s += __shfl_xor(s, 1, 64);
                s += __shfl_xor(s, 2, 64);
                s += __shfl_xor(s, 4, 64);
                s += __shfl_xor(s, 8, 64);
                if (l15 == 0) sred[rloc][wc >> 5] = s;
            }
        }
        __syncthreads();
        if (tid < BM)
            C[(size_t)(m0 + tid) * 8 + ch8] = sred[tid][0] + sred[tid][1];
    }
}

// ---------------- MFMA GEMM, 64x64 tile, KT=64 (small-M path) ----------------
__global__ __launch_bounds__(256)
void mfma_gemm64_kernel(const float* __restrict__ A1f, int lda1, int k1,
                        const short* __restrict__ W1, int ldw1,
                        const float* __restrict__ A2f, int lda2, int k2,
                        const short* __restrict__ W2, int ldw2,
                        const float* __restrict__ bias1,
                        const float* __restrict__ mulvec, const float* __restrict__ mul,
                        float* __restrict__ C, int ldc, int M, int N,
                        int do_relu, int abits, int c_bf16)
{
    __shared__ short sA[2][64][LSTR64];
    __shared__ short sB[2][64][LSTR64];
    const int tid = threadIdx.x;
    const int m0 = blockIdx.y << 6, n0 = blockIdx.x << 6;
    const short* A1b = (const short*)A1f;
    const short* A2b = (const short*)A2f;
    const int Ktot = k1 + k2;
    const int nt = (Ktot + 63) >> 6;
    const int lane = tid & 63, wave = tid >> 6;
    const int wr = (wave >> 1) << 5, wc = (wave & 1) << 5;
    const int l15 = lane & 15, lh = lane >> 4;
    const int srow = tid >> 2, skq = (tid & 3) << 4;
    const int rgA = min(m0 + srow, M - 1);
    const int ngW = min(n0 + srow, N - 1);

    f32x4 acc[2][2];
#pragma unroll
    for (int m = 0; m < 2; ++m)
#pragma unroll
        for (int n = 0; n < 2; ++n) acc[m][n] = (f32x4){0.f, 0.f, 0.f, 0.f};

    short8 aS0, aS1, wS0, wS1;
    auto loadA = [&](int t) {
        const int k0 = (t << 6) + skq;
        if (k0 + 16 <= k1) {
            if (abits & 1) {
                const short* p = A1b + (size_t)rgA * lda1 + k0;
                aS0 = *(const short8*)p; aS1 = *(const short8*)(p + 8);
            } else {
                const float* p = A1f + (size_t)rgA * lda1 + k0;
                float4 v0 = *(const float4*)p, v1 = *(const float4*)(p + 4);
                float4 v2 = *(const float4*)(p + 8), v3 = *(const float4*)(p + 12);
                float t0[8] = {v0.x, v0.y, v0.z, v0.w, v1.x, v1.y, v1.z, v1.w};
                float t1[8] = {v2.x, v2.y, v2.z, v2.w, v3.x, v3.y, v3.z, v3.w};
                aS0 = cvt8(t0); aS1 = cvt8(t1);
            }
        } else if (k0 >= k1 && k0 + 16 <= Ktot) {
            const int kk = k0 - k1;
            if (abits & 2) {
                const short* p = A2b + (size_t)rgA * lda2 + kk;
                aS0 = *(const short8*)p; aS1 = *(const short8*)(p + 8);
            } else {
                const float* p = A2f + (size_t)rgA * lda2 + kk;
                float4 v0 = *(const float4*)p, v1 = *(const float4*)(p + 4);
                float4 v2 = *(const float4*)(p + 8), v3 = *(const float4*)(p + 12);
                float t0[8] = {v0.x, v0.y, v0.z, v0.w, v1.x, v1.y, v1.z, v1.w};
                float t1[8] = {v2.x, v2.y, v2.z, v2.w, v3.x, v3.y, v3.z, v3.w};
                aS0 = cvt8(t0); aS1 = cvt8(t1);
            }
        } else {
            float tmp[16];
#pragma unroll
            for (int e = 0; e < 16; ++e) {
                const int kg = k0 + e;
                float v = 0.f;
                if (kg < k1) v = (abits & 1) ? bf2f(A1b[(size_t)rgA * lda1 + kg]) : A1f[(size_t)rgA * lda1 + kg];
                else if (kg < Ktot) v = (abits & 2) ? bf2f(A2b[(size_t)rgA * lda2 + (kg - k1)]) : A2f[(size_t)rgA * lda2 + (kg - k1)];
                tmp[e] = v;
            }
            aS0 = cvt8(tmp); aS1 = cvt8(tmp + 8);
        }
    };
    auto loadW = [&](int t) {
        const int k0 = (t << 6) + skq;
        if (k0 + 16 <= k1) {
            const short* p = W1 + (size_t)ngW * ldw1 + k0;
            wS0 = *(const short8*)p; wS1 = *(const short8*)(p + 8);
        } else if (k0 >= k1 && k0 + 16 <= Ktot) {
            const short* p = W2 + (size_t)ngW * ldw2 + (k0 - k1);
            wS0 = *(const short8*)p; wS1 = *(const short8*)(p + 8);
        } else {
            short8 w0, w1;
#pragma unroll
            for (int e = 0; e < 16; ++e) {
                const int kg = k0 + e;
                short v = (kg < k1) ? W1[(size_t)ngW * ldw1 + kg]
                                    : ((kg < Ktot) ? W2[(size_t)ngW * ldw2 + (kg - k1)] : (short)0);
                if (e < 8) w0[e] = v; else w1[e - 8] = v;
            }
            wS0 = w0; wS1 = w1;
        }
    };
    auto writeS = [&](int buf) {
        *(short8*)&sA[buf][srow][skq] = aS0;
        *(short8*)&sA[buf][srow][skq + 8] = aS1;
        *(short8*)&sB[buf][srow][skq] = wS0;
        *(short8*)&sB[buf][srow][skq + 8] = wS1;
    };

    loadA(0); loadW(0); writeS(0);
    __syncthreads();
    for (int t = 0; t < nt; ++t) {
        const int cur = t & 1;
        if (t + 1 < nt) { loadA(t + 1); loadW(t + 1); }
#pragma unroll
        for (int kk = 0; kk < 2; ++kk) {
            short8 af[2], bfv[2];
#pragma unroll
            for (int m = 0; m < 2; ++m)
                af[m] = *(const short8*)&sA[cur][wr + (m << 4) + l15][(kk << 5) + (lh << 3)];
#pragma unroll
            for (int n = 0; n < 2; ++n)
                bfv[n] = *(const short8*)&sB[cur][wc + (n << 4) + l15][(kk << 5) + (lh << 3)];
#pragma unroll
            for (int m = 0; m < 2; ++m)
#pragma unroll
                for (int n = 0; n < 2; ++n)
                    acc[m][n] = __builtin_amdgcn_mfma_f32_16x16x32_bf16(af[m], bfv[n], acc[m][n], 0, 0, 0);
        }
        if (t + 1 < nt) writeS(cur ^ 1);
        __syncthreads();
    }

#pragma unroll
    for (int m = 0; m < 2; ++m) {
#pragma unroll
        for (int j = 0; j < 4; ++j) {
            const int r = m0 + wr + (m << 4) + (lh << 2) + j;
            if (r >= M) continue;
#pragma unroll
            for (int n = 0; n < 2; ++n) {
                const int c = n0 + wc + (n << 4) + l15;
                if (c >= N) continue;
                float v = acc[m][n][j];
                if (bias1) v += bias1[c];
                if (do_relu) v = fmaxf(v, 0.f);
                if (mulvec) v *= mulvec[c];
                if (mul) v *= mul[(size_t)r * ldc + c];
                if (c_bf16) {
                    __hip_bfloat16 b = __float2bfloat16(v);
                    ((short*)C)[(size_t)r * ldc + c] = *(short*)&b;
                } else {
                    C[(size_t)r * ldc + c] = v;
                }
            }
        }
    }
}

// ---------------- weight bf16 pre-conversion (all GEMM weights, one pass) ----------------
__global__ __launch_bounds__(256)
void wcvt_kernel(const float* __restrict__ proj, const float* __restrict__ qW,
                 const float* __restrict__ vW, const float* __restrict__ qnet,
                 const float* __restrict__ vnet, const float* __restrict__ cls1,
                 const float* __restrict__ cls2, const float* __restrict__ g0,
                 const float* __restrict__ g1, const float* __restrict__ g2,
                 const float* __restrict__ g3, const float* __restrict__ f0,
                 const float* __restrict__ f1, short* __restrict__ dst)
{
    size_t idx = ((size_t)blockIdx.x * 256 + threadIdx.x) * 8;
    if (idx >= 5981184) return;
    const float* s;
    if (idx < 524288) s = proj + idx;
    else if (idx < 786432) s = qW + (idx - 524288);
    else if (idx < 1048576) s = vW + (idx - 786432);
    else if (idx < 1310720) s = qnet + (idx - 1048576);
    else if (idx < 1572864) s = vnet + (idx - 1310720);
    else if (idx < 2097152) s = cls1 + (idx - 1572864);
    else if (idx < 4146176) s = cls2 + (idx - 2097152);
    else if (idx < 4670464) {
        size_t li = idx - 4146176;
        int c = (int)(li >> 9), k = (int)(li & 511);
        s = (c < 512) ? g0 + (size_t)c * 1024 + k
                      : g0 + (size_t)(c - 512) * 1024 + 512 + k;
    }
    else if (idx < 4932608) s = g1 + (idx - 4670464);
    else if (idx < 5194752) s = g2 + (idx - 4932608);
    else if (idx < 5456896) s = g3 + (idx - 5194752);
    else if (idx < 5719040) s = f0 + (idx - 5456896);
    else s = f1 + (idx - 5719040);
    float4 a = *(const float4*)s, b = *(const float4*)(s + 4);
    float t[8] = {a.x, a.y, a.z, a.w, b.x, b.y, b.z, b.w};
    *(short8*)(dst + idx) = cvt8(t);
}

// ---------------- LSTM weight reorder (row-major [2048][832], gate-permuted) ----------------
__global__ __launch_bounds__(256)
void lstm_reorder_kernel(const float* __restrict__ Wih, const float* __restrict__ Whh,
                         const float* __restrict__ bih, const float* __restrict__ bhh,
                         short* __restrict__ Wbf, float* __restrict__ bias_perm)
{
    int id = blockIdx.x * 256 + threadIdx.x;   // < 2048*512
    int c = id >> 9, k = id & 511;
    int src = (c & 3) * 512 + (c >> 2);
    {
        __hip_bfloat16 b = __float2bfloat16(Whh[(size_t)src * 512 + k]);
        Wbf[(size_t)c * 832 + k] = *(short*)&b;
    }
    if (k < 300) {
        __hip_bfloat16 b = __float2bfloat16(Wih[(size_t)src * 300 + k]);
        Wbf[(size_t)c * 832 + 512 + k] = *(short*)&b;
    } else if (k < 320) {
        Wbf[(size_t)c * 832 + 512 + k] = 0;
    }
    if (k == 0) bias_perm[c] = bih[src] + bhh[src];
}

// ---------------- fused LSTM step, 64x64 tile, KT=64 (fallback per-step launch) ----------------
__global__ __launch_bounds__(256)
void lstm_step4_kernel(const short* __restrict__ hF_in, const short* __restrict__ hB_in,
                       const short* __restrict__ WbfF, const short* __restrict__ WbfB,
                       const float* __restrict__ biasF, const float* __restrict__ biasB,
                       const float* __restrict__ emb, const int* __restrict__ toks,
                       int tF, int tB, int first,
                       short* __restrict__ hF_out, short* __restrict__ hB_out,
                       float* __restrict__ cF, float* __restrict__ cB)
{
    __shared__ short sA[2][64][LSTR64];
    __shared__ short sB[2][64][LSTR64];
    const int dir = blockIdx.z;
    const short* h_in = dir ? hB_in : hF_in;
    const short* Wbf  = dir ? WbfB : WbfF;
    const float* bias_perm = dir ? biasB : biasF;
    short* h_out  = dir ? hB_out : hF_out;
    float* cstate = dir ? cB : cF;
    const int tt = dir ? tB : tF;

    const int tid = threadIdx.x;
    const int m0 = blockIdx.y << 6;
    const int n0 = blockIdx.x << 6;
    const int lane = tid & 63, wave = tid >> 6;
    const int wr = (wave >> 1) << 5, wc = (wave & 1) << 5;
    const int l15 = lane & 15, lh = lane >> 4;
    const int srow = tid >> 2, skq = (tid & 3) << 4;
    const int rgA = m0 + srow;
    const int ngW = n0 + srow;
    const int nt = 13;
    const int arow = toks[rgA * 10 + tt];

    f32x4 acc[2][2];
#pragma unroll
    for (int m = 0; m < 2; ++m)
#pragma unroll
        for (int n = 0; n < 2; ++n) acc[m][n] = (f32x4){0.f, 0.f, 0.f, 0.f};

    short8 aS0, aS1, wS0, wS1;
    auto loadA = [&](int t) {
        const int k0 = (t << 6) + skq;
        if (k0 + 16 <= 512) {
            if (first) { short8 z = {0,0,0,0,0,0,0,0}; aS0 = z; aS1 = z; }
            else {
                const short* p = h_in + (size_t)rgA * 512 + k0;
                aS0 = *(const short8*)p; aS1 = *(const short8*)(p + 8);
            }
        } else if (k0 >= 512 && k0 + 16 <= 812) {
            const float* p = emb + (size_t)arow * 300 + (k0 - 512);
            float4 v0 = *(const float4*)p, v1 = *(const float4*)(p + 4);
            float4 v2 = *(const float4*)(p + 8), v3 = *(const float4*)(p + 12);
            float t0[8] = {v0.x, v0.y, v0.z, v0.w, v1.x, v1.y, v1.z, v1.w};
            float t1[8] = {v2.x, v2.y, v2.z, v2.w, v3.x, v3.y, v3.z, v3.w};
            aS0 = cvt8(t0); aS1 = cvt8(t1);
        } else {
            float tmp[16];
#pragma unroll
            for (int e = 0; e < 16; ++e) {
                const int kg = k0 + e;
                float v = 0.f;
                if (kg < 512) v = first ? 0.f : bf2f(h_in[(size_t)rgA * 512 + kg]);
                else if (kg < 812) v = emb[(size_t)arow * 300 + (kg - 512)];
                tmp[e] = v;
            }
            aS0 = cvt8(tmp); aS1 = cvt8(tmp + 8);
        }
    };
    auto loadW = [&](int t) {
        const short* p = Wbf + (size_t)ngW * 832 + (t << 6) + skq;
        wS0 = *(const short8*)p; wS1 = *(const short8*)(p + 8);
    };
    auto writeS = [&](int buf) {
        *(short8*)&sA[buf][srow][skq] = aS0;
        *(short8*)&sA[buf][srow][skq + 8] = aS1;
        *(short8*)&sB[buf][srow][skq] = wS0;
        *(short8*)&sB[buf][srow][skq + 8] = wS1;
    };

    loadA(0); loadW(0); writeS(0);
    __syncthreads();
    for (int t = 0; t < nt; ++t) {
        const int cur = t & 1;
        if (t + 1 < nt) { loadA(t + 1); loadW(t + 1); }
#pragma unroll
        for (int kk = 0; kk < 2; ++kk) {
            short8 af[2], bfv[2];
#pragma unroll
            for (int m = 0; m < 2; ++m)
                af[m] = *(const short8*)&sA[cur][wr + (m << 4) + l15][(kk << 5) + (lh << 3)];
#pragma unroll
            for (int n = 0; n < 2; ++n)
                bfv[n] = *(const short8*)&sB[cur][wc + (n << 4) + l15][(kk << 5) + (lh << 3)];
#pragma unroll
            for (int m = 0; m < 2; ++m)
#pragma unroll
                for (int n = 0; n < 2; ++n)
                    acc[m][n] = __builtin_amdgcn_mfma_f32_16x16x32_bf16(af[m], bfv[n], acc[m][n], 0, 0, 0);
        }
        if (t + 1 < nt) writeS(cur ^ 1);
        __syncthreads();
    }

#pragma unroll
    for (int n = 0; n < 2; ++n) {
        const int ccol = n0 + wc + (n << 4) + l15;
        const float bb = bias_perm[ccol];
        const int u = ccol >> 2;
#pragma unroll
        for (int m = 0; m < 2; ++m) {
#pragma unroll
            for (int j = 0; j < 4; ++j) {
                const int r = m0 + wr + (m << 4) + (lh << 2) + j;
                float v = acc[m][n][j] + bb;
                const int base = lane & ~3;
                float gi = __shfl(v, base, 64);
                float gf = __shfl(v, base | 1, 64);
                float gg = __shfl(v, base | 2, 64);
                float go = __shfl(v, base | 3, 64);
                if ((lane & 3) == 0) {
                    float si = 1.f / (1.f + expf(-gi));
                    float sf = 1.f / (1.f + expf(-gf));
                    float so = 1.f / (1.f + expf(-go));
                    size_t idx = ((size_t)r << 9) + u;
                    float cold = first ? 0.f : cstate[idx];
                    float cv = sf * cold + si * tanhf(gg);
                    cstate[idx] = cv;
                    float hv = so * tanhf(cv);
                    __hip_bfloat16 b = __float2bfloat16(hv);
                    h_out[idx] = *(short*)&b;
                }
            }
        }
    }
}

// ---------------- persistent cooperative LSTM: all 10 steps, grid.sync between ----------------
// grid 1536 (1D): dir = bid/768; g = bid%768; cb = g&31 (XCD-spread); rb = g>>5.
// KT=32 body (20.5 KB LDS -> 7 blocks/CU capacity >= 6 needed for co-residency).
__global__ __launch_bounds__(256)
void lstm_persist_kernel(short* hFa, short* hFb, short* hBa, short* hBb,
                         const short* __restrict__ WbfF, const short* __restrict__ WbfB,
                         const float* __restrict__ biasF, const float* __restrict__ biasB,
                         const float* __restrict__ emb, const int* __restrict__ toks,
                         float* __restrict__ cF, float* __restrict__ cB)
{
    cg::grid_group grid = cg::this_grid();
    __shared__ short sA[2][64][LSTR];
    __shared__ short sB[2][64][LSTR];
    const int bid = blockIdx.x;
    const int dir = bid >= 768;
    const int g = bid - (dir ? 768 : 0);
    const int cb = g & 31, rb = g >> 5;
    const short* Wbf = dir ? WbfB : WbfF;
    const float* bias_perm = dir ? biasB : biasF;
    float* cstate = dir ? cB : cF;
    short* hb0 = dir ? hBa : hFa;
    short* hb1 = dir ? hBb : hFb;

    const int tid = threadIdx.x;
    const int m0 = rb << 6, n0 = cb << 6;
    const int lane = tid & 63, wave = tid >> 6;
    const int wr = (wave >> 1) << 5, wc = (wave & 1) << 5;
    const int l15 = lane & 15, lh = lane >> 4;
    const int srow = tid >> 2, skq = (tid & 3) << 3;
    const int rgA = m0 + srow;
    const int ngW = n0 + srow;

    for (int step = 0; step < 10; ++step) {
        if (step) grid.sync();
        const int tt = dir ? (9 - step) : step;
        const int first = (step == 0);
        const short* h_in = (step & 1) ? hb1 : hb0;
        short* h_out = (step & 1) ? hb0 : hb1;
        const int arow = toks[rgA * 10 + tt];

        f32x4 acc[2][2];
#pragma unroll
        for (int m = 0; m < 2; ++m)
#pragma unroll
            for (int n = 0; n < 2; ++n) acc[m][n] = (f32x4){0.f, 0.f, 0.f, 0.f};

        short8 aS, wS;
        auto loadA = [&](int t) {
            const int k0 = (t << 5) + skq;
            if (k0 + 8 <= 512) {
                if (first) { short8 z = {0,0,0,0,0,0,0,0}; aS = z; }
                else aS = *(const short8*)(h_in + (size_t)rgA * 512 + k0);
            } else if (k0 >= 512 && k0 + 8 <= 812) {
                const float* p = emb + (size_t)arow * 300 + (k0 - 512);
                float4 v0 = *(const float4*)p, v1 = *(const float4*)(p + 4);
                float t0[8] = {v0.x, v0.y, v0.z, v0.w, v1.x, v1.y, v1.z, v1.w};
                aS = cvt8(t0);
            } else {
                float tmp[8];
#pragma unroll
                for (int e = 0; e < 8; ++e) {
                    const int kg = k0 + e;
                    float v = 0.f;
                    if (kg < 512) v = first ? 0.f : bf2f(h_in[(size_t)rgA * 512 + kg]);
                    else if (kg < 812) v = emb[(size_t)arow * 300 + (kg - 512)];
                    tmp[e] = v;
                }
                aS = cvt8(tmp);
            }
        };
        auto loadW = [&](int t) {
            wS = *(const short8*)&Wbf[(size_t)ngW * 832 + (t << 5) + skq];
        };
        auto writeS = [&](int buf) {
            *(short8*)&sA[buf][srow][skq] = aS;
            *(short8*)&sB[buf][srow][skq] = wS;
        };

        loadA(0); loadW(0); writeS(0);
        __syncthreads();
        for (int t = 0; t < 26; ++t) {
            const int cur = t & 1;
            if (t + 1 < 26) { loadA(t + 1); loadW(t + 1); }
            short8 af[2], bfv[2];
#pragma unroll
            for (int m = 0; m < 2; ++m)
                af[m] = *(const short8*)&sA[cur][wr + (m << 4) + l15][lh << 3];
#pragma unroll
            for (int n = 0; n < 2; ++n)
                bfv[n] = *(const short8*)&sB[cur][wc + (n << 4) + l15][lh << 3];
#pragma unroll
            for (int m = 0; m < 2; ++m)
#pragma unroll
                for (int n = 0; n < 2; ++n)
                    acc[m][n] = __builtin_amdgcn_mfma_f32_16x16x32_bf16(af[m], bfv[n], acc[m][n], 0, 0, 0);
            if (t + 1 < 26) writeS(cur ^ 1);
            __syncthreads();
        }

#pragma unroll
        for (int n = 0; n < 2; ++n) {
            const int ccol = n0 + wc + (n << 4) + l15;
            const float bb = bias_perm[ccol];
            const int u = ccol >> 2;
#pragma unroll
            for (int m = 0; m < 2; ++m) {
#pragma unroll
                for (int j = 0; j < 4; ++j) {
                    const int r = m0 + wr + (m << 4) + (lh << 2) + j;
                    float v = acc[m][n][j] + bb;
                    const int base = lane & ~3;
                    float gi = __shfl(v, base, 64);
                    float gf = __shfl(v, base | 1, 64);
                    float gg = __shfl(v, base | 2, 64);
                    float go = __shfl(v, base | 3, 64);
                    if ((lane & 3) == 0) {
                        float si = 1.f / (1.f + expf(-gi));
                        float sf = 1.f / (1.f + expf(-gf));
                        float so = 1.f / (1.f + expf(-go));
                        size_t idx = ((size_t)r << 9) + u;
                        float cold = first ? 0.f : cstate[idx];
                        float cv = sf * cold + si * tanhf(gg);
                        cstate[idx] = cv;
                        float hv = so * tanhf(cv);
                        __hip_bfloat16 b = __float2bfloat16(hv);
                        h_out[idx] = *(short*)&b;
                    }
                }
            }
        }
    }
}

// img fp32 -> bf16
__global__ __launch_bounds__(256)
void imgcvt_kernel(const float* __restrict__ img, short* __restrict__ out)
{
    size_t i = ((size_t)blockIdx.x * 256 + threadIdx.x) * 8;
    float4 a = *(const float4*)(img + i), b = *(const float4*)(img + i + 4);
    float t[8] = {a.x, a.y, a.z, a.w, b.x, b.y, b.z, b.w};
    *(short8*)(out + i) = cvt8(t);
}

// softmax over 49 per n from 8-way partials, then v_emb[n,h] = sum_k att[k]*img[n,k,h]
__global__ __launch_bounds__(256)
void attn_vemb_kernel(const float* __restrict__ partial, const float* __restrict__ img,
                      const short* __restrict__ imgb, float* __restrict__ v_emb)
{
    __shared__ float satt[49];
    const int n = blockIdx.x;
    const int tid = threadIdx.x;
    if (tid < 64) {
        float v = -1e30f;
        if (tid < 49) {
            const float* pp = partial + ((size_t)n * 49 + tid) * 8;
            v = ((pp[0] + pp[1]) + (pp[2] + pp[3])) + ((pp[4] + pp[5]) + (pp[6] + pp[7]));
        }
        float m = v;
#pragma unroll
        for (int off = 32; off; off >>= 1) m = fmaxf(m, __shfl_xor(m, off, 64));
        float e = (tid < 49) ? expf(v - m) : 0.f;
        float s = e;
#pragma unroll
        for (int off = 32; off; off >>= 1) s += __shfl_xor(s, off, 64);
        if (tid < 49) satt[tid] = e / s;
    }
    __syncthreads();
    float2 s2 = make_float2(0.f, 0.f);
    if (imgb) {
        const unsigned int* ip = (const unsigned int*)(imgb + (size_t)n * 49 * 512);
        for (int k = 0; k < 49; ++k) {
            unsigned int v = ip[k * 256 + tid];
            float a = satt[k];
            s2.x = fmaf(a, bf2f((short)(v & 0xffff)), s2.x);
            s2.y = fmaf(a, bf2f((short)(v >> 16)), s2.y);
        }
    } else {
        const float2* ip = (const float2*)(img + (size_t)n * 49 * 512);
        for (int k = 0; k < 49; ++k) {
            float2 v = ip[k * 256 + tid];
            float a = satt[k];
            s2.x = fmaf(a, v.x, s2.x);
            s2.y = fmaf(a, v.y, s2.y);
        }
    }
    ((float2*)(v_emb + (size_t)n * 512))[tid] = s2;
}

// g0[b,i,j,c] = relu(PQ[b*6+j, c] + PQ[b*6+i, 512+c] + b0[c]) -> bf16
__global__ __launch_bounds__(256)
void g0build_kernel(const float* __restrict__ PQ, const float* __restrict__ b0,
                    short* __restrict__ g0)
{
    int id = blockIdx.x * 256 + threadIdx.x;
    int cc = id & 511;
    int r = id >> 9;
    int j = r % 6;
    int t = r / 6;
    int i = t % 6;
    int b = t / 6;
    float v = PQ[(size_t)(b * 6 + j) * 1024 + cc] + PQ[(size_t)(b * 6 + i) * 1024 + 512 + cc] + b0[cc];
    v = fmaxf(v, 0.f);
    __hip_bfloat16 h = __float2bfloat16(v);
    g0[id] = *(short*)&h;
}

__global__ __launch_bounds__(256)
void gsum_kernel(const short* __restrict__ g, float* __restrict__ out)
{
    int id = blockIdx.x * 256 + threadIdx.x;
    int b = id >> 9, hh = id & 511;
    const short* p = g + (size_t)b * 36 * 512 + hh;
    float s = 0.f;
#pragma unroll
    for (int i = 0; i < 36; ++i) s += bf2f(p[i * 512]);
    out[id] = s;
}

__global__ __launch_bounds__(256)
void l2norm_kernel(const float* __restrict__ in, float* __restrict__ out)
{
    int b = blockIdx.x;
    int tid = threadIdx.x;
    float v0 = in[(size_t)b * 512 + tid];
    float v1 = in[(size_t)b * 512 + 256 + tid];
    float s = v0 * v0 + v1 * v1;
#pragma unroll
    for (int off = 32; off; off >>= 1) s += __shfl_down(s, off, 64);
    __shared__ float ps[4];
    if ((tid & 63) == 0) ps[tid >> 6] = s;
    __syncthreads();
    float tot = ps[0] + ps[1] + ps[2] + ps[3];
    float inv = 1.f / sqrtf(tot);
    out[(size_t)b * 512 + tid] = v0 * inv;
    out[(size_t)b * 512 + 256 + tid] = v1 * inv;
}

extern "C" void kernel_launch(void* const* d_in, const int* in_sizes, int n_in,
                              void* d_out, int out_size, void* d_ws, size_t ws_size,
                              hipStream_t stream)
{
    (void)in_sizes; (void)n_in; (void)out_size;
    const float* img    = (const float*)d_in[0];
    const int*   toks   = (const int*)d_in[1];
    const float* qword  = (const float*)d_in[2];
    const float* Wih_f  = (const float*)d_in[3];
    const float* Whh_f  = (const float*)d_in[4];
    const float* bih_f  = (const float*)d_in[5];
    const float* bhh_f  = (const float*)d_in[6];
    const float* Wih_b  = (const float*)d_in[7];
    const float* Whh_b  = (const float*)d_in[8];
    const float* bih_b  = (const float*)d_in[9];
    const float* bhh_b  = (const float*)d_in[10];
    const float* proj_W = (const float*)d_in[11];
    const float* proj_b = (const float*)d_in[12];
    const float* vatt_vW = (const float*)d_in[13];
    const float* vatt_vb = (const float*)d_in[14];
    const float* vatt_qW = (const float*)d_in[15];
    const float* vatt_qb = (const float*)d_in[16];
    const float* vatt_oW = (const float*)d_in[17];
    const float* qnet_W = (const float*)d_in[19];
    const float* qnet_b = (const float*)d_in[20];
    const float* vnet_W = (const float*)d_in[21];
    const float* vnet_b = (const float*)d_in[22];
    const float* cls_W1 = (const float*)d_in[23];
    const float* cls_b1 = (const float*)d_in[24];
    const float* cls_W2 = (const float*)d_in[25];
    const float* cls_b2 = (const float*)d_in[26];
    const float* g0_W   = (const float*)d_in[27];
    const float* g0_b   = (const float*)d_in[28];
    const float* g1_W   = (const float*)d_in[29];
    const float* g1_b   = (const float*)d_in[30];
    const float* g2_W   = (const float*)d_in[31];
    const float* g2_b   = (const float*)d_in[32];
    const float* g3_W   = (const float*)d_in[33];
    const float* g3_b   = (const float*)d_in[34];
    const float* f0_W   = (const float*)d_in[35];
    const float* f0_b   = (const float*)d_in[36];
    const float* f1_W   = (const float*)d_in[37];
    const float* f1_b   = (const float*)d_in[38];

    float* out_logits = (float*)d_out;                  // [1536,2001]
    float* out_rec    = (float*)d_out + 1536 * 2001;    // [256,512]

    const size_t FB = 786432;  // 1536*512
    float* zone = (float*)d_ws;
    float* gA    = zone;                        // 4718592
    float* gB    = zone + 4718592;              // 4718592
    float* hid1  = zone + 9437184;              // 1572864 (bf16)
    float* PQb   = zone + 11010048;             // 1572864 (P|Q fp32 [1536,1024])
    float* gsumb = zone + 12582912;             // 131072
    float* f0o   = zone + 12713984;             // 131072
    float* rectb = zone + 12845056;             // 131072
    float* p = zone + 12976128;
    auto alloc = [&](size_t nf) { float* q = p; p += nf; return q; };
    float* hP0   = alloc(FB);       // h_f (bf16 in slot)
    float* hP2   = alloc(FB);       // h_b
    float* joint = alloc(FB);       // bf16
    float* partial = alloc(602112); // 75264*8 fp32
    short* WbfF  = (short*)alloc(851968);   // [2048][832] bf16
    short* WbfB  = (short*)alloc(851968);
    float* biasF = alloc(2048);
    float* biasB = alloc(2048);
    const size_t TOPF = 17645568;
    short* wb = (short*)(zone + TOPF);
    short* projbf = wb;
    short* qWbf   = wb + 524288;
    short* vWbf   = wb + 786432;
    short* qnetbf = wb + 1048576;
    short* vnetbf = wb + 1310720;
    short* cls1bf = wb + 1572864;
    short* cls2bf = wb + 2097152;
    short* wpqbf  = wb + 4146176;
    short* g1bf   = wb + 4670464;
    short* g2bf   = wb + 4932608;
    short* g3bf   = wb + 5194752;
    short* f0bf   = wb + 5456896;
    short* f1bf   = wb + 5719040;
    const size_t WEND = TOPF + 2990592;
    const size_t IMGBF = 19267584;
    const bool useimgbf = ws_size >= (WEND + IMGBF) * sizeof(float);
    short* imgbf = (short*)(zone + WEND);
    // LSTM-phase aliases inside gA (gA only used post-LSTM)
    short* hP1 = (short*)gA;
    short* hP3 = (short*)(gA + FB);
    float* cF  = gA + 2 * FB;
    float* cB  = gA + 3 * FB;
    // post-LSTM aliases
    float* q_emb  = PQb;
    float* swq    = hid1;
    float* q_repr = gA;
    float* v_emb  = gA + FB;

    auto gemm = [&](const float* A1, int lda1, int k1, const short* W1, int ldw1,
                    const float* A2, int lda2, int k2, const short* W2, int ldw2,
                    const float* b1, const float* mv, const float* mulp,
                    float* Cp, int ldc, int M, int N, int relu, int abits, int cbf) {
        if (M >= 4096) {
            dim3 g((N + 63) / 64, (M + 127) / 128);
            hipLaunchKernelGGL(HIP_KERNEL_NAME(mfma_gemm_t<128>), g, dim3(256), 0, stream,
                               A1, lda1, k1, W1, ldw1, A2, lda2, k2, W2, ldw2,
                               b1, mv, mulp, Cp, ldc, M, N, relu, 0, abits, cbf);
        } else {
            dim3 g((N + 63) / 64, (M + 63) / 64);
            hipLaunchKernelGGL(mfma_gemm64_kernel, g, dim3(256), 0, stream,
                               A1, lda1, k1, W1, ldw1, A2, lda2, k2, W2, ldw2,
                               b1, mv, mulp, Cp, ldc, M, N, relu, abits, cbf);
        }
    };

    const int NR = 1536;
    // ---- one-time weight conversions ----
    hipLaunchKernelGGL(lstm_reorder_kernel, dim3(4096), dim3(256), 0, stream,
                       Wih_f, Whh_f, bih_f, bhh_f, WbfF, biasF);
    hipLaunchKernelGGL(lstm_reorder_kernel, dim3(4096), dim3(256), 0, stream,
                       Wih_b, Whh_b, bih_b, bhh_b, WbfB, biasB);
    hipLaunchKernelGGL(wcvt_kernel, dim3(2921), dim3(256), 0, stream,
                       proj_W, vatt_qW, vatt_vW, qnet_W, vnet_W, cls_W1, cls_W2,
                       g0_W, g1_W, g2_W, g3_W, f0_W, f1_W, wb);
    if (useimgbf)
        hipLaunchKernelGGL(imgcvt_kernel, dim3(18816), dim3(256), 0, stream, img, imgbf);

    // ---- bidirectional LSTM: cooperative persistent if co-resident, else 10-step loop ----
    {
        bool coop = false;
        int maxb = 0;
        hipError_t oe = hipOccupancyMaxActiveBlocksPerMultiprocessor(
            &maxb, reinterpret_cast<const void*>(lstm_persist_kernel), 256, 0);
        if (oe == hipSuccess && maxb >= 6) {
            short* a0 = (short*)hP0; short* a1 = hP1;
            short* b0 = (short*)hP2; short* b1 = hP3;
            const short* wf = WbfF; const short* wbk = WbfB;
            const float* bf_ = biasF; const float* bb_ = biasB;
            const float* em = qword; const int* tk = toks;
            float* cf_ = cF; float* cb_ = cB;
            void* args[] = {&a0, &a1, &b0, &b1, &wf, &wbk, &bf_, &bb_, &em, &tk, &cf_, &cb_};
            hipError_t e = hipLaunchCooperativeKernel(
                reinterpret_cast<void*>(lstm_persist_kernel),
                dim3(1536), dim3(256), args, 0, stream);
            coop = (e == hipSuccess);
        }
        if (!coop) {
            short *fi = (short*)hP0, *fo = hP1, *bi = (short*)hP2, *bo = hP3;
            for (int t = 0; t < 10; ++t) {
                hipLaunchKernelGGL(lstm_step4_kernel, dim3(32, 24, 2), dim3(256), 0, stream,
                                   fi, bi, WbfF, WbfB, biasF, biasB, qword, toks, t, 9 - t,
                                   (t == 0) ? 1 : 0, fo, bo, cF, cB);
                short* tmp = fi; fi = fo; fo = tmp;
                tmp = bi; bi = bo; bo = tmp;
            }
        }
    }   // both paths: final h_f in hP0, h_b in hP2 (bf16)

    // q_emb(bf16) = [h_f|h_b] @ proj_W^T + proj_b
    gemm(hP0, 512, 512, projbf, 1024, hP2, 512, 512, projbf + 512, 1024,
         proj_b, nullptr, nullptr, q_emb, 512, NR, 512, 0, 3, 1);
    // swq(fp32) = relu(q_emb @ qW^T + qb) * oW
    gemm(q_emb, 512, 512, qWbf, 512, nullptr, 0, 0, nullptr, 0,
         vatt_qb, vatt_oW, nullptr, swq, 512, NR, 512, 1, 1, 0);
    // attention logits: XCD-swizzled mode-1 grid -> 8-way partials
    hipLaunchKernelGGL(HIP_KERNEL_NAME(mfma_gemm_t<128>), dim3(4704), dim3(256), 0, stream,
                       useimgbf ? (const float*)imgbf : img, 512, 512, vWbf, 512,
                       (const float*)nullptr, 0, 0, (const short*)nullptr, 0,
                       vatt_vb, (const float*)nullptr, swq,
                       partial, 512, 75264, 512, 0, 1, useimgbf ? 1 : 0, 0);
    hipLaunchKernelGGL(attn_vemb_kernel, dim3(1536), dim3(256), 0, stream,
                       partial, img, useimgbf ? imgbf : (const short*)nullptr, v_emb);
    // joint(bf16) = relu(q_emb@qnet^T+b) * relu(v_emb@vnet^T+b)
    gemm(q_emb, 512, 512, qnetbf, 512, nullptr, 0, 0, nullptr, 0,
         qnet_b, nullptr, nullptr, q_repr, 512, NR, 512, 1, 1, 0);
    gemm(v_emb, 512, 512, vnetbf, 512, nullptr, 0, 0, nullptr, 0,
         vnet_b, nullptr, q_repr, joint, 512, NR, 512, 1, 0, 1);
    // classifier
    gemm(joint, 512, 512, cls1bf, 512, nullptr, 0, 0, nullptr, 0,
         cls_b1, nullptr, nullptr, hid1, 1024, NR, 1024, 1, 1, 1);
    gemm(hid1, 1024, 1024, cls2bf, 1024, nullptr, 0, 0, nullptr, 0,
         cls_b2, nullptr, nullptr, out_logits, 2001, NR, 2001, 0, 1, 0);
    // relation network: P|Q in one GEMM (wpq pack), then g-chain
    gemm(joint, 512, 512, wpqbf, 512, nullptr, 0, 0, nullptr, 0,
         nullptr, nullptr, nullptr, PQb, 1024, NR, 1024, 0, 1, 0);
    hipLaunchKernelGGL(g0build_kernel, dim3(18432), dim3(256), 0, stream,
                       PQb, g0_b, (short*)gA);
    gemm(gA, 512, 512, g1bf, 512, nullptr, 0, 0, nullptr, 0,
         g1_b, nullptr, nullptr, gB, 512, 9216, 512, 1, 1, 1);
    gemm(gB, 512, 512, g2bf, 512, nullptr, 0, 0, nullptr, 0,
         g2_b, nullptr, nullptr, gA, 512, 9216, 512, 1, 1, 1);
    gemm(gA, 512, 512, g3bf, 512, nullptr, 0, 0, nullptr, 0,
         g3_b, nullptr, nullptr, gB, 512, 9216, 512, 1, 1, 1);
    hipLaunchKernelGGL(gsum_kernel, dim3(512), dim3(256), 0, stream, (const short*)gB, gsumb);
    gemm(gsumb, 512, 512, f0bf, 512, nullptr, 0, 0, nullptr, 0,
         f0_b, nullptr, nullptr, f0o, 512, 256, 512, 1, 0, 0);
    gemm(f0o, 512, 512, f1bf, 512, nullptr, 0, 0, nullptr, 0,
         f1_b, nullptr, nullptr, rectb, 512, 256, 512, 0, 0, 0);
    hipLaunchKernelGGL(l2norm_kernel, dim3(256), dim3(256), 0, stream, rectb, out_rec);
}

// Round 14
// 787.508 us; speedup vs baseline: 1.2872x; 1.0493x over previous
//
#include <hip/hip_runtime.h>
#include <hip/hip_bf16.h>
#include <math.h>

typedef __attribute__((ext_vector_type(8))) short short8;
typedef __attribute__((ext_vector_type(4))) float f32x4;

#define KTILE 32
#define LSTR 40    // KT=32 legacy paths: LDS row stride (bf16 elems)
#define LSTR64 72  // KT=64 reg-staged path

__device__ __forceinline__ short8 cvt8(const float* x) {
    short8 r;
#pragma unroll
    for (int i = 0; i < 8; ++i) {
        __hip_bfloat16 b = __float2bfloat16(x[i]);
        r[i] = *reinterpret_cast<const short*>(&b);
    }
    return r;
}
__device__ __forceinline__ float bf2f(short s) {
    unsigned int u = ((unsigned int)(unsigned short)s) << 16;
    return __uint_as_float(u);
}
// direct global->LDS, 16 B per lane; lds dest = base + lane*16 (wave-uniform base)
__device__ __forceinline__ void gload16(const void* g, void* l) {
    __builtin_amdgcn_global_load_lds(
        (const __attribute__((address_space(1))) unsigned int*)g,
        (__attribute__((address_space(3))) unsigned int*)l, 16, 0, 0);
}

// ---------------- MFMA GEMM, BM x 64 tile, KT=32 (large-M mode0 + attn fp32 fallback mode1) ----------------
template<int BM>
__global__ __launch_bounds__(256)
void mfma_gemm_t(const float* __restrict__ A1f, int lda1, int k1,
                 const short* __restrict__ W1, int ldw1,
                 const float* __restrict__ A2f, int lda2, int k2,
                 const short* __restrict__ W2, int ldw2,
                 const float* __restrict__ bias1,
                 const float* __restrict__ mulvec, const float* __restrict__ mul,
                 float* __restrict__ C, int ldc, int M, int N,
                 int do_relu, int mode, int abits, int c_bf16)
{
    __shared__ short sA[2][BM][LSTR];
    __shared__ short sB[2][64][LSTR];
    __shared__ float sred[BM][2];
    constexpr int MF = BM / 32;

    const int tid = threadIdx.x;
    int m0, n0, ch8 = 0;
    if (mode == 1) {
        const int xcd = blockIdx.x & 7;
        const int gi = xcd * 588 + (blockIdx.x >> 3);
        m0 = (gi >> 3) << 7;
        ch8 = gi & 7;
        n0 = ch8 << 6;
    } else {
        m0 = blockIdx.y * BM;
        n0 = blockIdx.x << 6;
    }
    const short* A1b = (const short*)A1f;
    const short* A2b = (const short*)A2f;
    const int Ktot = k1 + k2;
    const int nt = (Ktot + KTILE - 1) / KTILE;
    const int lane = tid & 63, wave = tid >> 6;
    const int wr = (wave >> 1) * (BM >> 1);
    const int wc = (wave & 1) << 5;
    const int l15 = lane & 15, lh = lane >> 4;
    const int rowA = (BM == 128) ? (tid >> 1) : (tid >> 2);
    const int kA   = (BM == 128) ? ((tid & 1) << 4) : ((tid & 3) << 3);
    const int rgA = min(m0 + rowA, M - 1);
    const int rowW = tid >> 2, kW = (tid & 3) << 3;
    const int ngW = min(n0 + rowW, N - 1);

    f32x4 acc[MF][2];
#pragma unroll
    for (int m = 0; m < MF; ++m)
#pragma unroll
        for (int n = 0; n < 2; ++n) acc[m][n] = (f32x4){0.f, 0.f, 0.f, 0.f};

    short8 aS0, aS1, wS;
    auto loadA = [&](int t) {
        constexpr int AE = (BM == 128) ? 16 : 8;
        const int k0 = t * KTILE + kA;
        if (k0 + AE <= k1) {
            if (abits & 1) {
                const short* p = A1b + (size_t)rgA * lda1 + k0;
                aS0 = *(const short8*)p;
                if constexpr (BM == 128) aS1 = *(const short8*)(p + 8);
            } else {
                const float* p = A1f + (size_t)rgA * lda1 + k0;
                float4 v0 = *(const float4*)p, v1 = *(const float4*)(p + 4);
                float t0[8] = {v0.x, v0.y, v0.z, v0.w, v1.x, v1.y, v1.z, v1.w};
                aS0 = cvt8(t0);
                if constexpr (BM == 128) {
                    float4 v2 = *(const float4*)(p + 8), v3 = *(const float4*)(p + 12);
                    float t1[8] = {v2.x, v2.y, v2.z, v2.w, v3.x, v3.y, v3.z, v3.w};
                    aS1 = cvt8(t1);
                }
            }
        } else if (k0 >= k1 && k0 + AE <= Ktot) {
            const int kk = k0 - k1;
            if (abits & 2) {
                const short* p = A2b + (size_t)rgA * lda2 + kk;
                aS0 = *(const short8*)p;
                if constexpr (BM == 128) aS1 = *(const short8*)(p + 8);
            } else {
                const float* p = A2f + (size_t)rgA * lda2 + kk;
                float4 v0 = *(const float4*)p, v1 = *(const float4*)(p + 4);
                float t0[8] = {v0.x, v0.y, v0.z, v0.w, v1.x, v1.y, v1.z, v1.w};
                aS0 = cvt8(t0);
                if constexpr (BM == 128) {
                    float4 v2 = *(const float4*)(p + 8), v3 = *(const float4*)(p + 12);
                    float t1[8] = {v2.x, v2.y, v2.z, v2.w, v3.x, v3.y, v3.z, v3.w};
                    aS1 = cvt8(t1);
                }
            }
        } else {
            float tmp[(BM == 128) ? 16 : 8];
#pragma unroll
            for (int e = 0; e < ((BM == 128) ? 16 : 8); ++e) {
                const int kg = k0 + e;
                float v = 0.f;
                if (kg < k1) v = (abits & 1) ? bf2f(A1b[(size_t)rgA * lda1 + kg]) : A1f[(size_t)rgA * lda1 + kg];
                else if (kg < Ktot) v = (abits & 2) ? bf2f(A2b[(size_t)rgA * lda2 + (kg - k1)]) : A2f[(size_t)rgA * lda2 + (kg - k1)];
                tmp[e] = v;
            }
            aS0 = cvt8(tmp);
            if constexpr (BM == 128) aS1 = cvt8(tmp + 8);
        }
    };
    auto loadW = [&](int t) {
        const int k0 = t * KTILE + kW;
        if (k0 + 8 <= k1) {
            wS = *(const short8*)&W1[(size_t)ngW * ldw1 + k0];
        } else if (k0 >= k1 && k0 + 8 <= Ktot) {
            wS = *(const short8*)&W2[(size_t)ngW * ldw2 + (k0 - k1)];
        } else {
            short8 w;
#pragma unroll
            for (int e = 0; e < 8; ++e) {
                const int kg = k0 + e;
                w[e] = (kg < k1) ? W1[(size_t)ngW * ldw1 + kg]
                                 : ((kg < Ktot) ? W2[(size_t)ngW * ldw2 + (kg - k1)] : (short)0);
            }
            wS = w;
        }
    };
    auto writeS = [&](int buf) {
        *(short8*)&sA[buf][rowA][kA] = aS0;
        if constexpr (BM == 128) *(short8*)&sA[buf][rowA][kA + 8] = aS1;
        *(short8*)&sB[buf][rowW][kW] = wS;
    };

    loadA(0); loadW(0); writeS(0);
    __syncthreads();
    for (int t = 0; t < nt; ++t) {
        const int cur = t & 1;
        if (t + 1 < nt) { loadA(t + 1); loadW(t + 1); }
        short8 af[MF], bfv[2];
#pragma unroll
        for (int m = 0; m < MF; ++m)
            af[m] = *(const short8*)&sA[cur][wr + (m << 4) + l15][lh << 3];
#pragma unroll
        for (int n = 0; n < 2; ++n)
            bfv[n] = *(const short8*)&sB[cur][wc + (n << 4) + l15][lh << 3];
#pragma unroll
        for (int m = 0; m < MF; ++m)
#pragma unroll
            for (int n = 0; n < 2; ++n)
                acc[m][n] = __builtin_amdgcn_mfma_f32_16x16x32_bf16(af[m], bfv[n], acc[m][n], 0, 0, 0);
        if (t + 1 < nt) writeS(cur ^ 1);
        __syncthreads();
    }

    if (mode == 0) {
#pragma unroll
        for (int m = 0; m < MF; ++m) {
#pragma unroll
            for (int j = 0; j < 4; ++j) {
                const int r = m0 + wr + (m << 4) + (lh << 2) + j;
                if (r >= M) continue;
#pragma unroll
                for (int n = 0; n < 2; ++n) {
                    const int c = n0 + wc + (n << 4) + l15;
                    if (c >= N) continue;
                    float v = acc[m][n][j];
                    if (bias1) v += bias1[c];
                    if (do_relu) v = fmaxf(v, 0.f);
                    if (mulvec) v *= mulvec[c];
                    if (mul) v *= mul[(size_t)r * ldc + c];
                    if (c_bf16) {
                        __hip_bfloat16 b = __float2bfloat16(v);
                        ((short*)C)[(size_t)r * ldc + c] = *(short*)&b;
                    } else {
                        C[(size_t)r * ldc + c] = v;
                    }
                }
            }
        }
    } else {
#pragma unroll
        for (int m = 0; m < MF; ++m) {
#pragma unroll
            for (int j = 0; j < 4; ++j) {
                const int rloc = wr + (m << 4) + (lh << 2) + j;
                const int r = m0 + rloc;
                const size_t sqbase = (size_t)(r / 49) * ldc;
                float s = 0.f;
#pragma unroll
                for (int n = 0; n < 2; ++n) {
                    const int c = n0 + wc + (n << 4) + l15;
                    float v = acc[m][n][j] + bias1[c];
                    v = fmaxf(v, 0.f);
                    s += v * mul[sqbase + c];
                }
                s += __shfl_xor(s, 1, 64);
                s += __shfl_xor(s, 2, 64);
                s += __shfl_xor(s, 4, 64);
                s += __shfl_xor(s, 8, 64);
                if (l15 == 0) sred[rloc][wc >> 5] = s;
            }
        }
        __syncthreads();
        if (tid < BM)
            C[(size_t)(m0 + tid) * 8 + ch8] = sred[tid][0] + sred[tid][1];
    }
}

// ---------------- attn logits, 128x64 tile, KT=64, global_load_lds + XOR swizzle ----------------
// A = imgbf bf16 [75264][512], W = vWbf bf16 [512][512]. LDS linear; source chunk
// pre-swizzled (c = pos ^ (row&7)); reads apply the same XOR -> conflict-free.
__global__ __launch_bounds__(256)
void attn_logits3_kernel(const short* __restrict__ imgb, const short* __restrict__ vW,
                         const float* __restrict__ vb, const float* __restrict__ swq,
                         float* __restrict__ partial)
{
    __shared__ short sA[2][128][64];
    __shared__ short sB[2][64][64];
    __shared__ float sred[128][2];
    const int tid = threadIdx.x;
    const int lane = tid & 63, wave = tid >> 6;
    const int xcd = blockIdx.x & 7;
    const int gi = xcd * 588 + (blockIdx.x >> 3);
    const int m0 = (gi >> 3) << 7;
    const int ch8 = gi & 7;
    const int n0 = ch8 << 6;
    const int wr = (wave >> 1) << 6;  // 0/64
    const int wc = (wave & 1) << 5;   // 0/32
    const int l15 = lane & 15, lh = lane >> 4;
    const int lr = lane >> 3;         // staging: row within 8-row chunk
    const int sc = (lane & 7) ^ lr;   // staging: pre-swizzled source chunk

    f32x4 acc[4][2];
#pragma unroll
    for (int m = 0; m < 4; ++m)
#pragma unroll
        for (int n = 0; n < 2; ++n) acc[m][n] = (f32x4){0.f, 0.f, 0.f, 0.f};

    auto stage = [&](int t, int buf) {
        const int kb = t << 6;
#pragma unroll
        for (int j = 0; j < 4; ++j) {        // A: rows 32*wave + 8j
            const int r0 = (wave << 5) + (j << 3);
            const int grow = m0 + r0 + lr;
            gload16(imgb + (size_t)grow * 512 + kb + (sc << 3), &sA[buf][r0][0]);
        }
#pragma unroll
        for (int j = 0; j < 2; ++j) {        // W: rows 16*wave + 8j
            const int r0 = (wave << 4) + (j << 3);
            const int grow = n0 + r0 + lr;
            gload16(vW + (size_t)grow * 512 + kb + (sc << 3), &sB[buf][r0][0]);
        }
    };

    stage(0, 0);
    __syncthreads();
    for (int t = 0; t < 8; ++t) {
        const int cur = t & 1;
        if (t + 1 < 8) stage(t + 1, cur ^ 1);
#pragma unroll
        for (int kk = 0; kk < 2; ++kk) {
            const int rd = (((kk << 2) + lh) ^ (l15 & 7)) << 3;
            short8 af[4], bfv[2];
#pragma unroll
            for (int m = 0; m < 4; ++m)
                af[m] = *(const short8*)&sA[cur][wr + (m << 4) + l15][rd];
#pragma unroll
            for (int n = 0; n < 2; ++n)
                bfv[n] = *(const short8*)&sB[cur][wc + (n << 4) + l15][rd];
#pragma unroll
            for (int m = 0; m < 4; ++m)
#pragma unroll
                for (int n = 0; n < 2; ++n)
                    acc[m][n] = __builtin_amdgcn_mfma_f32_16x16x32_bf16(af[m], bfv[n], acc[m][n], 0, 0, 0);
        }
        __syncthreads();
    }

#pragma unroll
    for (int m = 0; m < 4; ++m) {
#pragma unroll
        for (int j = 0; j < 4; ++j) {
            const int rloc = wr + (m << 4) + (lh << 2) + j;
            const int r = m0 + rloc;
            const size_t sqbase = (size_t)(r / 49) * 512;
            float s = 0.f;
#pragma unroll
            for (int n = 0; n < 2; ++n) {
                const int c = n0 + wc + (n << 4) + l15;
                float v = acc[m][n][j] + vb[c];
                v = fmaxf(v, 0.f);
                s += v * swq[sqbase + c];
            }
            s += __shfl_xor(s, 1, 64);
            s += __shfl_xor(s, 2, 64);
            s += __shfl_xor(s, 4, 64);
            s += __shfl_xor(s, 8, 64);
            if (l15 == 0) sred[rloc][wc >> 5] = s;
        }
    }
    __syncthreads();
    if (tid < 128)
        partial[(size_t)(m0 + tid) * 8 + ch8] = sred[tid][0] + sred[tid][1];
}

// ---------------- MFMA GEMM, 64x64 tile, KT=64 (small-M path, reg-staged) ----------------
__global__ __launch_bounds__(256)
void mfma_gemm64_kernel(const float* __restrict__ A1f, int lda1, int k1,
                        const short* __restrict__ W1, int ldw1,
                        const float* __restrict__ A2f, int lda2, int k2,
                        const short* __restrict__ W2, int ldw2,
                        const float* __restrict__ bias1,
                        const float* __restrict__ mulvec, const float* __restrict__ mul,
                        float* __restrict__ C, int ldc, int M, int N,
                        int do_relu, int abits, int c_bf16)
{
    __shared__ short sA[2][64][LSTR64];
    __shared__ short sB[2][64][LSTR64];
    const int tid = threadIdx.x;
    const int m0 = blockIdx.y << 6, n0 = blockIdx.x << 6;
    const short* A1b = (const short*)A1f;
    const short* A2b = (const short*)A2f;
    const int Ktot = k1 + k2;
    const int nt = (Ktot + 63) >> 6;
    const int lane = tid & 63, wave = tid >> 6;
    const int wr = (wave >> 1) << 5, wc = (wave & 1) << 5;
    const int l15 = lane & 15, lh = lane >> 4;
    const int srow = tid >> 2, skq = (tid & 3) << 4;
    const int rgA = min(m0 + srow, M - 1);
    const int ngW = min(n0 + srow, N - 1);

    f32x4 acc[2][2];
#pragma unroll
    for (int m = 0; m < 2; ++m)
#pragma unroll
        for (int n = 0; n < 2; ++n) acc[m][n] = (f32x4){0.f, 0.f, 0.f, 0.f};

    short8 aS0, aS1, wS0, wS1;
    auto loadA = [&](int t) {
        const int k0 = (t << 6) + skq;
        if (k0 + 16 <= k1) {
            if (abits & 1) {
                const short* p = A1b + (size_t)rgA * lda1 + k0;
                aS0 = *(const short8*)p; aS1 = *(const short8*)(p + 8);
            } else {
                const float* p = A1f + (size_t)rgA * lda1 + k0;
                float4 v0 = *(const float4*)p, v1 = *(const float4*)(p + 4);
                float4 v2 = *(const float4*)(p + 8), v3 = *(const float4*)(p + 12);
                float t0[8] = {v0.x, v0.y, v0.z, v0.w, v1.x, v1.y, v1.z, v1.w};
                float t1[8] = {v2.x, v2.y, v2.z, v2.w, v3.x, v3.y, v3.z, v3.w};
                aS0 = cvt8(t0); aS1 = cvt8(t1);
            }
        } else if (k0 >= k1 && k0 + 16 <= Ktot) {
            const int kk = k0 - k1;
            if (abits & 2) {
                const short* p = A2b + (size_t)rgA * lda2 + kk;
                aS0 = *(const short8*)p; aS1 = *(const short8*)(p + 8);
            } else {
                const float* p = A2f + (size_t)rgA * lda2 + kk;
                float4 v0 = *(const float4*)p, v1 = *(const float4*)(p + 4);
                float4 v2 = *(const float4*)(p + 8), v3 = *(const float4*)(p + 12);
                float t0[8] = {v0.x, v0.y, v0.z, v0.w, v1.x, v1.y, v1.z, v1.w};
                float t1[8] = {v2.x, v2.y, v2.z, v2.w, v3.x, v3.y, v3.z, v3.w};
                aS0 = cvt8(t0); aS1 = cvt8(t1);
            }
        } else {
            float tmp[16];
#pragma unroll
            for (int e = 0; e < 16; ++e) {
                const int kg = k0 + e;
                float v = 0.f;
                if (kg < k1) v = (abits & 1) ? bf2f(A1b[(size_t)rgA * lda1 + kg]) : A1f[(size_t)rgA * lda1 + kg];
                else if (kg < Ktot) v = (abits & 2) ? bf2f(A2b[(size_t)rgA * lda2 + (kg - k1)]) : A2f[(size_t)rgA * lda2 + (kg - k1)];
                tmp[e] = v;
            }
            aS0 = cvt8(tmp); aS1 = cvt8(tmp + 8);
        }
    };
    auto loadW = [&](int t) {
        const int k0 = (t << 6) + skq;
        if (k0 + 16 <= k1) {
            const short* p = W1 + (size_t)ngW * ldw1 + k0;
            wS0 = *(const short8*)p; wS1 = *(const short8*)(p + 8);
        } else if (k0 >= k1 && k0 + 16 <= Ktot) {
            const short* p = W2 + (size_t)ngW * ldw2 + (k0 - k1);
            wS0 = *(const short8*)p; wS1 = *(const short8*)(p + 8);
        } else {
            short8 w0, w1;
#pragma unroll
            for (int e = 0; e < 16; ++e) {
                const int kg = k0 + e;
                short v = (kg < k1) ? W1[(size_t)ngW * ldw1 + kg]
                                    : ((kg < Ktot) ? W2[(size_t)ngW * ldw2 + (kg - k1)] : (short)0);
                if (e < 8) w0[e] = v; else w1[e - 8] = v;
            }
            wS0 = w0; wS1 = w1;
        }
    };
    auto writeS = [&](int buf) {
        *(short8*)&sA[buf][srow][skq] = aS0;
        *(short8*)&sA[buf][srow][skq + 8] = aS1;
        *(short8*)&sB[buf][srow][skq] = wS0;
        *(short8*)&sB[buf][srow][skq + 8] = wS1;
    };

    loadA(0); loadW(0); writeS(0);
    __syncthreads();
    for (int t = 0; t < nt; ++t) {
        const int cur = t & 1;
        if (t + 1 < nt) { loadA(t + 1); loadW(t + 1); }
#pragma unroll
        for (int kk = 0; kk < 2; ++kk) {
            short8 af[2], bfv[2];
#pragma unroll
            for (int m = 0; m < 2; ++m)
                af[m] = *(const short8*)&sA[cur][wr + (m << 4) + l15][(kk << 5) + (lh << 3)];
#pragma unroll
            for (int n = 0; n < 2; ++n)
                bfv[n] = *(const short8*)&sB[cur][wc + (n << 4) + l15][(kk << 5) + (lh << 3)];
#pragma unroll
            for (int m = 0; m < 2; ++m)
#pragma unroll
                for (int n = 0; n < 2; ++n)
                    acc[m][n] = __builtin_amdgcn_mfma_f32_16x16x32_bf16(af[m], bfv[n], acc[m][n], 0, 0, 0);
        }
        if (t + 1 < nt) writeS(cur ^ 1);
        __syncthreads();
    }

#pragma unroll
    for (int m = 0; m < 2; ++m) {
#pragma unroll
        for (int j = 0; j < 4; ++j) {
            const int r = m0 + wr + (m << 4) + (lh << 2) + j;
            if (r >= M) continue;
#pragma unroll
            for (int n = 0; n < 2; ++n) {
                const int c = n0 + wc + (n << 4) + l15;
                if (c >= N) continue;
                float v = acc[m][n][j];
                if (bias1) v += bias1[c];
                if (do_relu) v = fmaxf(v, 0.f);
                if (mulvec) v *= mulvec[c];
                if (mul) v *= mul[(size_t)r * ldc + c];
                if (c_bf16) {
                    __hip_bfloat16 b = __float2bfloat16(v);
                    ((short*)C)[(size_t)r * ldc + c] = *(short*)&b;
                } else {
                    C[(size_t)r * ldc + c] = v;
                }
            }
        }
    }
}

// ---------------- weight bf16 pre-conversion ----------------
__global__ __launch_bounds__(256)
void wcvt_kernel(const float* __restrict__ proj, const float* __restrict__ qW,
                 const float* __restrict__ vW, const float* __restrict__ qnet,
                 const float* __restrict__ vnet, const float* __restrict__ cls1,
                 const float* __restrict__ cls2, const float* __restrict__ g0,
                 const float* __restrict__ g1, const float* __restrict__ g2,
                 const float* __restrict__ g3, const float* __restrict__ f0,
                 const float* __restrict__ f1, short* __restrict__ dst)
{
    size_t idx = ((size_t)blockIdx.x * 256 + threadIdx.x) * 8;
    if (idx >= 5981184) return;
    const float* s;
    if (idx < 524288) s = proj + idx;
    else if (idx < 786432) s = qW + (idx - 524288);
    else if (idx < 1048576) s = vW + (idx - 786432);
    else if (idx < 1310720) s = qnet + (idx - 1048576);
    else if (idx < 1572864) s = vnet + (idx - 1310720);
    else if (idx < 2097152) s = cls1 + (idx - 1572864);
    else if (idx < 4146176) s = cls2 + (idx - 2097152);
    else if (idx < 4670464) {
        size_t li = idx - 4146176;
        int c = (int)(li >> 9), k = (int)(li & 511);
        s = (c < 512) ? g0 + (size_t)c * 1024 + k
                      : g0 + (size_t)(c - 512) * 1024 + 512 + k;
    }
    else if (idx < 4932608) s = g1 + (idx - 4670464);
    else if (idx < 5194752) s = g2 + (idx - 4932608);
    else if (idx < 5456896) s = g3 + (idx - 5194752);
    else if (idx < 5719040) s = f0 + (idx - 5456896);
    else s = f1 + (idx - 5719040);
    float4 a = *(const float4*)s, b = *(const float4*)(s + 4);
    float t[8] = {a.x, a.y, a.z, a.w, b.x, b.y, b.z, b.w};
    *(short8*)(dst + idx) = cvt8(t);
}

// ---------------- LSTM weight reorder ([2048][832] bf16, gate-permuted) ----------------
__global__ __launch_bounds__(256)
void lstm_reorder_kernel(const float* __restrict__ Wih, const float* __restrict__ Whh,
                         const float* __restrict__ bih, const float* __restrict__ bhh,
                         short* __restrict__ Wbf, float* __restrict__ bias_perm)
{
    int id = blockIdx.x * 256 + threadIdx.x;   // < 2048*512
    int c = id >> 9, k = id & 511;
    int src = (c & 3) * 512 + (c >> 2);
    {
        __hip_bfloat16 b = __float2bfloat16(Whh[(size_t)src * 512 + k]);
        Wbf[(size_t)c * 832 + k] = *(short*)&b;
    }
    if (k < 300) {
        __hip_bfloat16 b = __float2bfloat16(Wih[(size_t)src * 300 + k]);
        Wbf[(size_t)c * 832 + 512 + k] = *(short*)&b;
    } else if (k < 320) {
        Wbf[(size_t)c * 832 + 512 + k] = 0;
    }
    if (k == 0) bias_perm[c] = bih[src] + bhh[src];
}

// padded bf16 embedding table: embp[10000][320] (cols 300..319 = 0)
__global__ __launch_bounds__(256)
void embcvt_kernel(const float* __restrict__ qword, short* __restrict__ embp)
{
    int id = blockIdx.x * 256 + threadIdx.x;   // < 3,200,000
    if (id >= 3200000) return;
    int r = id / 320, c = id % 320;
    float v = (c < 300) ? qword[(size_t)r * 300 + c] : 0.f;
    __hip_bfloat16 b = __float2bfloat16(v);
    embp[id] = *(short*)&b;
}

// ---------------- LSTM step, 64x64, KT=64, global_load_lds + XOR swizzle ----------------
// All-bf16 staging: h (tiles 0..7) + embp gather (tiles 8..12); W = Wbf [2048][832].
__global__ __launch_bounds__(256)
void lstm_step6_kernel(const short* __restrict__ hF_in, const short* __restrict__ hB_in,
                       const short* __restrict__ WbfF, const short* __restrict__ WbfB,
                       const float* __restrict__ biasF, const float* __restrict__ biasB,
                       const short* __restrict__ embp, const int* __restrict__ toks,
                       int tF, int tB, int first,
                       short* __restrict__ hF_out, short* __restrict__ hB_out,
                       float* __restrict__ cF, float* __restrict__ cB)
{
    __shared__ short sA[2][64][64];
    __shared__ short sB[2][64][64];
    const int dir = blockIdx.z;
    const short* h_in = dir ? hB_in : hF_in;
    const short* Wbf  = dir ? WbfB : WbfF;
    const float* bias_perm = dir ? biasB : biasF;
    short* h_out  = dir ? hB_out : hF_out;
    float* cstate = dir ? cB : cF;
    const int tt = dir ? tB : tF;

    const int tid = threadIdx.x;
    const int m0 = blockIdx.y << 6;
    const int n0 = blockIdx.x << 6;
    const int lane = tid & 63, wave = tid >> 6;
    const int wr = (wave >> 1) << 5, wc = (wave & 1) << 5;
    const int l15 = lane & 15, lh = lane >> 4;
    const int lr = lane >> 3;
    const int sc = (lane & 7) ^ lr;

    f32x4 acc[2][2];
#pragma unroll
    for (int m = 0; m < 2; ++m)
#pragma unroll
        for (int n = 0; n < 2; ++n) acc[m][n] = (f32x4){0.f, 0.f, 0.f, 0.f};

    auto stage = [&](int t, int buf) {
#pragma unroll
        for (int j = 0; j < 2; ++j) {        // A rows 16*wave + 8j
            const int r0 = (wave << 4) + (j << 3);
            const int grow = m0 + r0 + lr;
            const short* g;
            if (t < 8) {
                g = h_in + (size_t)grow * 512 + (t << 6) + (sc << 3);
            } else {
                const int ar = toks[grow * 10 + tt];
                g = embp + (size_t)ar * 320 + ((t - 8) << 6) + (sc << 3);
            }
            gload16(g, &sA[buf][r0][0]);
        }
#pragma unroll
        for (int j = 0; j < 2; ++j) {        // W rows 16*wave + 8j
            const int r0 = (wave << 4) + (j << 3);
            const int grow = n0 + r0 + lr;
            gload16(Wbf + (size_t)grow * 832 + (t << 6) + (sc << 3), &sB[buf][r0][0]);
        }
    };

    stage(0, 0);
    __syncthreads();
    for (int t = 0; t < 13; ++t) {
        const int cur = t & 1;
        if (t + 1 < 13) stage(t + 1, cur ^ 1);
#pragma unroll
        for (int kk = 0; kk < 2; ++kk) {
            const int rd = (((kk << 2) + lh) ^ (l15 & 7)) << 3;
            short8 af[2], bfv[2];
#pragma unroll
            for (int m = 0; m < 2; ++m)
                af[m] = *(const short8*)&sA[cur][wr + (m << 4) + l15][rd];
#pragma unroll
            for (int n = 0; n < 2; ++n)
                bfv[n] = *(const short8*)&sB[cur][wc + (n << 4) + l15][rd];
#pragma unroll
            for (int m = 0; m < 2; ++m)
#pragma unroll
                for (int n = 0; n < 2; ++n)
                    acc[m][n] = __builtin_amdgcn_mfma_f32_16x16x32_bf16(af[m], bfv[n], acc[m][n], 0, 0, 0);
        }
        __syncthreads();
    }

    // fused cell epilogue: lanes base..base+3 hold i,f,g,o of unit ccol>>2
#pragma unroll
    for (int n = 0; n < 2; ++n) {
        const int ccol = n0 + wc + (n << 4) + l15;
        const float bb = bias_perm[ccol];
        const int u = ccol >> 2;
#pragma unroll
        for (int m = 0; m < 2; ++m) {
#pragma unroll
            for (int j = 0; j < 4; ++j) {
                const int r = m0 + wr + (m << 4) + (lh << 2) + j;
                float v = acc[m][n][j] + bb;
                const int base = lane & ~3;
                float gi = __shfl(v, base, 64);
                float gf = __shfl(v, base | 1, 64);
                float gg = __shfl(v, base | 2, 64);
                float go = __shfl(v, base | 3, 64);
                if ((lane & 3) == 0) {
                    float si = 1.f / (1.f + expf(-gi));
                    float sf = 1.f / (1.f + expf(-gf));
                    float so = 1.f / (1.f + expf(-go));
                    size_t idx = ((size_t)r << 9) + u;
                    float cold = first ? 0.f : cstate[idx];
                    float cv = sf * cold + si * tanhf(gg);
                    cstate[idx] = cv;
                    float hv = so * tanhf(cv);
                    __hip_bfloat16 b = __float2bfloat16(hv);
                    h_out[idx] = *(short*)&b;
                }
            }
        }
    }
}

// ---------------- fused LSTM step fallback (reg-staged, KT=64) ----------------
__global__ __launch_bounds__(256)
void lstm_step4_kernel(const short* __restrict__ hF_in, const short* __restrict__ hB_in,
                       const short* __restrict__ WbfF, const short* __restrict__ WbfB,
                       const float* __restrict__ biasF, const float* __restrict__ biasB,
                       const float* __restrict__ emb, const int* __restrict__ toks,
                       int tF, int tB, int first,
                       short* __restrict__ hF_out, short* __restrict__ hB_out,
                       float* __restrict__ cF, float* __restrict__ cB)
{
    __shared__ short sA[2][64][LSTR64];
    __shared__ short sB[2][64][LSTR64];
    const int dir = blockIdx.z;
    const short* h_in = dir ? hB_in : hF_in;
    const short* Wbf  = dir ? WbfB : WbfF;
    const float* bias_perm = dir ? biasB : biasF;
    short* h_out  = dir ? hB_out : hF_out;
    float* cstate = dir ? cB : cF;
    const int tt = dir ? tB : tF;

    const int tid = threadIdx.x;
    const int m0 = blockIdx.y << 6;
    const int n0 = blockIdx.x << 6;
    const int lane = tid & 63, wave = tid >> 6;
    const int wr = (wave >> 1) << 5, wc = (wave & 1) << 5;
    const int l15 = lane & 15, lh = lane >> 4;
    const int srow = tid >> 2, skq = (tid & 3) << 4;
    const int rgA = m0 + srow;
    const int ngW = n0 + srow;
    const int nt = 13;
    const int arow = toks[rgA * 10 + tt];

    f32x4 acc[2][2];
#pragma unroll
    for (int m = 0; m < 2; ++m)
#pragma unroll
        for (int n = 0; n < 2; ++n) acc[m][n] = (f32x4){0.f, 0.f, 0.f, 0.f};

    short8 aS0, aS1, wS0, wS1;
    auto loadA = [&](int t) {
        const int k0 = (t << 6) + skq;
        if (k0 + 16 <= 512) {
            if (first) { short8 z = {0,0,0,0,0,0,0,0}; aS0 = z; aS1 = z; }
            else {
                const short* p = h_in + (size_t)rgA * 512 + k0;
                aS0 = *(const short8*)p; aS1 = *(const short8*)(p + 8);
            }
        } else if (k0 >= 512 && k0 + 16 <= 812) {
            const float* p = emb + (size_t)arow * 300 + (k0 - 512);
            float4 v0 = *(const float4*)p, v1 = *(const float4*)(p + 4);
            float4 v2 = *(const float4*)(p + 8), v3 = *(const float4*)(p + 12);
            float t0[8] = {v0.x, v0.y, v0.z, v0.w, v1.x, v1.y, v1.z, v1.w};
            float t1[8] = {v2.x, v2.y, v2.z, v2.w, v3.x, v3.y, v3.z, v3.w};
            aS0 = cvt8(t0); aS1 = cvt8(t1);
        } else {
            float tmp[16];
#pragma unroll
            for (int e = 0; e < 16; ++e) {
                const int kg = k0 + e;
                float v = 0.f;
                if (kg < 512) v = first ? 0.f : bf2f(h_in[(size_t)rgA * 512 + kg]);
                else if (kg < 812) v = emb[(size_t)arow * 300 + (kg - 512)];
                tmp[e] = v;
            }
            aS0 = cvt8(tmp); aS1 = cvt8(tmp + 8);
        }
    };
    auto loadW = [&](int t) {
        const short* p = Wbf + (size_t)ngW * 832 + (t << 6) + skq;
        wS0 = *(const short8*)p; wS1 = *(const short8*)(p + 8);
    };
    auto writeS = [&](int buf) {
        *(short8*)&sA[buf][srow][skq] = aS0;
        *(short8*)&sA[buf][srow][skq + 8] = aS1;
        *(short8*)&sB[buf][srow][skq] = wS0;
        *(short8*)&sB[buf][srow][skq + 8] = wS1;
    };

    loadA(0); loadW(0); writeS(0);
    __syncthreads();
    for (int t = 0; t < nt; ++t) {
        const int cur = t & 1;
        if (t + 1 < nt) { loadA(t + 1); loadW(t + 1); }
#pragma unroll
        for (int kk = 0; kk < 2; ++kk) {
            short8 af[2], bfv[2];
#pragma unroll
            for (int m = 0; m < 2; ++m)
                af[m] = *(const short8*)&sA[cur][wr + (m << 4) + l15][(kk << 5) + (lh << 3)];
#pragma unroll
            for (int n = 0; n < 2; ++n)
                bfv[n] = *(const short8*)&sB[cur][wc + (n << 4) + l15][(kk << 5) + (lh << 3)];
#pragma unroll
            for (int m = 0; m < 2; ++m)
#pragma unroll
                for (int n = 0; n < 2; ++n)
                    acc[m][n] = __builtin_amdgcn_mfma_f32_16x16x32_bf16(af[m], bfv[n], acc[m][n], 0, 0, 0);
        }
        if (t + 1 < nt) writeS(cur ^ 1);
        __syncthreads();
    }

#pragma unroll
    for (int n = 0; n < 2; ++n) {
        const int ccol = n0 + wc + (n << 4) + l15;
        const float bb = bias_perm[ccol];
        const int u = ccol >> 2;
#pragma unroll
        for (int m = 0; m < 2; ++m) {
#pragma unroll
            for (int j = 0; j < 4; ++j) {
                const int r = m0 + wr + (m << 4) + (lh << 2) + j;
                float v = acc[m][n][j] + bb;
                const int base = lane & ~3;
                float gi = __shfl(v, base, 64);
                float gf = __shfl(v, base | 1, 64);
                float gg = __shfl(v, base | 2, 64);
                float go = __shfl(v, base | 3, 64);
                if ((lane & 3) == 0) {
                    float si = 1.f / (1.f + expf(-gi));
                    float sf = 1.f / (1.f + expf(-gf));
                    float so = 1.f / (1.f + expf(-go));
                    size_t idx = ((size_t)r << 9) + u;
                    float cold = first ? 0.f : cstate[idx];
                    float cv = sf * cold + si * tanhf(gg);
                    cstate[idx] = cv;
                    float hv = so * tanhf(cv);
                    __hip_bfloat16 b = __float2bfloat16(hv);
                    h_out[idx] = *(short*)&b;
                }
            }
        }
    }
}

// img fp32 -> bf16
__global__ __launch_bounds__(256)
void imgcvt_kernel(const float* __restrict__ img, short* __restrict__ out)
{
    size_t i = ((size_t)blockIdx.x * 256 + threadIdx.x) * 8;
    float4 a = *(const float4*)(img + i), b = *(const float4*)(img + i + 4);
    float t[8] = {a.x, a.y, a.z, a.w, b.x, b.y, b.z, b.w};
    *(short8*)(out + i) = cvt8(t);
}

// softmax over 49 per n from 8-way partials, then v_emb[n,h] = sum_k att[k]*img[n,k,h]
__global__ __launch_bounds__(256)
void attn_vemb_kernel(const float* __restrict__ partial, const float* __restrict__ img,
                      const short* __restrict__ imgb, float* __restrict__ v_emb)
{
    __shared__ float satt[49];
    const int n = blockIdx.x;
    const int tid = threadIdx.x;
    if (tid < 64) {
        float v = -1e30f;
        if (tid < 49) {
            const float* pp = partial + ((size_t)n * 49 + tid) * 8;
            v = ((pp[0] + pp[1]) + (pp[2] + pp[3])) + ((pp[4] + pp[5]) + (pp[6] + pp[7]));
        }
        float m = v;
#pragma unroll
        for (int off = 32; off; off >>= 1) m = fmaxf(m, __shfl_xor(m, off, 64));
        float e = (tid < 49) ? expf(v - m) : 0.f;
        float s = e;
#pragma unroll
        for (int off = 32; off; off >>= 1) s += __shfl_xor(s, off, 64);
        if (tid < 49) satt[tid] = e / s;
    }
    __syncthreads();
    float2 s2 = make_float2(0.f, 0.f);
    if (imgb) {
        const unsigned int* ip = (const unsigned int*)(imgb + (size_t)n * 49 * 512);
        for (int k = 0; k < 49; ++k) {
            unsigned int v = ip[k * 256 + tid];
            float a = satt[k];
            s2.x = fmaf(a, bf2f((short)(v & 0xffff)), s2.x);
            s2.y = fmaf(a, bf2f((short)(v >> 16)), s2.y);
        }
    } else {
        const float2* ip = (const float2*)(img + (size_t)n * 49 * 512);
        for (int k = 0; k < 49; ++k) {
            float2 v = ip[k * 256 + tid];
            float a = satt[k];
            s2.x = fmaf(a, v.x, s2.x);
            s2.y = fmaf(a, v.y, s2.y);
        }
    }
    ((float2*)(v_emb + (size_t)n * 512))[tid] = s2;
}

// g0[b,i,j,c] = relu(PQ[b*6+j, c] + PQ[b*6+i, 512+c] + b0[c]) -> bf16
__global__ __launch_bounds__(256)
void g0build_kernel(const float* __restrict__ PQ, const float* __restrict__ b0,
                    short* __restrict__ g0)
{
    int id = blockIdx.x * 256 + threadIdx.x;
    int cc = id & 511;
    int r = id >> 9;
    int j = r % 6;
    int t = r / 6;
    int i = t % 6;
    int b = t / 6;
    float v = PQ[(size_t)(b * 6 + j) * 1024 + cc] + PQ[(size_t)(b * 6 + i) * 1024 + 512 + cc] + b0[cc];
    v = fmaxf(v, 0.f);
    __hip_bfloat16 h = __float2bfloat16(v);
    g0[id] = *(short*)&h;
}

__global__ __launch_bounds__(256)
void gsum_kernel(const short* __restrict__ g, float* __restrict__ out)
{
    int id = blockIdx.x * 256 + threadIdx.x;
    int b = id >> 9, hh = id & 511;
    const short* p = g + (size_t)b * 36 * 512 + hh;
    float s = 0.f;
#pragma unroll
    for (int i = 0; i < 36; ++i) s += bf2f(p[i * 512]);
    out[id] = s;
}

__global__ __launch_bounds__(256)
void l2norm_kernel(const float* __restrict__ in, float* __restrict__ out)
{
    int b = blockIdx.x;
    int tid = threadIdx.x;
    float v0 = in[(size_t)b * 512 + tid];
    float v1 = in[(size_t)b * 512 + 256 + tid];
    float s = v0 * v0 + v1 * v1;
#pragma unroll
    for (int off = 32; off; off >>= 1) s += __shfl_down(s, off, 64);
    __shared__ float ps[4];
    if ((tid & 63) == 0) ps[tid >> 6] = s;
    __syncthreads();
    float tot = ps[0] + ps[1] + ps[2] + ps[3];
    float inv = 1.f / sqrtf(tot);
    out[(size_t)b * 512 + tid] = v0 * inv;
    out[(size_t)b * 512 + 256 + tid] = v1 * inv;
}

extern "C" void kernel_launch(void* const* d_in, const int* in_sizes, int n_in,
                              void* d_out, int out_size, void* d_ws, size_t ws_size,
                              hipStream_t stream)
{
    (void)in_sizes; (void)n_in; (void)out_size;
    const float* img    = (const float*)d_in[0];
    const int*   toks   = (const int*)d_in[1];
    const float* qword  = (const float*)d_in[2];
    const float* Wih_f  = (const float*)d_in[3];
    const float* Whh_f  = (const float*)d_in[4];
    const float* bih_f  = (const float*)d_in[5];
    const float* bhh_f  = (const float*)d_in[6];
    const float* Wih_b  = (const float*)d_in[7];
    const float* Whh_b  = (const float*)d_in[8];
    const float* bih_b  = (const float*)d_in[9];
    const float* bhh_b  = (const float*)d_in[10];
    const float* proj_W = (const float*)d_in[11];
    const float* proj_b = (const float*)d_in[12];
    const float* vatt_vW = (const float*)d_in[13];
    const float* vatt_vb = (const float*)d_in[14];
    const float* vatt_qW = (const float*)d_in[15];
    const float* vatt_qb = (const float*)d_in[16];
    const float* vatt_oW = (const float*)d_in[17];
    const float* qnet_W = (const float*)d_in[19];
    const float* qnet_b = (const float*)d_in[20];
    const float* vnet_W = (const float*)d_in[21];
    const float* vnet_b = (const float*)d_in[22];
    const float* cls_W1 = (const float*)d_in[23];
    const float* cls_b1 = (const float*)d_in[24];
    const float* cls_W2 = (const float*)d_in[25];
    const float* cls_b2 = (const float*)d_in[26];
    const float* g0_W   = (const float*)d_in[27];
    const float* g0_b   = (const float*)d_in[28];
    const float* g1_W   = (const float*)d_in[29];
    const float* g1_b   = (const float*)d_in[30];
    const float* g2_W   = (const float*)d_in[31];
    const float* g2_b   = (const float*)d_in[32];
    const float* g3_W   = (const float*)d_in[33];
    const float* g3_b   = (const float*)d_in[34];
    const float* f0_W   = (const float*)d_in[35];
    const float* f0_b   = (const float*)d_in[36];
    const float* f1_W   = (const float*)d_in[37];
    const float* f1_b   = (const float*)d_in[38];

    float* out_logits = (float*)d_out;                  // [1536,2001]
    float* out_rec    = (float*)d_out + 1536 * 2001;    // [256,512]

    const size_t FB = 786432;  // 1536*512
    float* zone = (float*)d_ws;
    float* gA    = zone;                        // 4718592
    float* gB    = zone + 4718592;              // 4718592
    float* hid1  = zone + 9437184;              // 1572864 (bf16)
    float* PQb   = zone + 11010048;             // 1572864 (P|Q fp32 [1536,1024])
    float* gsumb = zone + 12582912;             // 131072
    float* f0o   = zone + 12713984;             // 131072
    float* rectb = zone + 12845056;             // 131072
    float* p = zone + 12976128;
    auto alloc = [&](size_t nf) { float* q = p; p += nf; return q; };
    float* hP0   = alloc(FB);       // h_f (bf16 in slot)
    float* hP2   = alloc(FB);       // h_b
    float* joint = alloc(FB);       // bf16
    float* partial = alloc(602112); // 75264*8 fp32
    short* WbfF  = (short*)alloc(851968);   // [2048][832] bf16
    short* WbfB  = (short*)alloc(851968);
    float* biasF = alloc(2048);
    float* biasB = alloc(2048);
    const size_t TOPF = 17645568;
    short* wb = (short*)(zone + TOPF);
    short* projbf = wb;
    short* qWbf   = wb + 524288;
    short* vWbf   = wb + 786432;
    short* qnetbf = wb + 1048576;
    short* vnetbf = wb + 1310720;
    short* cls1bf = wb + 1572864;
    short* cls2bf = wb + 2097152;
    short* wpqbf  = wb + 4146176;
    short* g1bf   = wb + 4670464;
    short* g2bf   = wb + 4932608;
    short* g3bf   = wb + 5194752;
    short* f0bf   = wb + 5456896;
    short* f1bf   = wb + 5719040;
    const size_t WEND = TOPF + 2990592;
    const size_t IMGBF = 19267584;   // floats for img bf16
    const size_t EMBPF = 1600000;    // floats for embp (10000*320 bf16)
    const bool useimgbf = ws_size >= (WEND + IMGBF) * sizeof(float);
    const bool useglds  = ws_size >= (WEND + IMGBF + EMBPF) * sizeof(float);
    short* imgbf = (short*)(zone + WEND);
    short* embp  = (short*)(zone + WEND + IMGBF);
    // LSTM-phase aliases inside gA (gA only used post-LSTM)
    short* hP1 = (short*)gA;
    short* hP3 = (short*)(gA + FB);
    float* cF  = gA + 2 * FB;
    float* cB  = gA + 3 * FB;
    // post-LSTM aliases
    float* q_emb  = PQb;
    float* swq    = hid1;
    float* q_repr = gA;
    float* v_emb  = gA + FB;

    auto gemm = [&](const float* A1, int lda1, int k1, const short* W1, int ldw1,
                    const float* A2, int lda2, int k2, const short* W2, int ldw2,
                    const float* b1, const float* mv, const float* mulp,
                    float* Cp, int ldc, int M, int N, int relu, int abits, int cbf) {
        if (M >= 4096) {
            dim3 g((N + 63) / 64, (M + 127) / 128);
            hipLaunchKernelGGL(HIP_KERNEL_NAME(mfma_gemm_t<128>), g, dim3(256), 0, stream,
                               A1, lda1, k1, W1, ldw1, A2, lda2, k2, W2, ldw2,
                               b1, mv, mulp, Cp, ldc, M, N, relu, 0, abits, cbf);
        } else {
            dim3 g((N + 63) / 64, (M + 63) / 64);
            hipLaunchKernelGGL(mfma_gemm64_kernel, g, dim3(256), 0, stream,
                               A1, lda1, k1, W1, ldw1, A2, lda2, k2, W2, ldw2,
                               b1, mv, mulp, Cp, ldc, M, N, relu, abits, cbf);
        }
    };

    const int NR = 1536;
    // ---- one-time weight conversions ----
    hipLaunchKernelGGL(lstm_reorder_kernel, dim3(4096), dim3(256), 0, stream,
                       Wih_f, Whh_f, bih_f, bhh_f, WbfF, biasF);
    hipLaunchKernelGGL(lstm_reorder_kernel, dim3(4096), dim3(256), 0, stream,
                       Wih_b, Whh_b, bih_b, bhh_b, WbfB, biasB);
    hipLaunchKernelGGL(wcvt_kernel, dim3(2921), dim3(256), 0, stream,
                       proj_W, vatt_qW, vatt_vW, qnet_W, vnet_W, cls_W1, cls_W2,
                       g0_W, g1_W, g2_W, g3_W, f0_W, f1_W, wb);
    if (useimgbf)
        hipLaunchKernelGGL(imgcvt_kernel, dim3(18816), dim3(256), 0, stream, img, imgbf);

    // ---- bidirectional LSTM: glds path (direct-to-LDS) or reg-staged fallback ----
    if (useglds) {
        hipLaunchKernelGGL(embcvt_kernel, dim3(12500), dim3(256), 0, stream, qword, embp);
        hipMemsetAsync(hP0, 0, FB * sizeof(short), stream);
        hipMemsetAsync(hP2, 0, FB * sizeof(short), stream);
        short *fi = (short*)hP0, *fo = hP1, *bi = (short*)hP2, *bo = hP3;
        for (int t = 0; t < 10; ++t) {
            hipLaunchKernelGGL(lstm_step6_kernel, dim3(32, 24, 2), dim3(256), 0, stream,
                               fi, bi, WbfF, WbfB, biasF, biasB, embp, toks, t, 9 - t,
                               (t == 0) ? 1 : 0, fo, bo, cF, cB);
            short* tmp = fi; fi = fo; fo = tmp;
            tmp = bi; bi = bo; bo = tmp;
        }
    } else {
        short *fi = (short*)hP0, *fo = hP1, *bi = (short*)hP2, *bo = hP3;
        for (int t = 0; t < 10; ++t) {
            hipLaunchKernelGGL(lstm_step4_kernel, dim3(32, 24, 2), dim3(256), 0, stream,
                               fi, bi, WbfF, WbfB, biasF, biasB, qword, toks, t, 9 - t,
                               (t == 0) ? 1 : 0, fo, bo, cF, cB);
            short* tmp = fi; fi = fo; fo = tmp;
            tmp = bi; bi = bo; bo = tmp;
        }
    }   // final h_f in hP0, h_b in hP2 (bf16)

    // q_emb(bf16) = [h_f|h_b] @ proj_W^T + proj_b
    gemm(hP0, 512, 512, projbf, 1024, hP2, 512, 512, projbf + 512, 1024,
         proj_b, nullptr, nullptr, q_emb, 512, NR, 512, 0, 3, 1);
    // swq(fp32) = relu(q_emb @ qW^T + qb) * oW
    gemm(q_emb, 512, 512, qWbf, 512, nullptr, 0, 0, nullptr, 0,
         vatt_qb, vatt_oW, nullptr, swq, 512, NR, 512, 1, 1, 0);
    // attention logits -> 8-way partials
    if (useimgbf) {
        hipLaunchKernelGGL(attn_logits3_kernel, dim3(4704), dim3(256), 0, stream,
                           imgbf, vWbf, vatt_vb, swq, partial);
    } else {
        hipLaunchKernelGGL(HIP_KERNEL_NAME(mfma_gemm_t<128>), dim3(4704), dim3(256), 0, stream,
                           img, 512, 512, vWbf, 512,
                           (const float*)nullptr, 0, 0, (const short*)nullptr, 0,
                           vatt_vb, (const float*)nullptr, swq,
                           partial, 512, 75264, 512, 0, 1, 0, 0);
    }
    hipLaunchKernelGGL(attn_vemb_kernel, dim3(1536), dim3(256), 0, stream,
                       partial, img, useimgbf ? imgbf : (const short*)nullptr, v_emb);
    // joint(bf16) = relu(q_emb@qnet^T+b) * relu(v_emb@vnet^T+b)
    gemm(q_emb, 512, 512, qnetbf, 512, nullptr, 0, 0, nullptr, 0,
         qnet_b, nullptr, nullptr, q_repr, 512, NR, 512, 1, 1, 0);
    gemm(v_emb, 512, 512, vnetbf, 512, nullptr, 0, 0, nullptr, 0,
         vnet_b, nullptr, q_repr, joint, 512, NR, 512, 1, 0, 1);
    // classifier
    gemm(joint, 512, 512, cls1bf, 512, nullptr, 0, 0, nullptr, 0,
         cls_b1, nullptr, nullptr, hid1, 1024, NR, 1024, 1, 1, 1);
    gemm(hid1, 1024, 1024, cls2bf, 1024, nullptr, 0, 0, nullptr, 0,
         cls_b2, nullptr, nullptr, out_logits, 2001, NR, 2001, 0, 1, 0);
    // relation network: P|Q in one GEMM (wpq pack), then g-chain
    gemm(joint, 512, 512, wpqbf, 512, nullptr, 0, 0, nullptr, 0,
         nullptr, nullptr, nullptr, PQb, 1024, NR, 1024, 0, 1, 0);
    hipLaunchKernelGGL(g0build_kernel, dim3(18432), dim3(256), 0, stream,
                       PQb, g0_b, (short*)gA);
    gemm(gA, 512, 512, g1bf, 512, nullptr, 0, 0, nullptr, 0,
         g1_b, nullptr, nullptr, gB, 512, 9216, 512, 1, 1, 1);
    gemm(gB, 512, 512, g2bf, 512, nullptr, 0, 0, nullptr, 0,
         g2_b, nullptr, nullptr, gA, 512, 9216, 512, 1, 1, 1);
    gemm(gA, 512, 512, g3bf, 512, nullptr, 0, 0, nullptr, 0,
         g3_b, nullptr, nullptr, gB, 512, 9216, 512, 1, 1, 1);
    hipLaunchKernelGGL(gsum_kernel, dim3(512), dim3(256), 0, stream, (const short*)gB, gsumb);
    gemm(gsumb, 512, 512, f0bf, 512, nullptr, 0, 0, nullptr, 0,
         f0_b, nullptr, nullptr, f0o, 512, 256, 512, 1, 0, 0);
    gemm(f0o, 512, 512, f1bf, 512, nullptr, 0, 0, nullptr, 0,
         f1_b, nullptr, nullptr, rectb, 512, 256, 512, 0, 0, 0);
    hipLaunchKernelGGL(l2norm_kernel, dim3(256), dim3(256), 0, stream, rectb, out_rec);
}

// Round 15
// 777.175 us; speedup vs baseline: 1.3043x; 1.0133x over previous
//
#include <hip/hip_runtime.h>
#include <hip/hip_bf16.h>
#include <math.h>

typedef __attribute__((ext_vector_type(8))) short short8;
typedef __attribute__((ext_vector_type(4))) float f32x4;

#define KTILE 32
#define LSTR 40    // KT=32 legacy path stride
#define LSTR64 72  // KT=64 reg-staged path stride

__device__ __forceinline__ short8 cvt8(const float* x) {
    short8 r;
#pragma unroll
    for (int i = 0; i < 8; ++i) {
        __hip_bfloat16 b = __float2bfloat16(x[i]);
        r[i] = *reinterpret_cast<const short*>(&b);
    }
    return r;
}
__device__ __forceinline__ float bf2f(short s) {
    unsigned int u = ((unsigned int)(unsigned short)s) << 16;
    return __uint_as_float(u);
}
__device__ __forceinline__ void gload16(const void* g, void* l) {
    __builtin_amdgcn_global_load_lds(
        (const __attribute__((address_space(1))) unsigned int*)g,
        (__attribute__((address_space(3))) unsigned int*)l, 16, 0, 0);
}

// ---------------- legacy MFMA GEMM (KT=32): only used for attn fp32 fallback ----------------
template<int BM>
__global__ __launch_bounds__(256)
void mfma_gemm_t(const float* __restrict__ A1f, int lda1, int k1,
                 const short* __restrict__ W1, int ldw1,
                 const float* __restrict__ A2f, int lda2, int k2,
                 const short* __restrict__ W2, int ldw2,
                 const float* __restrict__ bias1,
                 const float* __restrict__ mulvec, const float* __restrict__ mul,
                 float* __restrict__ C, int ldc, int M, int N,
                 int do_relu, int mode, int abits, int c_bf16)
{
    __shared__ short sA[2][BM][LSTR];
    __shared__ short sB[2][64][LSTR];
    __shared__ float sred[BM][2];
    constexpr int MF = BM / 32;

    const int tid = threadIdx.x;
    int m0, n0, ch8 = 0;
    if (mode == 1) {
        const int xcd = blockIdx.x & 7;
        const int gi = xcd * 588 + (blockIdx.x >> 3);
        m0 = (gi >> 3) << 7;
        ch8 = gi & 7;
        n0 = ch8 << 6;
    } else {
        m0 = blockIdx.y * BM;
        n0 = blockIdx.x << 6;
    }
    const short* A1b = (const short*)A1f;
    const short* A2b = (const short*)A2f;
    const int Ktot = k1 + k2;
    const int nt = (Ktot + KTILE - 1) / KTILE;
    const int lane = tid & 63, wave = tid >> 6;
    const int wr = (wave >> 1) * (BM >> 1);
    const int wc = (wave & 1) << 5;
    const int l15 = lane & 15, lh = lane >> 4;
    const int rowA = (BM == 128) ? (tid >> 1) : (tid >> 2);
    const int kA   = (BM == 128) ? ((tid & 1) << 4) : ((tid & 3) << 3);
    const int rgA = min(m0 + rowA, M - 1);
    const int rowW = tid >> 2, kW = (tid & 3) << 3;
    const int ngW = min(n0 + rowW, N - 1);

    f32x4 acc[MF][2];
#pragma unroll
    for (int m = 0; m < MF; ++m)
#pragma unroll
        for (int n = 0; n < 2; ++n) acc[m][n] = (f32x4){0.f, 0.f, 0.f, 0.f};

    short8 aS0, aS1, wS;
    auto loadA = [&](int t) {
        constexpr int AE = (BM == 128) ? 16 : 8;
        const int k0 = t * KTILE + kA;
        if (k0 + AE <= k1) {
            if (abits & 1) {
                const short* p = A1b + (size_t)rgA * lda1 + k0;
                aS0 = *(const short8*)p;
                if constexpr (BM == 128) aS1 = *(const short8*)(p + 8);
            } else {
                const float* p = A1f + (size_t)rgA * lda1 + k0;
                float4 v0 = *(const float4*)p, v1 = *(const float4*)(p + 4);
                float t0[8] = {v0.x, v0.y, v0.z, v0.w, v1.x, v1.y, v1.z, v1.w};
                aS0 = cvt8(t0);
                if constexpr (BM == 128) {
                    float4 v2 = *(const float4*)(p + 8), v3 = *(const float4*)(p + 12);
                    float t1[8] = {v2.x, v2.y, v2.z, v2.w, v3.x, v3.y, v3.z, v3.w};
                    aS1 = cvt8(t1);
                }
            }
        } else if (k0 >= k1 && k0 + AE <= Ktot) {
            const int kk = k0 - k1;
            if (abits & 2) {
                const short* p = A2b + (size_t)rgA * lda2 + kk;
                aS0 = *(const short8*)p;
                if constexpr (BM == 128) aS1 = *(const short8*)(p + 8);
            } else {
                const float* p = A2f + (size_t)rgA * lda2 + kk;
                float4 v0 = *(const float4*)p, v1 = *(const float4*)(p + 4);
                float t0[8] = {v0.x, v0.y, v0.z, v0.w, v1.x, v1.y, v1.z, v1.w};
                aS0 = cvt8(t0);
                if constexpr (BM == 128) {
                    float4 v2 = *(const float4*)(p + 8), v3 = *(const float4*)(p + 12);
                    float t1[8] = {v2.x, v2.y, v2.z, v2.w, v3.x, v3.y, v3.z, v3.w};
                    aS1 = cvt8(t1);
                }
            }
        } else {
            float tmp[(BM == 128) ? 16 : 8];
#pragma unroll
            for (int e = 0; e < ((BM == 128) ? 16 : 8); ++e) {
                const int kg = k0 + e;
                float v = 0.f;
                if (kg < k1) v = (abits & 1) ? bf2f(A1b[(size_t)rgA * lda1 + kg]) : A1f[(size_t)rgA * lda1 + kg];
                else if (kg < Ktot) v = (abits & 2) ? bf2f(A2b[(size_t)rgA * lda2 + (kg - k1)]) : A2f[(size_t)rgA * lda2 + (kg - k1)];
                tmp[e] = v;
            }
            aS0 = cvt8(tmp);
            if constexpr (BM == 128) aS1 = cvt8(tmp + 8);
        }
    };
    auto loadW = [&](int t) {
        const int k0 = t * KTILE + kW;
        if (k0 + 8 <= k1) {
            wS = *(const short8*)&W1[(size_t)ngW * ldw1 + k0];
        } else if (k0 >= k1 && k0 + 8 <= Ktot) {
            wS = *(const short8*)&W2[(size_t)ngW * ldw2 + (k0 - k1)];
        } else {
            short8 w;
#pragma unroll
            for (int e = 0; e < 8; ++e) {
                const int kg = k0 + e;
                w[e] = (kg < k1) ? W1[(size_t)ngW * ldw1 + kg]
                                 : ((kg < Ktot) ? W2[(size_t)ngW * ldw2 + (kg - k1)] : (short)0);
            }
            wS = w;
        }
    };
    auto writeS = [&](int buf) {
        *(short8*)&sA[buf][rowA][kA] = aS0;
        if constexpr (BM == 128) *(short8*)&sA[buf][rowA][kA + 8] = aS1;
        *(short8*)&sB[buf][rowW][kW] = wS;
    };

    loadA(0); loadW(0); writeS(0);
    __syncthreads();
    for (int t = 0; t < nt; ++t) {
        const int cur = t & 1;
        if (t + 1 < nt) { loadA(t + 1); loadW(t + 1); }
        short8 af[MF], bfv[2];
#pragma unroll
        for (int m = 0; m < MF; ++m)
            af[m] = *(const short8*)&sA[cur][wr + (m << 4) + l15][lh << 3];
#pragma unroll
        for (int n = 0; n < 2; ++n)
            bfv[n] = *(const short8*)&sB[cur][wc + (n << 4) + l15][lh << 3];
#pragma unroll
        for (int m = 0; m < MF; ++m)
#pragma unroll
            for (int n = 0; n < 2; ++n)
                acc[m][n] = __builtin_amdgcn_mfma_f32_16x16x32_bf16(af[m], bfv[n], acc[m][n], 0, 0, 0);
        if (t + 1 < nt) writeS(cur ^ 1);
        __syncthreads();
    }

    if (mode == 0) {
#pragma unroll
        for (int m = 0; m < MF; ++m) {
#pragma unroll
            for (int j = 0; j < 4; ++j) {
                const int r = m0 + wr + (m << 4) + (lh << 2) + j;
                if (r >= M) continue;
#pragma unroll
                for (int n = 0; n < 2; ++n) {
                    const int c = n0 + wc + (n << 4) + l15;
                    if (c >= N) continue;
                    float v = acc[m][n][j];
                    if (bias1) v += bias1[c];
                    if (do_relu) v = fmaxf(v, 0.f);
                    if (mulvec) v *= mulvec[c];
                    if (mul) v *= mul[(size_t)r * ldc + c];
                    if (c_bf16) {
                        __hip_bfloat16 b = __float2bfloat16(v);
                        ((short*)C)[(size_t)r * ldc + c] = *(short*)&b;
                    } else {
                        C[(size_t)r * ldc + c] = v;
                    }
                }
            }
        }
    } else {
#pragma unroll
        for (int m = 0; m < MF; ++m) {
#pragma unroll
            for (int j = 0; j < 4; ++j) {
                const int rloc = wr + (m << 4) + (lh << 2) + j;
                const int r = m0 + rloc;
                const size_t sqbase = (size_t)(r / 49) * ldc;
                float s = 0.f;
#pragma unroll
                for (int n = 0; n < 2; ++n) {
                    const int c = n0 + wc + (n << 4) + l15;
                    float v = acc[m][n][j] + bias1[c];
                    v = fmaxf(v, 0.f);
                    s += v * mul[sqbase + c];
                }
                s += __shfl_xor(s, 1, 64);
                s += __shfl_xor(s, 2, 64);
                s += __shfl_xor(s, 4, 64);
                s += __shfl_xor(s, 8, 64);
                if (l15 == 0) sred[rloc][wc >> 5] = s;
            }
        }
        __syncthreads();
        if (tid < BM)
            C[(size_t)(m0 + tid) * 8 + ch8] = sred[tid][0] + sred[tid][1];
    }
}

// ---------------- glds GEMM, 64x64, KT=64: all-bf16, tile-aligned concat A ----------------
__global__ __launch_bounds__(256)
void mfma_glds64_kernel(const short* __restrict__ A1, const short* __restrict__ A2,
                        int lda, int k1, const short* __restrict__ W, int ldw,
                        const float* __restrict__ bias, const float* __restrict__ mulvec,
                        float* __restrict__ C, int ldc, int Ktot, int do_relu, int c_bf16)
{
    __shared__ short sA[2][64][64];
    __shared__ short sB[2][64][64];
    const int tid = threadIdx.x;
    const int m0 = blockIdx.y << 6, n0 = blockIdx.x << 6;
    const int lane = tid & 63, wave = tid >> 6;
    const int wr = (wave >> 1) << 5, wc = (wave & 1) << 5;
    const int l15 = lane & 15, lh = lane >> 4;
    const int lr = lane >> 3;
    const int sc = (lane & 7) ^ lr;
    const int nt = Ktot >> 6;
    const int t1 = k1 >> 6;

    f32x4 acc[2][2];
#pragma unroll
    for (int m = 0; m < 2; ++m)
#pragma unroll
        for (int n = 0; n < 2; ++n) acc[m][n] = (f32x4){0.f, 0.f, 0.f, 0.f};

    auto stage = [&](int t, int buf) {
        const short* Ab = (t < t1) ? A1 : A2;
        const int kb = ((t < t1) ? t : (t - t1)) << 6;
#pragma unroll
        for (int j = 0; j < 2; ++j) {
            const int r0 = (wave << 4) + (j << 3);
            gload16(Ab + (size_t)(m0 + r0 + lr) * lda + kb + (sc << 3), &sA[buf][r0][0]);
        }
#pragma unroll
        for (int j = 0; j < 2; ++j) {
            const int r0 = (wave << 4) + (j << 3);
            gload16(W + (size_t)(n0 + r0 + lr) * ldw + (t << 6) + (sc << 3), &sB[buf][r0][0]);
        }
    };

    stage(0, 0);
    __syncthreads();
    for (int t = 0; t < nt; ++t) {
        const int cur = t & 1;
        if (t + 1 < nt) stage(t + 1, cur ^ 1);
#pragma unroll
        for (int kk = 0; kk < 2; ++kk) {
            const int rd = (((kk << 2) + lh) ^ (l15 & 7)) << 3;
            short8 af[2], bfv[2];
#pragma unroll
            for (int m = 0; m < 2; ++m)
                af[m] = *(const short8*)&sA[cur][wr + (m << 4) + l15][rd];
#pragma unroll
            for (int n = 0; n < 2; ++n)
                bfv[n] = *(const short8*)&sB[cur][wc + (n << 4) + l15][rd];
#pragma unroll
            for (int m = 0; m < 2; ++m)
#pragma unroll
                for (int n = 0; n < 2; ++n)
                    acc[m][n] = __builtin_amdgcn_mfma_f32_16x16x32_bf16(af[m], bfv[n], acc[m][n], 0, 0, 0);
        }
        __syncthreads();
    }

#pragma unroll
    for (int m = 0; m < 2; ++m) {
#pragma unroll
        for (int j = 0; j < 4; ++j) {
            const int r = m0 + wr + (m << 4) + (lh << 2) + j;
#pragma unroll
            for (int n = 0; n < 2; ++n) {
                const int c = n0 + wc + (n << 4) + l15;
                float v = acc[m][n][j];
                if (bias) v += bias[c];
                if (do_relu) v = fmaxf(v, 0.f);
                if (mulvec) v *= mulvec[c];
                if (c_bf16) {
                    __hip_bfloat16 b = __float2bfloat16(v);
                    ((short*)C)[(size_t)r * ldc + c] = *(short*)&b;
                } else {
                    C[(size_t)r * ldc + c] = v;
                }
            }
        }
    }
}

// ---------------- glds GEMM, 128x64, KT=64 (g-chain, M multiple of 128) ----------------
__global__ __launch_bounds__(256)
void mfma_glds128_kernel(const short* __restrict__ A, int lda,
                         const short* __restrict__ W, int ldw,
                         const float* __restrict__ bias,
                         float* __restrict__ C, int ldc, int Ktot, int do_relu, int c_bf16)
{
    __shared__ short sA[2][128][64];
    __shared__ short sB[2][64][64];
    const int tid = threadIdx.x;
    const int m0 = blockIdx.y << 7, n0 = blockIdx.x << 6;
    const int lane = tid & 63, wave = tid >> 6;
    const int wr = (wave >> 1) << 6, wc = (wave & 1) << 5;
    const int l15 = lane & 15, lh = lane >> 4;
    const int lr = lane >> 3;
    const int sc = (lane & 7) ^ lr;
    const int nt = Ktot >> 6;

    f32x4 acc[4][2];
#pragma unroll
    for (int m = 0; m < 4; ++m)
#pragma unroll
        for (int n = 0; n < 2; ++n) acc[m][n] = (f32x4){0.f, 0.f, 0.f, 0.f};

    auto stage = [&](int t, int buf) {
        const int kb = t << 6;
#pragma unroll
        for (int j = 0; j < 4; ++j) {
            const int r0 = (wave << 5) + (j << 3);
            gload16(A + (size_t)(m0 + r0 + lr) * lda + kb + (sc << 3), &sA[buf][r0][0]);
        }
#pragma unroll
        for (int j = 0; j < 2; ++j) {
            const int r0 = (wave << 4) + (j << 3);
            gload16(W + (size_t)(n0 + r0 + lr) * ldw + kb + (sc << 3), &sB[buf][r0][0]);
        }
    };

    stage(0, 0);
    __syncthreads();
    for (int t = 0; t < nt; ++t) {
        const int cur = t & 1;
        if (t + 1 < nt) stage(t + 1, cur ^ 1);
#pragma unroll
        for (int kk = 0; kk < 2; ++kk) {
            const int rd = (((kk << 2) + lh) ^ (l15 & 7)) << 3;
            short8 af[4], bfv[2];
#pragma unroll
            for (int m = 0; m < 4; ++m)
                af[m] = *(const short8*)&sA[cur][wr + (m << 4) + l15][rd];
#pragma unroll
            for (int n = 0; n < 2; ++n)
                bfv[n] = *(const short8*)&sB[cur][wc + (n << 4) + l15][rd];
#pragma unroll
            for (int m = 0; m < 4; ++m)
#pragma unroll
                for (int n = 0; n < 2; ++n)
                    acc[m][n] = __builtin_amdgcn_mfma_f32_16x16x32_bf16(af[m], bfv[n], acc[m][n], 0, 0, 0);
        }
        __syncthreads();
    }

#pragma unroll
    for (int m = 0; m < 4; ++m) {
#pragma unroll
        for (int j = 0; j < 4; ++j) {
            const int r = m0 + wr + (m << 4) + (lh << 2) + j;
#pragma unroll
            for (int n = 0; n < 2; ++n) {
                const int c = n0 + wc + (n << 4) + l15;
                float v = acc[m][n][j];
                if (bias) v += bias[c];
                if (do_relu) v = fmaxf(v, 0.f);
                if (c_bf16) {
                    __hip_bfloat16 b = __float2bfloat16(v);
                    ((short*)C)[(size_t)r * ldc + c] = *(short*)&b;
                } else {
                    C[(size_t)r * ldc + c] = v;
                }
            }
        }
    }
}

// ---------------- attn logits, 64x64, KT=64, glds + swizzle (9408 blocks) ----------------
__global__ __launch_bounds__(256)
void attn_logits4_kernel(const short* __restrict__ imgb, const short* __restrict__ vW,
                         const float* __restrict__ vb, const float* __restrict__ swq,
                         float* __restrict__ partial)
{
    __shared__ short sA[2][64][64];
    __shared__ short sB[2][64][64];
    __shared__ float sred[64][2];
    const int tid = threadIdx.x;
    const int lane = tid & 63, wave = tid >> 6;
    const int xcd = blockIdx.x & 7;
    const int gi = xcd * 1176 + (blockIdx.x >> 3);
    const int m0 = (gi >> 3) << 6;
    const int ch8 = gi & 7;
    const int n0 = ch8 << 6;
    const int wr = (wave >> 1) << 5, wc = (wave & 1) << 5;
    const int l15 = lane & 15, lh = lane >> 4;
    const int lr = lane >> 3;
    const int sc = (lane & 7) ^ lr;

    f32x4 acc[2][2];
#pragma unroll
    for (int m = 0; m < 2; ++m)
#pragma unroll
        for (int n = 0; n < 2; ++n) acc[m][n] = (f32x4){0.f, 0.f, 0.f, 0.f};

    auto stage = [&](int t, int buf) {
        const int kb = t << 6;
#pragma unroll
        for (int j = 0; j < 2; ++j) {
            const int r0 = (wave << 4) + (j << 3);
            gload16(imgb + (size_t)(m0 + r0 + lr) * 512 + kb + (sc << 3), &sA[buf][r0][0]);
        }
#pragma unroll
        for (int j = 0; j < 2; ++j) {
            const int r0 = (wave << 4) + (j << 3);
            gload16(vW + (size_t)(n0 + r0 + lr) * 512 + kb + (sc << 3), &sB[buf][r0][0]);
        }
    };

    stage(0, 0);
    __syncthreads();
    for (int t = 0; t < 8; ++t) {
        const int cur = t & 1;
        if (t + 1 < 8) stage(t + 1, cur ^ 1);
#pragma unroll
        for (int kk = 0; kk < 2; ++kk) {
            const int rd = (((kk << 2) + lh) ^ (l15 & 7)) << 3;
            short8 af[2], bfv[2];
#pragma unroll
            for (int m = 0; m < 2; ++m)
                af[m] = *(const short8*)&sA[cur][wr + (m << 4) + l15][rd];
#pragma unroll
            for (int n = 0; n < 2; ++n)
                bfv[n] = *(const short8*)&sB[cur][wc + (n << 4) + l15][rd];
#pragma unroll
            for (int m = 0; m < 2; ++m)
#pragma unroll
                for (int n = 0; n < 2; ++n)
                    acc[m][n] = __builtin_amdgcn_mfma_f32_16x16x32_bf16(af[m], bfv[n], acc[m][n], 0, 0, 0);
        }
        __syncthreads();
    }

#pragma unroll
    for (int m = 0; m < 2; ++m) {
#pragma unroll
        for (int j = 0; j < 4; ++j) {
            const int rloc = wr + (m << 4) + (lh << 2) + j;
            const int r = m0 + rloc;
            const size_t sqbase = (size_t)(r / 49) * 512;
            float s = 0.f;
#pragma unroll
            for (int n = 0; n < 2; ++n) {
                const int c = n0 + wc + (n << 4) + l15;
                float v = acc[m][n][j] + vb[c];
                v = fmaxf(v, 0.f);
                s += v * swq[sqbase + c];
            }
            s += __shfl_xor(s, 1, 64);
            s += __shfl_xor(s, 2, 64);
            s += __shfl_xor(s, 4, 64);
            s += __shfl_xor(s, 8, 64);
            if (l15 == 0) sred[rloc][wc >> 5] = s;
        }
    }
    __syncthreads();
    if (tid < 64)
        partial[(size_t)(m0 + tid) * 8 + ch8] = sred[tid][0] + sred[tid][1];
}

// ---------------- reg-staged 64x64 KT=64 GEMM (fp32-A / ragged-N cases) ----------------
__global__ __launch_bounds__(256)
void mfma_gemm64_kernel(const float* __restrict__ A1f, int lda1, int k1,
                        const short* __restrict__ W1, int ldw1,
                        const float* __restrict__ A2f, int lda2, int k2,
                        const short* __restrict__ W2, int ldw2,
                        const float* __restrict__ bias1,
                        const float* __restrict__ mulvec, const float* __restrict__ mul,
                        float* __restrict__ C, int ldc, int M, int N,
                        int do_relu, int abits, int c_bf16)
{
    __shared__ short sA[2][64][LSTR64];
    __shared__ short sB[2][64][LSTR64];
    const int tid = threadIdx.x;
    const int m0 = blockIdx.y << 6, n0 = blockIdx.x << 6;
    const short* A1b = (const short*)A1f;
    const short* A2b = (const short*)A2f;
    const int Ktot = k1 + k2;
    const int nt = (Ktot + 63) >> 6;
    const int lane = tid & 63, wave = tid >> 6;
    const int wr = (wave >> 1) << 5, wc = (wave & 1) << 5;
    const int l15 = lane & 15, lh = lane >> 4;
    const int srow = tid >> 2, skq = (tid & 3) << 4;
    const int rgA = min(m0 + srow, M - 1);
    const int ngW = min(n0 + srow, N - 1);

    f32x4 acc[2][2];
#pragma unroll
    for (int m = 0; m < 2; ++m)
#pragma unroll
        for (int n = 0; n < 2; ++n) acc[m][n] = (f32x4){0.f, 0.f, 0.f, 0.f};

    short8 aS0, aS1, wS0, wS1;
    auto loadA = [&](int t) {
        const int k0 = (t << 6) + skq;
        if (k0 + 16 <= k1) {
            if (abits & 1) {
                const short* p = A1b + (size_t)rgA * lda1 + k0;
                aS0 = *(const short8*)p; aS1 = *(const short8*)(p + 8);
            } else {
                const float* p = A1f + (size_t)rgA * lda1 + k0;
                float4 v0 = *(const float4*)p, v1 = *(const float4*)(p + 4);
                float4 v2 = *(const float4*)(p + 8), v3 = *(const float4*)(p + 12);
                float t0[8] = {v0.x, v0.y, v0.z, v0.w, v1.x, v1.y, v1.z, v1.w};
                float t1[8] = {v2.x, v2.y, v2.z, v2.w, v3.x, v3.y, v3.z, v3.w};
                aS0 = cvt8(t0); aS1 = cvt8(t1);
            }
        } else if (k0 >= k1 && k0 + 16 <= Ktot) {
            const int kk = k0 - k1;
            if (abits & 2) {
                const short* p = A2b + (size_t)rgA * lda2 + kk;
                aS0 = *(const short8*)p; aS1 = *(const short8*)(p + 8);
            } else {
                const float* p = A2f + (size_t)rgA * lda2 + kk;
                float4 v0 = *(const float4*)p, v1 = *(const float4*)(p + 4);
                float4 v2 = *(const float4*)(p + 8), v3 = *(const float4*)(p + 12);
                float t0[8] = {v0.x, v0.y, v0.z, v0.w, v1.x, v1.y, v1.z, v1.w};
                float t1[8] = {v2.x, v2.y, v2.z, v2.w, v3.x, v3.y, v3.z, v3.w};
                aS0 = cvt8(t0); aS1 = cvt8(t1);
            }
        } else {
            float tmp[16];
#pragma unroll
            for (int e = 0; e < 16; ++e) {
                const int kg = k0 + e;
                float v = 0.f;
                if (kg < k1) v = (abits & 1) ? bf2f(A1b[(size_t)rgA * lda1 + kg]) : A1f[(size_t)rgA * lda1 + kg];
                else if (kg < Ktot) v = (abits & 2) ? bf2f(A2b[(size_t)rgA * lda2 + (kg - k1)]) : A2f[(size_t)rgA * lda2 + (kg - k1)];
                tmp[e] = v;
            }
            aS0 = cvt8(tmp); aS1 = cvt8(tmp + 8);
        }
    };
    auto loadW = [&](int t) {
        const int k0 = (t << 6) + skq;
        if (k0 + 16 <= k1) {
            const short* p = W1 + (size_t)ngW * ldw1 + k0;
            wS0 = *(const short8*)p; wS1 = *(const short8*)(p + 8);
        } else if (k0 >= k1 && k0 + 16 <= Ktot) {
            const short* p = W2 + (size_t)ngW * ldw2 + (k0 - k1);
            wS0 = *(const short8*)p; wS1 = *(const short8*)(p + 8);
        } else {
            short8 w0, w1;
#pragma unroll
            for (int e = 0; e < 16; ++e) {
                const int kg = k0 + e;
                short v = (kg < k1) ? W1[(size_t)ngW * ldw1 + kg]
                                    : ((kg < Ktot) ? W2[(size_t)ngW * ldw2 + (kg - k1)] : (short)0);
                if (e < 8) w0[e] = v; else w1[e - 8] = v;
            }
            wS0 = w0; wS1 = w1;
        }
    };
    auto writeS = [&](int buf) {
        *(short8*)&sA[buf][srow][skq] = aS0;
        *(short8*)&sA[buf][srow][skq + 8] = aS1;
        *(short8*)&sB[buf][srow][skq] = wS0;
        *(short8*)&sB[buf][srow][skq + 8] = wS1;
    };

    loadA(0); loadW(0); writeS(0);
    __syncthreads();
    for (int t = 0; t < nt; ++t) {
        const int cur = t & 1;
        if (t + 1 < nt) { loadA(t + 1); loadW(t + 1); }
#pragma unroll
        for (int kk = 0; kk < 2; ++kk) {
            short8 af[2], bfv[2];
#pragma unroll
            for (int m = 0; m < 2; ++m)
                af[m] = *(const short8*)&sA[cur][wr + (m << 4) + l15][(kk << 5) + (lh << 3)];
#pragma unroll
            for (int n = 0; n < 2; ++n)
                bfv[n] = *(const short8*)&sB[cur][wc + (n << 4) + l15][(kk << 5) + (lh << 3)];
#pragma unroll
            for (int m = 0; m < 2; ++m)
#pragma unroll
                for (int n = 0; n < 2; ++n)
                    acc[m][n] = __builtin_amdgcn_mfma_f32_16x16x32_bf16(af[m], bfv[n], acc[m][n], 0, 0, 0);
        }
        if (t + 1 < nt) writeS(cur ^ 1);
        __syncthreads();
    }

#pragma unroll
    for (int m = 0; m < 2; ++m) {
#pragma unroll
        for (int j = 0; j < 4; ++j) {
            const int r = m0 + wr + (m << 4) + (lh << 2) + j;
            if (r >= M) continue;
#pragma unroll
            for (int n = 0; n < 2; ++n) {
                const int c = n0 + wc + (n << 4) + l15;
                if (c >= N) continue;
                float v = acc[m][n][j];
                if (bias1) v += bias1[c];
                if (do_relu) v = fmaxf(v, 0.f);
                if (mulvec) v *= mulvec[c];
                if (mul) v *= mul[(size_t)r * ldc + c];
                if (c_bf16) {
                    __hip_bfloat16 b = __float2bfloat16(v);
                    ((short*)C)[(size_t)r * ldc + c] = *(short*)&b;
                } else {
                    C[(size_t)r * ldc + c] = v;
                }
            }
        }
    }
}

// ---------------- weight bf16 pre-conversion ----------------
__global__ __launch_bounds__(256)
void wcvt_kernel(const float* __restrict__ proj, const float* __restrict__ qW,
                 const float* __restrict__ vW, const float* __restrict__ qnet,
                 const float* __restrict__ vnet, const float* __restrict__ cls1,
                 const float* __restrict__ cls2, const float* __restrict__ g0,
                 const float* __restrict__ g1, const float* __restrict__ g2,
                 const float* __restrict__ g3, const float* __restrict__ f0,
                 const float* __restrict__ f1, short* __restrict__ dst)
{
    size_t idx = ((size_t)blockIdx.x * 256 + threadIdx.x) * 8;
    if (idx >= 5981184) return;
    const float* s;
    if (idx < 524288) s = proj + idx;
    else if (idx < 786432) s = qW + (idx - 524288);
    else if (idx < 1048576) s = vW + (idx - 786432);
    else if (idx < 1310720) s = qnet + (idx - 1048576);
    else if (idx < 1572864) s = vnet + (idx - 1310720);
    else if (idx < 2097152) s = cls1 + (idx - 1572864);
    else if (idx < 4146176) s = cls2 + (idx - 2097152);
    else if (idx < 4670464) {
        size_t li = idx - 4146176;
        int c = (int)(li >> 9), k = (int)(li & 511);
        s = (c < 512) ? g0 + (size_t)c * 1024 + k
                      : g0 + (size_t)(c - 512) * 1024 + 512 + k;
    }
    else if (idx < 4932608) s = g1 + (idx - 4670464);
    else if (idx < 5194752) s = g2 + (idx - 4932608);
    else if (idx < 5456896) s = g3 + (idx - 5194752);
    else if (idx < 5719040) s = f0 + (idx - 5456896);
    else s = f1 + (idx - 5719040);
    float4 a = *(const float4*)s, b = *(const float4*)(s + 4);
    float t[8] = {a.x, a.y, a.z, a.w, b.x, b.y, b.z, b.w};
    *(short8*)(dst + idx) = cvt8(t);
}

// ---------------- LSTM weight reorder ([2048][832] bf16, gate-permuted) ----------------
__global__ __launch_bounds__(256)
void lstm_reorder_kernel(const float* __restrict__ Wih, const float* __restrict__ Whh,
                         const float* __restrict__ bih, const float* __restrict__ bhh,
                         short* __restrict__ Wbf, float* __restrict__ bias_perm)
{
    int id = blockIdx.x * 256 + threadIdx.x;   // < 2048*512
    int c = id >> 9, k = id & 511;
    int src = (c & 3) * 512 + (c >> 2);
    {
        __hip_bfloat16 b = __float2bfloat16(Whh[(size_t)src * 512 + k]);
        Wbf[(size_t)c * 832 + k] = *(short*)&b;
    }
    if (k < 300) {
        __hip_bfloat16 b = __float2bfloat16(Wih[(size_t)src * 300 + k]);
        Wbf[(size_t)c * 832 + 512 + k] = *(short*)&b;
    } else if (k < 320) {
        Wbf[(size_t)c * 832 + 512 + k] = 0;
    }
    if (k == 0) bias_perm[c] = bih[src] + bhh[src];
}

// padded bf16 embedding table: embp[10000][320] (cols 300..319 = 0)
__global__ __launch_bounds__(256)
void embcvt_kernel(const float* __restrict__ qword, short* __restrict__ embp)
{
    int id = blockIdx.x * 256 + threadIdx.x;   // < 3,200,000
    if (id >= 3200000) return;
    int r = id / 320, c = id % 320;
    float v = (c < 300) ? qword[(size_t)r * 300 + c] : 0.f;
    __hip_bfloat16 b = __float2bfloat16(v);
    embp[id] = *(short*)&b;
}

// ---------------- LSTM step, 64x64, KT=64, glds + swizzle ----------------
__global__ __launch_bounds__(256)
void lstm_step6_kernel(const short* __restrict__ hF_in, const short* __restrict__ hB_in,
                       const short* __restrict__ WbfF, const short* __restrict__ WbfB,
                       const float* __restrict__ biasF, const float* __restrict__ biasB,
                       const short* __restrict__ embp, const int* __restrict__ toks,
                       int tF, int tB, int first,
                       short* __restrict__ hF_out, short* __restrict__ hB_out,
                       float* __restrict__ cF, float* __restrict__ cB)
{
    __shared__ short sA[2][64][64];
    __shared__ short sB[2][64][64];
    const int dir = blockIdx.z;
    const short* h_in = dir ? hB_in : hF_in;
    const short* Wbf  = dir ? WbfB : WbfF;
    const float* bias_perm = dir ? biasB : biasF;
    short* h_out  = dir ? hB_out : hF_out;
    float* cstate = dir ? cB : cF;
    const int tt = dir ? tB : tF;

    const int tid = threadIdx.x;
    const int m0 = blockIdx.y << 6;
    const int n0 = blockIdx.x << 6;
    const int lane = tid & 63, wave = tid >> 6;
    const int wr = (wave >> 1) << 5, wc = (wave & 1) << 5;
    const int l15 = lane & 15, lh = lane >> 4;
    const int lr = lane >> 3;
    const int sc = (lane & 7) ^ lr;

    f32x4 acc[2][2];
#pragma unroll
    for (int m = 0; m < 2; ++m)
#pragma unroll
        for (int n = 0; n < 2; ++n) acc[m][n] = (f32x4){0.f, 0.f, 0.f, 0.f};

    auto stage = [&](int t, int buf) {
#pragma unroll
        for (int j = 0; j < 2; ++j) {
            const int r0 = (wave << 4) + (j << 3);
            const int grow = m0 + r0 + lr;
            const short* g;
            if (t < 8) {
                g = h_in + (size_t)grow * 512 + (t << 6) + (sc << 3);
            } else {
                const int ar = toks[grow * 10 + tt];
                g = embp + (size_t)ar * 320 + ((t - 8) << 6) + (sc << 3);
            }
            gload16(g, &sA[buf][r0][0]);
        }
#pragma unroll
        for (int j = 0; j < 2; ++j) {
            const int r0 = (wave << 4) + (j << 3);
            gload16(Wbf + (size_t)(n0 + r0 + lr) * 832 + (t << 6) + (sc << 3), &sB[buf][r0][0]);
        }
    };

    stage(0, 0);
    __syncthreads();
    for (int t = 0; t < 13; ++t) {
        const int cur = t & 1;
        if (t + 1 < 13) stage(t + 1, cur ^ 1);
#pragma unroll
        for (int kk = 0; kk < 2; ++kk) {
            const int rd = (((kk << 2) + lh) ^ (l15 & 7)) << 3;
            short8 af[2], bfv[2];
#pragma unroll
            for (int m = 0; m < 2; ++m)
                af[m] = *(const short8*)&sA[cur][wr + (m << 4) + l15][rd];
#pragma unroll
            for (int n = 0; n < 2; ++n)
                bfv[n] = *(const short8*)&sB[cur][wc + (n << 4) + l15][rd];
#pragma unroll
            for (int m = 0; m < 2; ++m)
#pragma unroll
                for (int n = 0; n < 2; ++n)
                    acc[m][n] = __builtin_amdgcn_mfma_f32_16x16x32_bf16(af[m], bfv[n], acc[m][n], 0, 0, 0);
        }
        __syncthreads();
    }

#pragma unroll
    for (int n = 0; n < 2; ++n) {
        const int ccol = n0 + wc + (n << 4) + l15;
        const float bb = bias_perm[ccol];
        const int u = ccol >> 2;
#pragma unroll
        for (int m = 0; m < 2; ++m) {
#pragma unroll
            for (int j = 0; j < 4; ++j) {
                const int r = m0 + wr + (m << 4) + (lh << 2) + j;
                float v = acc[m][n][j] + bb;
                const int base = lane & ~3;
                float gi = __shfl(v, base, 64);
                float gf = __shfl(v, base | 1, 64);
                float gg = __shfl(v, base | 2, 64);
                float go = __shfl(v, base | 3, 64);
                if ((lane & 3) == 0) {
                    float si = 1.f / (1.f + expf(-gi));
                    float sf = 1.f / (1.f + expf(-gf));
                    float so = 1.f / (1.f + expf(-go));
                    size_t idx = ((size_t)r << 9) + u;
                    float cold = first ? 0.f : cstate[idx];
                    float cv = sf * cold + si * tanhf(gg);
                    cstate[idx] = cv;
                    float hv = so * tanhf(cv);
                    __hip_bfloat16 b = __float2bfloat16(hv);
                    h_out[idx] = *(short*)&b;
                }
            }
        }
    }
}

// ---------------- LSTM step fallback (reg-staged, KT=64) ----------------
__global__ __launch_bounds__(256)
void lstm_step4_kernel(const short* __restrict__ hF_in, const short* __restrict__ hB_in,
                       const short* __restrict__ WbfF, const short* __restrict__ WbfB,
                       const float* __restrict__ biasF, const float* __restrict__ biasB,
                       const float* __restrict__ emb, const int* __restrict__ toks,
                       int tF, int tB, int first,
                       short* __restrict__ hF_out, short* __restrict__ hB_out,
                       float* __restrict__ cF, float* __restrict__ cB)
{
    __shared__ short sA[2][64][LSTR64];
    __shared__ short sB[2][64][LSTR64];
    const int dir = blockIdx.z;
    const short* h_in = dir ? hB_in : hF_in;
    const short* Wbf  = dir ? WbfB : WbfF;
    const float* bias_perm = dir ? biasB : biasF;
    short* h_out  = dir ? hB_out : hF_out;
    float* cstate = dir ? cB : cF;
    const int tt = dir ? tB : tF;

    const int tid = threadIdx.x;
    const int m0 = blockIdx.y << 6;
    const int n0 = blockIdx.x << 6;
    const int lane = tid & 63, wave = tid >> 6;
    const int wr = (wave >> 1) << 5, wc = (wave & 1) << 5;
    const int l15 = lane & 15, lh = lane >> 4;
    const int srow = tid >> 2, skq = (tid & 3) << 4;
    const int rgA = m0 + srow;
    const int ngW = n0 + srow;
    const int nt = 13;
    const int arow = toks[rgA * 10 + tt];

    f32x4 acc[2][2];
#pragma unroll
    for (int m = 0; m < 2; ++m)
#pragma unroll
        for (int n = 0; n < 2; ++n) acc[m][n] = (f32x4){0.f, 0.f, 0.f, 0.f};

    short8 aS0, aS1, wS0, wS1;
    auto loadA = [&](int t) {
        const int k0 = (t << 6) + skq;
        if (k0 + 16 <= 512) {
            if (first) { short8 z = {0,0,0,0,0,0,0,0}; aS0 = z; aS1 = z; }
            else {
                const short* p = h_in + (size_t)rgA * 512 + k0;
                aS0 = *(const short8*)p; aS1 = *(const short8*)(p + 8);
            }
        } else if (k0 >= 512 && k0 + 16 <= 812) {
            const float* p = emb + (size_t)arow * 300 + (k0 - 512);
            float4 v0 = *(const float4*)p, v1 = *(const float4*)(p + 4);
            float4 v2 = *(const float4*)(p + 8), v3 = *(const float4*)(p + 12);
            float t0[8] = {v0.x, v0.y, v0.z, v0.w, v1.x, v1.y, v1.z, v1.w};
            float t1[8] = {v2.x, v2.y, v2.z, v2.w, v3.x, v3.y, v3.z, v3.w};
            aS0 = cvt8(t0); aS1 = cvt8(t1);
        } else {
            float tmp[16];
#pragma unroll
            for (int e = 0; e < 16; ++e) {
                const int kg = k0 + e;
                float v = 0.f;
                if (kg < 512) v = first ? 0.f : bf2f(h_in[(size_t)rgA * 512 + kg]);
                else if (kg < 812) v = emb[(size_t)arow * 300 + (kg - 512)];
                tmp[e] = v;
            }
            aS0 = cvt8(tmp); aS1 = cvt8(tmp + 8);
        }
    };
    auto loadW = [&](int t) {
        const short* p = Wbf + (size_t)ngW * 832 + (t << 6) + skq;
        wS0 = *(const short8*)p; wS1 = *(const short8*)(p + 8);
    };
    auto writeS = [&](int buf) {
        *(short8*)&sA[buf][srow][skq] = aS0;
        *(short8*)&sA[buf][srow][skq + 8] = aS1;
        *(short8*)&sB[buf][srow][skq] = wS0;
        *(short8*)&sB[buf][srow][skq + 8] = wS1;
    };

    loadA(0); loadW(0); writeS(0);
    __syncthreads();
    for (int t = 0; t < nt; ++t) {
        const int cur = t & 1;
        if (t + 1 < nt) { loadA(t + 1); loadW(t + 1); }
#pragma unroll
        for (int kk = 0; kk < 2; ++kk) {
            short8 af[2], bfv[2];
#pragma unroll
            for (int m = 0; m < 2; ++m)
                af[m] = *(const short8*)&sA[cur][wr + (m << 4) + l15][(kk << 5) + (lh << 3)];
#pragma unroll
            for (int n = 0; n < 2; ++n)
                bfv[n] = *(const short8*)&sB[cur][wc + (n << 4) + l15][(kk << 5) + (lh << 3)];
#pragma unroll
            for (int m = 0; m < 2; ++m)
#pragma unroll
                for (int n = 0; n < 2; ++n)
                    acc[m][n] = __builtin_amdgcn_mfma_f32_16x16x32_bf16(af[m], bfv[n], acc[m][n], 0, 0, 0);
        }
        if (t + 1 < nt) writeS(cur ^ 1);
        __syncthreads();
    }

#pragma unroll
    for (int n = 0; n < 2; ++n) {
        const int ccol = n0 + wc + (n << 4) + l15;
        const float bb = bias_perm[ccol];
        const int u = ccol >> 2;
#pragma unroll
        for (int m = 0; m < 2; ++m) {
#pragma unroll
            for (int j = 0; j < 4; ++j) {
                const int r = m0 + wr + (m << 4) + (lh << 2) + j;
                float v = acc[m][n][j] + bb;
                const int base = lane & ~3;
                float gi = __shfl(v, base, 64);
                float gf = __shfl(v, base | 1, 64);
                float gg = __shfl(v, base | 2, 64);
                float go = __shfl(v, base | 3, 64);
                if ((lane & 3) == 0) {
                    float si = 1.f / (1.f + expf(-gi));
                    float sf = 1.f / (1.f + expf(-gf));
                    float so = 1.f / (1.f + expf(-go));
                    size_t idx = ((size_t)r << 9) + u;
                    float cold = first ? 0.f : cstate[idx];
                    float cv = sf * cold + si * tanhf(gg);
                    cstate[idx] = cv;
                    float hv = so * tanhf(cv);
                    __hip_bfloat16 b = __float2bfloat16(hv);
                    h_out[idx] = *(short*)&b;
                }
            }
        }
    }
}

// img fp32 -> bf16
__global__ __launch_bounds__(256)
void imgcvt_kernel(const float* __restrict__ img, short* __restrict__ out)
{
    size_t i = ((size_t)blockIdx.x * 256 + threadIdx.x) * 8;
    float4 a = *(const float4*)(img + i), b = *(const float4*)(img + i + 4);
    float t[8] = {a.x, a.y, a.z, a.w, b.x, b.y, b.z, b.w};
    *(short8*)(out + i) = cvt8(t);
}

// softmax over 49 per n from 8-way partials, then v_emb[n,h] = sum_k att[k]*img[n,k,h]
__global__ __launch_bounds__(256)
void attn_vemb_kernel(const float* __restrict__ partial, const float* __restrict__ img,
                      const short* __restrict__ imgb, float* __restrict__ v_emb)
{
    __shared__ float satt[49];
    const int n = blockIdx.x;
    const int tid = threadIdx.x;
    if (tid < 64) {
        float v = -1e30f;
        if (tid < 49) {
            const float* pp = partial + ((size_t)n * 49 + tid) * 8;
            v = ((pp[0] + pp[1]) + (pp[2] + pp[3])) + ((pp[4] + pp[5]) + (pp[6] + pp[7]));
        }
        float m = v;
#pragma unroll
        for (int off = 32; off; off >>= 1) m = fmaxf(m, __shfl_xor(m, off, 64));
        float e = (tid < 49) ? expf(v - m) : 0.f;
        float s = e;
#pragma unroll
        for (int off = 32; off; off >>= 1) s += __shfl_xor(s, off, 64);
        if (tid < 49) satt[tid] = e / s;
    }
    __syncthreads();
    float2 s2 = make_float2(0.f, 0.f);
    if (imgb) {
        const unsigned int* ip = (const unsigned int*)(imgb + (size_t)n * 49 * 512);
        for (int k = 0; k < 49; ++k) {
            unsigned int v = ip[k * 256 + tid];
            float a = satt[k];
            s2.x = fmaf(a, bf2f((short)(v & 0xffff)), s2.x);
            s2.y = fmaf(a, bf2f((short)(v >> 16)), s2.y);
        }
    } else {
        const float2* ip = (const float2*)(img + (size_t)n * 49 * 512);
        for (int k = 0; k < 49; ++k) {
            float2 v = ip[k * 256 + tid];
            float a = satt[k];
            s2.x = fmaf(a, v.x, s2.x);
            s2.y = fmaf(a, v.y, s2.y);
        }
    }
    ((float2*)(v_emb + (size_t)n * 512))[tid] = s2;
}

// g0[b,i,j,c] = relu(PQ[b*6+j, c] + PQ[b*6+i, 512+c] + b0[c]) -> bf16
__global__ __launch_bounds__(256)
void g0build_kernel(const float* __restrict__ PQ, const float* __restrict__ b0,
                    short* __restrict__ g0)
{
    int id = blockIdx.x * 256 + threadIdx.x;
    int cc = id & 511;
    int r = id >> 9;
    int j = r % 6;
    int t = r / 6;
    int i = t % 6;
    int b = t / 6;
    float v = PQ[(size_t)(b * 6 + j) * 1024 + cc] + PQ[(size_t)(b * 6 + i) * 1024 + 512 + cc] + b0[cc];
    v = fmaxf(v, 0.f);
    __hip_bfloat16 h = __float2bfloat16(v);
    g0[id] = *(short*)&h;
}

__global__ __launch_bounds__(256)
void gsum_kernel(const short* __restrict__ g, float* __restrict__ out)
{
    int id = blockIdx.x * 256 + threadIdx.x;
    int b = id >> 9, hh = id & 511;
    const short* p = g + (size_t)b * 36 * 512 + hh;
    float s = 0.f;
#pragma unroll
    for (int i = 0; i < 36; ++i) s += bf2f(p[i * 512]);
    out[id] = s;
}

__global__ __launch_bounds__(256)
void l2norm_kernel(const float* __restrict__ in, float* __restrict__ out)
{
    int b = blockIdx.x;
    int tid = threadIdx.x;
    float v0 = in[(size_t)b * 512 + tid];
    float v1 = in[(size_t)b * 512 + 256 + tid];
    float s = v0 * v0 + v1 * v1;
#pragma unroll
    for (int off = 32; off; off >>= 1) s += __shfl_down(s, off, 64);
    __shared__ float ps[4];
    if ((tid & 63) == 0) ps[tid >> 6] = s;
    __syncthreads();
    float tot = ps[0] + ps[1] + ps[2] + ps[3];
    float inv = 1.f / sqrtf(tot);
    out[(size_t)b * 512 + tid] = v0 * inv;
    out[(size_t)b * 512 + 256 + tid] = v1 * inv;
}

extern "C" void kernel_launch(void* const* d_in, const int* in_sizes, int n_in,
                              void* d_out, int out_size, void* d_ws, size_t ws_size,
                              hipStream_t stream)
{
    (void)in_sizes; (void)n_in; (void)out_size;
    const float* img    = (const float*)d_in[0];
    const int*   toks   = (const int*)d_in[1];
    const float* qword  = (const float*)d_in[2];
    const float* Wih_f  = (const float*)d_in[3];
    const float* Whh_f  = (const float*)d_in[4];
    const float* bih_f  = (const float*)d_in[5];
    const float* bhh_f  = (const float*)d_in[6];
    const float* Wih_b  = (const float*)d_in[7];
    const float* Whh_b  = (const float*)d_in[8];
    const float* bih_b  = (const float*)d_in[9];
    const float* bhh_b  = (const float*)d_in[10];
    const float* proj_W = (const float*)d_in[11];
    const float* proj_b = (const float*)d_in[12];
    const float* vatt_vW = (const float*)d_in[13];
    const float* vatt_vb = (const float*)d_in[14];
    const float* vatt_qW = (const float*)d_in[15];
    const float* vatt_qb = (const float*)d_in[16];
    const float* vatt_oW = (const float*)d_in[17];
    const float* qnet_W = (const float*)d_in[19];
    const float* qnet_b = (const float*)d_in[20];
    const float* vnet_W = (const float*)d_in[21];
    const float* vnet_b = (const float*)d_in[22];
    const float* cls_W1 = (const float*)d_in[23];
    const float* cls_b1 = (const float*)d_in[24];
    const float* cls_W2 = (const float*)d_in[25];
    const float* cls_b2 = (const float*)d_in[26];
    const float* g0_W   = (const float*)d_in[27];
    const float* g0_b   = (const float*)d_in[28];
    const float* g1_W   = (const float*)d_in[29];
    const float* g1_b   = (const float*)d_in[30];
    const float* g2_W   = (const float*)d_in[31];
    const float* g2_b   = (const float*)d_in[32];
    const float* g3_W   = (const float*)d_in[33];
    const float* g3_b   = (const float*)d_in[34];
    const float* f0_W   = (const float*)d_in[35];
    const float* f0_b   = (const float*)d_in[36];
    const float* f1_W   = (const float*)d_in[37];
    const float* f1_b   = (const float*)d_in[38];

    float* out_logits = (float*)d_out;                  // [1536,2001]
    float* out_rec    = (float*)d_out + 1536 * 2001;    // [256,512]

    const size_t FB = 786432;  // 1536*512
    float* zone = (float*)d_ws;
    float* gA    = zone;                        // 4718592
    float* gB    = zone + 4718592;              // 4718592
    float* hid1  = zone + 9437184;              // 1572864 (bf16)
    float* PQb   = zone + 11010048;             // 1572864 (P|Q fp32 [1536,1024])
    float* gsumb = zone + 12582912;             // 131072
    float* f0o   = zone + 12713984;             // 131072
    float* rectb = zone + 12845056;             // 131072
    float* p = zone + 12976128;
    auto alloc = [&](size_t nf) { float* q = p; p += nf; return q; };
    float* hP0   = alloc(FB);       // h_f (bf16 in slot)
    float* hP2   = alloc(FB);       // h_b
    float* joint = alloc(FB);       // bf16
    float* partial = alloc(602112); // 75264*8 fp32
    short* WbfF  = (short*)alloc(851968);   // [2048][832] bf16
    short* WbfB  = (short*)alloc(851968);
    float* biasF = alloc(2048);
    float* biasB = alloc(2048);
    const size_t TOPF = 17645568;
    short* wb = (short*)(zone + TOPF);
    short* projbf = wb;
    short* qWbf   = wb + 524288;
    short* vWbf   = wb + 786432;
    short* qnetbf = wb + 1048576;
    short* vnetbf = wb + 1310720;
    short* cls1bf = wb + 1572864;
    short* cls2bf = wb + 2097152;
    short* wpqbf  = wb + 4146176;
    short* g1bf   = wb + 4670464;
    short* g2bf   = wb + 4932608;
    short* g3bf   = wb + 5194752;
    short* f0bf   = wb + 5456896;
    short* f1bf   = wb + 5719040;
    const size_t WEND = TOPF + 2990592;
    const size_t IMGBF = 19267584;
    const size_t EMBPF = 1600000;
    const bool useimgbf = ws_size >= (WEND + IMGBF) * sizeof(float);
    const bool useglds  = ws_size >= (WEND + IMGBF + EMBPF) * sizeof(float);
    short* imgbf = (short*)(zone + WEND);
    short* embp  = (short*)(zone + WEND + IMGBF);
    // LSTM-phase aliases inside gA (gA only used post-LSTM)
    short* hP1 = (short*)gA;
    short* hP3 = (short*)(gA + FB);
    float* cF  = gA + 2 * FB;
    float* cB  = gA + 3 * FB;
    // post-LSTM aliases
    float* q_emb  = PQb;
    float* swq    = hid1;
    float* q_repr = gA;
    float* v_emb  = gA + FB;

    // reg-staged fallback GEMM (fp32 A or ragged N)
    auto gemm = [&](const float* A1, int lda1, int k1, const short* W1, int ldw1,
                    const float* A2, int lda2, int k2, const short* W2, int ldw2,
                    const float* b1, const float* mv, const float* mulp,
                    float* Cp, int ldc, int M, int N, int relu, int abits, int cbf) {
        dim3 g((N + 63) / 64, (M + 63) / 64);
        hipLaunchKernelGGL(mfma_gemm64_kernel, g, dim3(256), 0, stream,
                           A1, lda1, k1, W1, ldw1, A2, lda2, k2, W2, ldw2,
                           b1, mv, mulp, Cp, ldc, M, N, relu, abits, cbf);
    };
    // glds GEMM (bf16 A, tile-aligned)
    auto gemmg = [&](const short* A1, const short* A2, int lda, int k1,
                     const short* W, int ldw, const float* b1, const float* mv,
                     float* Cp, int ldc, int M, int N, int Ktot, int relu, int cbf) {
        dim3 g(N >> 6, M >> 6);
        hipLaunchKernelGGL(mfma_glds64_kernel, g, dim3(256), 0, stream,
                           A1, A2, lda, k1, W, ldw, b1, mv, Cp, ldc, Ktot, relu, cbf);
    };

    const int NR = 1536;
    // ---- one-time weight conversions ----
    hipLaunchKernelGGL(lstm_reorder_kernel, dim3(4096), dim3(256), 0, stream,
                       Wih_f, Whh_f, bih_f, bhh_f, WbfF, biasF);
    hipLaunchKernelGGL(lstm_reorder_kernel, dim3(4096), dim3(256), 0, stream,
                       Wih_b, Whh_b, bih_b, bhh_b, WbfB, biasB);
    hipLaunchKernelGGL(wcvt_kernel, dim3(2921), dim3(256), 0, stream,
                       proj_W, vatt_qW, vatt_vW, qnet_W, vnet_W, cls_W1, cls_W2,
                       g0_W, g1_W, g2_W, g3_W, f0_W, f1_W, wb);
    if (useimgbf)
        hipLaunchKernelGGL(imgcvt_kernel, dim3(18816), dim3(256), 0, stream, img, imgbf);

    // ---- bidirectional LSTM ----
    if (useglds) {
        hipLaunchKernelGGL(embcvt_kernel, dim3(12500), dim3(256), 0, stream, qword, embp);
        hipMemsetAsync(hP0, 0, FB * sizeof(short), stream);
        hipMemsetAsync(hP2, 0, FB * sizeof(short), stream);
        short *fi = (short*)hP0, *fo = hP1, *bi = (short*)hP2, *bo = hP3;
        for (int t = 0; t < 10; ++t) {
            hipLaunchKernelGGL(lstm_step6_kernel, dim3(32, 24, 2), dim3(256), 0, stream,
                               fi, bi, WbfF, WbfB, biasF, biasB, embp, toks, t, 9 - t,
                               (t == 0) ? 1 : 0, fo, bo, cF, cB);
            short* tmp = fi; fi = fo; fo = tmp;
            tmp = bi; bi = bo; bo = tmp;
        }
    } else {
        short *fi = (short*)hP0, *fo = hP1, *bi = (short*)hP2, *bo = hP3;
        for (int t = 0; t < 10; ++t) {
            hipLaunchKernelGGL(lstm_step4_kernel, dim3(32, 24, 2), dim3(256), 0, stream,
                               fi, bi, WbfF, WbfB, biasF, biasB, qword, toks, t, 9 - t,
                               (t == 0) ? 1 : 0, fo, bo, cF, cB);
            short* tmp = fi; fi = fo; fo = tmp;
            tmp = bi; bi = bo; bo = tmp;
        }
    }   // final h_f in hP0, h_b in hP2 (bf16)

    // q_emb(bf16) = [h_f|h_b] @ proj_W^T + proj_b   (W spans [512][1024] contiguously)
    gemmg((const short*)hP0, (const short*)hP2, 512, 512, projbf, 1024,
          proj_b, nullptr, q_emb, 512, NR, 512, 1024, 0, 1);
    // swq(fp32) = relu(q_emb @ qW^T + qb) * oW
    gemmg((const short*)q_emb, nullptr, 512, 512, qWbf, 512,
          vatt_qb, vatt_oW, swq, 512, NR, 512, 512, 1, 0);
    // attention logits -> 8-way partials
    if (useimgbf) {
        hipLaunchKernelGGL(attn_logits4_kernel, dim3(9408), dim3(256), 0, stream,
                           imgbf, vWbf, vatt_vb, swq, partial);
    } else {
        hipLaunchKernelGGL(HIP_KERNEL_NAME(mfma_gemm_t<128>), dim3(4704), dim3(256), 0, stream,
                           img, 512, 512, vWbf, 512,
                           (const float*)nullptr, 0, 0, (const short*)nullptr, 0,
                           vatt_vb, (const float*)nullptr, swq,
                           partial, 512, 75264, 512, 0, 1, 0, 0);
    }
    hipLaunchKernelGGL(attn_vemb_kernel, dim3(1536), dim3(256), 0, stream,
                       partial, img, useimgbf ? imgbf : (const short*)nullptr, v_emb);
    // joint(bf16) = relu(q_emb@qnet^T+b) * relu(v_emb@vnet^T+b)
    gemmg((const short*)q_emb, nullptr, 512, 512, qnetbf, 512,
          qnet_b, nullptr, q_repr, 512, NR, 512, 512, 1, 0);
    gemm(v_emb, 512, 512, vnetbf, 512, nullptr, 0, 0, nullptr, 0,
         vnet_b, nullptr, q_repr, joint, 512, NR, 512, 1, 0, 1);
    // classifier
    gemmg((const short*)joint, nullptr, 512, 512, cls1bf, 512,
          cls_b1, nullptr, hid1, 1024, NR, 1024, 512, 1, 1);
    gemm(hid1, 1024, 1024, cls2bf, 1024, nullptr, 0, 0, nullptr, 0,
         cls_b2, nullptr, nullptr, out_logits, 2001, NR, 2001, 0, 1, 0);
    // relation network: P|Q in one GEMM, then g-chain (glds128)
    gemmg((const short*)joint, nullptr, 512, 512, wpqbf, 512,
          nullptr, nullptr, PQb, 1024, NR, 1024, 512, 0, 0);
    hipLaunchKernelGGL(g0build_kernel, dim3(18432), dim3(256), 0, stream,
                       PQb, g0_b, (short*)gA);
    hipLaunchKernelGGL(mfma_glds128_kernel, dim3(8, 72), dim3(256), 0, stream,
                       (const short*)gA, 512, g1bf, 512, g1_b, gB, 512, 512, 1, 1);
    hipLaunchKernelGGL(mfma_glds128_kernel, dim3(8, 72), dim3(256), 0, stream,
                       (const short*)gB, 512, g2bf, 512, g2_b, gA, 512, 512, 1, 1);
    hipLaunchKernelGGL(mfma_glds128_kernel, dim3(8, 72), dim3(256), 0, stream,
                       (const short*)gA, 512, g3bf, 512, g3_b, gB, 512, 512, 1, 1);
    hipLaunchKernelGGL(gsum_kernel, dim3(512), dim3(256), 0, stream, (const short*)gB, gsumb);
    gemm(gsumb, 512, 512, f0bf, 512, nullptr, 0, 0, nullptr, 0,
         f0_b, nullptr, nullptr, f0o, 512, 256, 512, 1, 0, 0);
    gemm(f0o, 512, 512, f1bf, 512, nullptr, 0, 0, nullptr, 0,
         f1_b, nullptr, nullptr, rectb, 512, 256, 512, 0, 0, 0);
    hipLaunchKernelGGL(l2norm_kernel, dim3(256), dim3(256), 0, stream, rectb, out_rec);
}

// Round 16
// 773.280 us; speedup vs baseline: 1.3109x; 1.0050x over previous
//
#include <hip/hip_runtime.h>
#include <hip/hip_bf16.h>
#include <math.h>

typedef __attribute__((ext_vector_type(8))) short short8;
typedef __attribute__((ext_vector_type(4))) float f32x4;

#define KTILE 32
#define LSTR 40    // KT=32 legacy path stride
#define LSTR64 72  // KT=64 reg-staged path stride

__device__ __forceinline__ short8 cvt8(const float* x) {
    short8 r;
#pragma unroll
    for (int i = 0; i < 8; ++i) {
        __hip_bfloat16 b = __float2bfloat16(x[i]);
        r[i] = *reinterpret_cast<const short*>(&b);
    }
    return r;
}
__device__ __forceinline__ float bf2f(short s) {
    unsigned int u = ((unsigned int)(unsigned short)s) << 16;
    return __uint_as_float(u);
}
__device__ __forceinline__ void gload16(const void* g, void* l) {
    __builtin_amdgcn_global_load_lds(
        (const __attribute__((address_space(1))) unsigned int*)g,
        (__attribute__((address_space(3))) unsigned int*)l, 16, 0, 0);
}

// ---------------- legacy MFMA GEMM (KT=32): only used for attn fp32 fallback ----------------
template<int BM>
__global__ __launch_bounds__(256)
void mfma_gemm_t(const float* __restrict__ A1f, int lda1, int k1,
                 const short* __restrict__ W1, int ldw1,
                 const float* __restrict__ A2f, int lda2, int k2,
                 const short* __restrict__ W2, int ldw2,
                 const float* __restrict__ bias1,
                 const float* __restrict__ mulvec, const float* __restrict__ mul,
                 float* __restrict__ C, int ldc, int M, int N,
                 int do_relu, int mode, int abits, int c_bf16)
{
    __shared__ short sA[2][BM][LSTR];
    __shared__ short sB[2][64][LSTR];
    __shared__ float sred[BM][2];
    constexpr int MF = BM / 32;

    const int tid = threadIdx.x;
    int m0, n0, ch8 = 0;
    if (mode == 1) {
        const int xcd = blockIdx.x & 7;
        const int gi = xcd * 588 + (blockIdx.x >> 3);
        m0 = (gi >> 3) << 7;
        ch8 = gi & 7;
        n0 = ch8 << 6;
    } else {
        m0 = blockIdx.y * BM;
        n0 = blockIdx.x << 6;
    }
    const short* A1b = (const short*)A1f;
    const short* A2b = (const short*)A2f;
    const int Ktot = k1 + k2;
    const int nt = (Ktot + KTILE - 1) / KTILE;
    const int lane = tid & 63, wave = tid >> 6;
    const int wr = (wave >> 1) * (BM >> 1);
    const int wc = (wave & 1) << 5;
    const int l15 = lane & 15, lh = lane >> 4;
    const int rowA = (BM == 128) ? (tid >> 1) : (tid >> 2);
    const int kA   = (BM == 128) ? ((tid & 1) << 4) : ((tid & 3) << 3);
    const int rgA = min(m0 + rowA, M - 1);
    const int rowW = tid >> 2, kW = (tid & 3) << 3;
    const int ngW = min(n0 + rowW, N - 1);

    f32x4 acc[MF][2];
#pragma unroll
    for (int m = 0; m < MF; ++m)
#pragma unroll
        for (int n = 0; n < 2; ++n) acc[m][n] = (f32x4){0.f, 0.f, 0.f, 0.f};

    short8 aS0, aS1, wS;
    auto loadA = [&](int t) {
        constexpr int AE = (BM == 128) ? 16 : 8;
        const int k0 = t * KTILE + kA;
        if (k0 + AE <= k1) {
            if (abits & 1) {
                const short* p = A1b + (size_t)rgA * lda1 + k0;
                aS0 = *(const short8*)p;
                if constexpr (BM == 128) aS1 = *(const short8*)(p + 8);
            } else {
                const float* p = A1f + (size_t)rgA * lda1 + k0;
                float4 v0 = *(const float4*)p, v1 = *(const float4*)(p + 4);
                float t0[8] = {v0.x, v0.y, v0.z, v0.w, v1.x, v1.y, v1.z, v1.w};
                aS0 = cvt8(t0);
                if constexpr (BM == 128) {
                    float4 v2 = *(const float4*)(p + 8), v3 = *(const float4*)(p + 12);
                    float t1[8] = {v2.x, v2.y, v2.z, v2.w, v3.x, v3.y, v3.z, v3.w};
                    aS1 = cvt8(t1);
                }
            }
        } else if (k0 >= k1 && k0 + AE <= Ktot) {
            const int kk = k0 - k1;
            if (abits & 2) {
                const short* p = A2b + (size_t)rgA * lda2 + kk;
                aS0 = *(const short8*)p;
                if constexpr (BM == 128) aS1 = *(const short8*)(p + 8);
            } else {
                const float* p = A2f + (size_t)rgA * lda2 + kk;
                float4 v0 = *(const float4*)p, v1 = *(const float4*)(p + 4);
                float t0[8] = {v0.x, v0.y, v0.z, v0.w, v1.x, v1.y, v1.z, v1.w};
                aS0 = cvt8(t0);
                if constexpr (BM == 128) {
                    float4 v2 = *(const float4*)(p + 8), v3 = *(const float4*)(p + 12);
                    float t1[8] = {v2.x, v2.y, v2.z, v2.w, v3.x, v3.y, v3.z, v3.w};
                    aS1 = cvt8(t1);
                }
            }
        } else {
            float tmp[(BM == 128) ? 16 : 8];
#pragma unroll
            for (int e = 0; e < ((BM == 128) ? 16 : 8); ++e) {
                const int kg = k0 + e;
                float v = 0.f;
                if (kg < k1) v = (abits & 1) ? bf2f(A1b[(size_t)rgA * lda1 + kg]) : A1f[(size_t)rgA * lda1 + kg];
                else if (kg < Ktot) v = (abits & 2) ? bf2f(A2b[(size_t)rgA * lda2 + (kg - k1)]) : A2f[(size_t)rgA * lda2 + (kg - k1)];
                tmp[e] = v;
            }
            aS0 = cvt8(tmp);
            if constexpr (BM == 128) aS1 = cvt8(tmp + 8);
        }
    };
    auto loadW = [&](int t) {
        const int k0 = t * KTILE + kW;
        if (k0 + 8 <= k1) {
            wS = *(const short8*)&W1[(size_t)ngW * ldw1 + k0];
        } else if (k0 >= k1 && k0 + 8 <= Ktot) {
            wS = *(const short8*)&W2[(size_t)ngW * ldw2 + (k0 - k1)];
        } else {
            short8 w;
#pragma unroll
            for (int e = 0; e < 8; ++e) {
                const int kg = k0 + e;
                w[e] = (kg < k1) ? W1[(size_t)ngW * ldw1 + kg]
                                 : ((kg < Ktot) ? W2[(size_t)ngW * ldw2 + (kg - k1)] : (short)0);
            }
            wS = w;
        }
    };
    auto writeS = [&](int buf) {
        *(short8*)&sA[buf][rowA][kA] = aS0;
        if constexpr (BM == 128) *(short8*)&sA[buf][rowA][kA + 8] = aS1;
        *(short8*)&sB[buf][rowW][kW] = wS;
    };

    loadA(0); loadW(0); writeS(0);
    __syncthreads();
    for (int t = 0; t < nt; ++t) {
        const int cur = t & 1;
        if (t + 1 < nt) { loadA(t + 1); loadW(t + 1); }
        short8 af[MF], bfv[2];
#pragma unroll
        for (int m = 0; m < MF; ++m)
            af[m] = *(const short8*)&sA[cur][wr + (m << 4) + l15][lh << 3];
#pragma unroll
        for (int n = 0; n < 2; ++n)
            bfv[n] = *(const short8*)&sB[cur][wc + (n << 4) + l15][lh << 3];
#pragma unroll
        for (int m = 0; m < MF; ++m)
#pragma unroll
            for (int n = 0; n < 2; ++n)
                acc[m][n] = __builtin_amdgcn_mfma_f32_16x16x32_bf16(af[m], bfv[n], acc[m][n], 0, 0, 0);
        if (t + 1 < nt) writeS(cur ^ 1);
        __syncthreads();
    }

    if (mode == 0) {
#pragma unroll
        for (int m = 0; m < MF; ++m) {
#pragma unroll
            for (int j = 0; j < 4; ++j) {
                const int r = m0 + wr + (m << 4) + (lh << 2) + j;
                if (r >= M) continue;
#pragma unroll
                for (int n = 0; n < 2; ++n) {
                    const int c = n0 + wc + (n << 4) + l15;
                    if (c >= N) continue;
                    float v = acc[m][n][j];
                    if (bias1) v += bias1[c];
                    if (do_relu) v = fmaxf(v, 0.f);
                    if (mulvec) v *= mulvec[c];
                    if (mul) v *= mul[(size_t)r * ldc + c];
                    if (c_bf16) {
                        __hip_bfloat16 b = __float2bfloat16(v);
                        ((short*)C)[(size_t)r * ldc + c] = *(short*)&b;
                    } else {
                        C[(size_t)r * ldc + c] = v;
                    }
                }
            }
        }
    } else {
#pragma unroll
        for (int m = 0; m < MF; ++m) {
#pragma unroll
            for (int j = 0; j < 4; ++j) {
                const int rloc = wr + (m << 4) + (lh << 2) + j;
                const int r = m0 + rloc;
                const size_t sqbase = (size_t)(r / 49) * ldc;
                float s = 0.f;
#pragma unroll
                for (int n = 0; n < 2; ++n) {
                    const int c = n0 + wc + (n << 4) + l15;
                    float v = acc[m][n][j] + bias1[c];
                    v = fmaxf(v, 0.f);
                    s += v * mul[sqbase + c];
                }
                s += __shfl_xor(s, 1, 64);
                s += __shfl_xor(s, 2, 64);
                s += __shfl_xor(s, 4, 64);
                s += __shfl_xor(s, 8, 64);
                if (l15 == 0) sred[rloc][wc >> 5] = s;
            }
        }
        __syncthreads();
        if (tid < BM)
            C[(size_t)(m0 + tid) * 8 + ch8] = sred[tid][0] + sred[tid][1];
    }
}

// ---------------- glds GEMM, 64x64, KT=64: all-bf16, tile-aligned concat A ----------------
__global__ __launch_bounds__(256)
void mfma_glds64_kernel(const short* __restrict__ A1, const short* __restrict__ A2,
                        int lda, int k1, const short* __restrict__ W, int ldw,
                        const float* __restrict__ bias, const float* __restrict__ mulvec,
                        float* __restrict__ C, int ldc, int Ktot, int do_relu, int c_bf16)
{
    __shared__ short sA[2][64][64];
    __shared__ short sB[2][64][64];
    const int tid = threadIdx.x;
    const int m0 = blockIdx.y << 6, n0 = blockIdx.x << 6;
    const int lane = tid & 63, wave = tid >> 6;
    const int wr = (wave >> 1) << 5, wc = (wave & 1) << 5;
    const int l15 = lane & 15, lh = lane >> 4;
    const int lr = lane >> 3;
    const int sc = (lane & 7) ^ lr;
    const int nt = Ktot >> 6;
    const int t1 = k1 >> 6;

    f32x4 acc[2][2];
#pragma unroll
    for (int m = 0; m < 2; ++m)
#pragma unroll
        for (int n = 0; n < 2; ++n) acc[m][n] = (f32x4){0.f, 0.f, 0.f, 0.f};

    auto stage = [&](int t, int buf) {
        const short* Ab = (t < t1) ? A1 : A2;
        const int kb = ((t < t1) ? t : (t - t1)) << 6;
#pragma unroll
        for (int j = 0; j < 2; ++j) {
            const int r0 = (wave << 4) + (j << 3);
            gload16(Ab + (size_t)(m0 + r0 + lr) * lda + kb + (sc << 3), &sA[buf][r0][0]);
        }
#pragma unroll
        for (int j = 0; j < 2; ++j) {
            const int r0 = (wave << 4) + (j << 3);
            gload16(W + (size_t)(n0 + r0 + lr) * ldw + (t << 6) + (sc << 3), &sB[buf][r0][0]);
        }
    };

    stage(0, 0);
    __syncthreads();
    for (int t = 0; t < nt; ++t) {
        const int cur = t & 1;
        if (t + 1 < nt) stage(t + 1, cur ^ 1);
#pragma unroll
        for (int kk = 0; kk < 2; ++kk) {
            const int rd = (((kk << 2) + lh) ^ (l15 & 7)) << 3;
            short8 af[2], bfv[2];
#pragma unroll
            for (int m = 0; m < 2; ++m)
                af[m] = *(const short8*)&sA[cur][wr + (m << 4) + l15][rd];
#pragma unroll
            for (int n = 0; n < 2; ++n)
                bfv[n] = *(const short8*)&sB[cur][wc + (n << 4) + l15][rd];
#pragma unroll
            for (int m = 0; m < 2; ++m)
#pragma unroll
                for (int n = 0; n < 2; ++n)
                    acc[m][n] = __builtin_amdgcn_mfma_f32_16x16x32_bf16(af[m], bfv[n], acc[m][n], 0, 0, 0);
        }
        __syncthreads();
    }

#pragma unroll
    for (int m = 0; m < 2; ++m) {
#pragma unroll
        for (int j = 0; j < 4; ++j) {
            const int r = m0 + wr + (m << 4) + (lh << 2) + j;
#pragma unroll
            for (int n = 0; n < 2; ++n) {
                const int c = n0 + wc + (n << 4) + l15;
                float v = acc[m][n][j];
                if (bias) v += bias[c];
                if (do_relu) v = fmaxf(v, 0.f);
                if (mulvec) v *= mulvec[c];
                if (c_bf16) {
                    __hip_bfloat16 b = __float2bfloat16(v);
                    ((short*)C)[(size_t)r * ldc + c] = *(short*)&b;
                } else {
                    C[(size_t)r * ldc + c] = v;
                }
            }
        }
    }
}

// ---------------- glds GEMM, 128x64, KT=64 (g-chain, M multiple of 128) ----------------
__global__ __launch_bounds__(256)
void mfma_glds128_kernel(const short* __restrict__ A, int lda,
                         const short* __restrict__ W, int ldw,
                         const float* __restrict__ bias,
                         float* __restrict__ C, int ldc, int Ktot, int do_relu, int c_bf16)
{
    __shared__ short sA[2][128][64];
    __shared__ short sB[2][64][64];
    const int tid = threadIdx.x;
    const int m0 = blockIdx.y << 7, n0 = blockIdx.x << 6;
    const int lane = tid & 63, wave = tid >> 6;
    const int wr = (wave >> 1) << 6, wc = (wave & 1) << 5;
    const int l15 = lane & 15, lh = lane >> 4;
    const int lr = lane >> 3;
    const int sc = (lane & 7) ^ lr;
    const int nt = Ktot >> 6;

    f32x4 acc[4][2];
#pragma unroll
    for (int m = 0; m < 4; ++m)
#pragma unroll
        for (int n = 0; n < 2; ++n) acc[m][n] = (f32x4){0.f, 0.f, 0.f, 0.f};

    auto stage = [&](int t, int buf) {
        const int kb = t << 6;
#pragma unroll
        for (int j = 0; j < 4; ++j) {
            const int r0 = (wave << 5) + (j << 3);
            gload16(A + (size_t)(m0 + r0 + lr) * lda + kb + (sc << 3), &sA[buf][r0][0]);
        }
#pragma unroll
        for (int j = 0; j < 2; ++j) {
            const int r0 = (wave << 4) + (j << 3);
            gload16(W + (size_t)(n0 + r0 + lr) * ldw + kb + (sc << 3), &sB[buf][r0][0]);
        }
    };

    stage(0, 0);
    __syncthreads();
    for (int t = 0; t < nt; ++t) {
        const int cur = t & 1;
        if (t + 1 < nt) stage(t + 1, cur ^ 1);
#pragma unroll
        for (int kk = 0; kk < 2; ++kk) {
            const int rd = (((kk << 2) + lh) ^ (l15 & 7)) << 3;
            short8 af[4], bfv[2];
#pragma unroll
            for (int m = 0; m < 4; ++m)
                af[m] = *(const short8*)&sA[cur][wr + (m << 4) + l15][rd];
#pragma unroll
            for (int n = 0; n < 2; ++n)
                bfv[n] = *(const short8*)&sB[cur][wc + (n << 4) + l15][rd];
#pragma unroll
            for (int m = 0; m < 4; ++m)
#pragma unroll
                for (int n = 0; n < 2; ++n)
                    acc[m][n] = __builtin_amdgcn_mfma_f32_16x16x32_bf16(af[m], bfv[n], acc[m][n], 0, 0, 0);
        }
        __syncthreads();
    }

#pragma unroll
    for (int m = 0; m < 4; ++m) {
#pragma unroll
        for (int j = 0; j < 4; ++j) {
            const int r = m0 + wr + (m << 4) + (lh << 2) + j;
#pragma unroll
            for (int n = 0; n < 2; ++n) {
                const int c = n0 + wc + (n << 4) + l15;
                float v = acc[m][n][j];
                if (bias) v += bias[c];
                if (do_relu) v = fmaxf(v, 0.f);
                if (c_bf16) {
                    __hip_bfloat16 b = __float2bfloat16(v);
                    ((short*)C)[(size_t)r * ldc + c] = *(short*)&b;
                } else {
                    C[(size_t)r * ldc + c] = v;
                }
            }
        }
    }
}

// ---------------- attn logits, 128x64, KT=64, glds + swizzle (4704 blocks) ----------------
__global__ __launch_bounds__(256)
void attn_logits3_kernel(const short* __restrict__ imgb, const short* __restrict__ vW,
                         const float* __restrict__ vb, const float* __restrict__ swq,
                         float* __restrict__ partial)
{
    __shared__ short sA[2][128][64];
    __shared__ short sB[2][64][64];
    __shared__ float sred[128][2];
    const int tid = threadIdx.x;
    const int lane = tid & 63, wave = tid >> 6;
    const int xcd = blockIdx.x & 7;
    const int gi = xcd * 588 + (blockIdx.x >> 3);
    const int m0 = (gi >> 3) << 7;
    const int ch8 = gi & 7;
    const int n0 = ch8 << 6;
    const int wr = (wave >> 1) << 6;
    const int wc = (wave & 1) << 5;
    const int l15 = lane & 15, lh = lane >> 4;
    const int lr = lane >> 3;
    const int sc = (lane & 7) ^ lr;

    f32x4 acc[4][2];
#pragma unroll
    for (int m = 0; m < 4; ++m)
#pragma unroll
        for (int n = 0; n < 2; ++n) acc[m][n] = (f32x4){0.f, 0.f, 0.f, 0.f};

    auto stage = [&](int t, int buf) {
        const int kb = t << 6;
#pragma unroll
        for (int j = 0; j < 4; ++j) {
            const int r0 = (wave << 5) + (j << 3);
            gload16(imgb + (size_t)(m0 + r0 + lr) * 512 + kb + (sc << 3), &sA[buf][r0][0]);
        }
#pragma unroll
        for (int j = 0; j < 2; ++j) {
            const int r0 = (wave << 4) + (j << 3);
            gload16(vW + (size_t)(n0 + r0 + lr) * 512 + kb + (sc << 3), &sB[buf][r0][0]);
        }
    };

    stage(0, 0);
    __syncthreads();
    for (int t = 0; t < 8; ++t) {
        const int cur = t & 1;
        if (t + 1 < 8) stage(t + 1, cur ^ 1);
#pragma unroll
        for (int kk = 0; kk < 2; ++kk) {
            const int rd = (((kk << 2) + lh) ^ (l15 & 7)) << 3;
            short8 af[4], bfv[2];
#pragma unroll
            for (int m = 0; m < 4; ++m)
                af[m] = *(const short8*)&sA[cur][wr + (m << 4) + l15][rd];
#pragma unroll
            for (int n = 0; n < 2; ++n)
                bfv[n] = *(const short8*)&sB[cur][wc + (n << 4) + l15][rd];
#pragma unroll
            for (int m = 0; m < 4; ++m)
#pragma unroll
                for (int n = 0; n < 2; ++n)
                    acc[m][n] = __builtin_amdgcn_mfma_f32_16x16x32_bf16(af[m], bfv[n], acc[m][n], 0, 0, 0);
        }
        __syncthreads();
    }

#pragma unroll
    for (int m = 0; m < 4; ++m) {
#pragma unroll
        for (int j = 0; j < 4; ++j) {
            const int rloc = wr + (m << 4) + (lh << 2) + j;
            const int r = m0 + rloc;
            const size_t sqbase = (size_t)(r / 49) * 512;
            float s = 0.f;
#pragma unroll
            for (int n = 0; n < 2; ++n) {
                const int c = n0 + wc + (n << 4) + l15;
                float v = acc[m][n][j] + vb[c];
                v = fmaxf(v, 0.f);
                s += v * swq[sqbase + c];
            }
            s += __shfl_xor(s, 1, 64);
            s += __shfl_xor(s, 2, 64);
            s += __shfl_xor(s, 4, 64);
            s += __shfl_xor(s, 8, 64);
            if (l15 == 0) sred[rloc][wc >> 5] = s;
        }
    }
    __syncthreads();
    if (tid < 128)
        partial[(size_t)(m0 + tid) * 8 + ch8] = sred[tid][0] + sred[tid][1];
}

// ---------------- reg-staged 64x64 KT=64 GEMM (fp32-A / ragged-N cases) ----------------
__global__ __launch_bounds__(256)
void mfma_gemm64_kernel(const float* __restrict__ A1f, int lda1, int k1,
                        const short* __restrict__ W1, int ldw1,
                        const float* __restrict__ A2f, int lda2, int k2,
                        const short* __restrict__ W2, int ldw2,
                        const float* __restrict__ bias1,
                        const float* __restrict__ mulvec, const float* __restrict__ mul,
                        float* __restrict__ C, int ldc, int M, int N,
                        int do_relu, int abits, int c_bf16)
{
    __shared__ short sA[2][64][LSTR64];
    __shared__ short sB[2][64][LSTR64];
    const int tid = threadIdx.x;
    const int m0 = blockIdx.y << 6, n0 = blockIdx.x << 6;
    const short* A1b = (const short*)A1f;
    const short* A2b = (const short*)A2f;
    const int Ktot = k1 + k2;
    const int nt = (Ktot + 63) >> 6;
    const int lane = tid & 63, wave = tid >> 6;
    const int wr = (wave >> 1) << 5, wc = (wave & 1) << 5;
    const int l15 = lane & 15, lh = lane >> 4;
    const int srow = tid >> 2, skq = (tid & 3) << 4;
    const int rgA = min(m0 + srow, M - 1);
    const int ngW = min(n0 + srow, N - 1);

    f32x4 acc[2][2];
#pragma unroll
    for (int m = 0; m < 2; ++m)
#pragma unroll
        for (int n = 0; n < 2; ++n) acc[m][n] = (f32x4){0.f, 0.f, 0.f, 0.f};

    short8 aS0, aS1, wS0, wS1;
    auto loadA = [&](int t) {
        const int k0 = (t << 6) + skq;
        if (k0 + 16 <= k1) {
            if (abits & 1) {
                const short* p = A1b + (size_t)rgA * lda1 + k0;
                aS0 = *(const short8*)p; aS1 = *(const short8*)(p + 8);
            } else {
                const float* p = A1f + (size_t)rgA * lda1 + k0;
                float4 v0 = *(const float4*)p, v1 = *(const float4*)(p + 4);
                float4 v2 = *(const float4*)(p + 8), v3 = *(const float4*)(p + 12);
                float t0[8] = {v0.x, v0.y, v0.z, v0.w, v1.x, v1.y, v1.z, v1.w};
                float t1[8] = {v2.x, v2.y, v2.z, v2.w, v3.x, v3.y, v3.z, v3.w};
                aS0 = cvt8(t0); aS1 = cvt8(t1);
            }
        } else if (k0 >= k1 && k0 + 16 <= Ktot) {
            const int kk = k0 - k1;
            if (abits & 2) {
                const short* p = A2b + (size_t)rgA * lda2 + kk;
                aS0 = *(const short8*)p; aS1 = *(const short8*)(p + 8);
            } else {
                const float* p = A2f + (size_t)rgA * lda2 + kk;
                float4 v0 = *(const float4*)p, v1 = *(const float4*)(p + 4);
                float4 v2 = *(const float4*)(p + 8), v3 = *(const float4*)(p + 12);
                float t0[8] = {v0.x, v0.y, v0.z, v0.w, v1.x, v1.y, v1.z, v1.w};
                float t1[8] = {v2.x, v2.y, v2.z, v2.w, v3.x, v3.y, v3.z, v3.w};
                aS0 = cvt8(t0); aS1 = cvt8(t1);
            }
        } else {
            float tmp[16];
#pragma unroll
            for (int e = 0; e < 16; ++e) {
                const int kg = k0 + e;
                float v = 0.f;
                if (kg < k1) v = (abits & 1) ? bf2f(A1b[(size_t)rgA * lda1 + kg]) : A1f[(size_t)rgA * lda1 + kg];
                else if (kg < Ktot) v = (abits & 2) ? bf2f(A2b[(size_t)rgA * lda2 + (kg - k1)]) : A2f[(size_t)rgA * lda2 + (kg - k1)];
                tmp[e] = v;
            }
            aS0 = cvt8(tmp); aS1 = cvt8(tmp + 8);
        }
    };
    auto loadW = [&](int t) {
        const int k0 = (t << 6) + skq;
        if (k0 + 16 <= k1) {
            const short* p = W1 + (size_t)ngW * ldw1 + k0;
            wS0 = *(const short8*)p; wS1 = *(const short8*)(p + 8);
        } else if (k0 >= k1 && k0 + 16 <= Ktot) {
            const short* p = W2 + (size_t)ngW * ldw2 + (k0 - k1);
            wS0 = *(const short8*)p; wS1 = *(const short8*)(p + 8);
        } else {
            short8 w0, w1;
#pragma unroll
            for (int e = 0; e < 16; ++e) {
                const int kg = k0 + e;
                short v = (kg < k1) ? W1[(size_t)ngW * ldw1 + kg]
                                    : ((kg < Ktot) ? W2[(size_t)ngW * ldw2 + (kg - k1)] : (short)0);
                if (e < 8) w0[e] = v; else w1[e - 8] = v;
            }
            wS0 = w0; wS1 = w1;
        }
    };
    auto writeS = [&](int buf) {
        *(short8*)&sA[buf][srow][skq] = aS0;
        *(short8*)&sA[buf][srow][skq + 8] = aS1;
        *(short8*)&sB[buf][srow][skq] = wS0;
        *(short8*)&sB[buf][srow][skq + 8] = wS1;
    };

    loadA(0); loadW(0); writeS(0);
    __syncthreads();
    for (int t = 0; t < nt; ++t) {
        const int cur = t & 1;
        if (t + 1 < nt) { loadA(t + 1); loadW(t + 1); }
#pragma unroll
        for (int kk = 0; kk < 2; ++kk) {
            short8 af[2], bfv[2];
#pragma unroll
            for (int m = 0; m < 2; ++m)
                af[m] = *(const short8*)&sA[cur][wr + (m << 4) + l15][(kk << 5) + (lh << 3)];
#pragma unroll
            for (int n = 0; n < 2; ++n)
                bfv[n] = *(const short8*)&sB[cur][wc + (n << 4) + l15][(kk << 5) + (lh << 3)];
#pragma unroll
            for (int m = 0; m < 2; ++m)
#pragma unroll
                for (int n = 0; n < 2; ++n)
                    acc[m][n] = __builtin_amdgcn_mfma_f32_16x16x32_bf16(af[m], bfv[n], acc[m][n], 0, 0, 0);
        }
        if (t + 1 < nt) writeS(cur ^ 1);
        __syncthreads();
    }

#pragma unroll
    for (int m = 0; m < 2; ++m) {
#pragma unroll
        for (int j = 0; j < 4; ++j) {
            const int r = m0 + wr + (m << 4) + (lh << 2) + j;
            if (r >= M) continue;
#pragma unroll
            for (int n = 0; n < 2; ++n) {
                const int c = n0 + wc + (n << 4) + l15;
                if (c >= N) continue;
                float v = acc[m][n][j];
                if (bias1) v += bias1[c];
                if (do_relu) v = fmaxf(v, 0.f);
                if (mulvec) v *= mulvec[c];
                if (mul) v *= mul[(size_t)r * ldc + c];
                if (c_bf16) {
                    __hip_bfloat16 b = __float2bfloat16(v);
                    ((short*)C)[(size_t)r * ldc + c] = *(short*)&b;
                } else {
                    C[(size_t)r * ldc + c] = v;
                }
            }
        }
    }
}

// ---------------- weight bf16 pre-conversion ----------------
__global__ __launch_bounds__(256)
void wcvt_kernel(const float* __restrict__ proj, const float* __restrict__ qW,
                 const float* __restrict__ vW, const float* __restrict__ qnet,
                 const float* __restrict__ vnet, const float* __restrict__ cls1,
                 const float* __restrict__ cls2, const float* __restrict__ g0,
                 const float* __restrict__ g1, const float* __restrict__ g2,
                 const float* __restrict__ g3, const float* __restrict__ f0,
                 const float* __restrict__ f1, short* __restrict__ dst)
{
    size_t idx = ((size_t)blockIdx.x * 256 + threadIdx.x) * 8;
    if (idx >= 5981184) return;
    const float* s;
    if (idx < 524288) s = proj + idx;
    else if (idx < 786432) s = qW + (idx - 524288);
    else if (idx < 1048576) s = vW + (idx - 786432);
    else if (idx < 1310720) s = qnet + (idx - 1048576);
    else if (idx < 1572864) s = vnet + (idx - 1310720);
    else if (idx < 2097152) s = cls1 + (idx - 1572864);
    else if (idx < 4146176) s = cls2 + (idx - 2097152);
    else if (idx < 4670464) {
        size_t li = idx - 4146176;
        int c = (int)(li >> 9), k = (int)(li & 511);
        s = (c < 512) ? g0 + (size_t)c * 1024 + k
                      : g0 + (size_t)(c - 512) * 1024 + 512 + k;
    }
    else if (idx < 4932608) s = g1 + (idx - 4670464);
    else if (idx < 5194752) s = g2 + (idx - 4932608);
    else if (idx < 5456896) s = g3 + (idx - 5194752);
    else if (idx < 5719040) s = f0 + (idx - 5456896);
    else s = f1 + (idx - 5719040);
    float4 a = *(const float4*)s, b = *(const float4*)(s + 4);
    float t[8] = {a.x, a.y, a.z, a.w, b.x, b.y, b.z, b.w};
    *(short8*)(dst + idx) = cvt8(t);
}

// ---------------- LSTM weight reorder ([2048][832] bf16, gate-permuted) ----------------
__global__ __launch_bounds__(256)
void lstm_reorder_kernel(const float* __restrict__ Wih, const float* __restrict__ Whh,
                         const float* __restrict__ bih, const float* __restrict__ bhh,
                         short* __restrict__ Wbf, float* __restrict__ bias_perm)
{
    int id = blockIdx.x * 256 + threadIdx.x;   // < 2048*512
    int c = id >> 9, k = id & 511;
    int src = (c & 3) * 512 + (c >> 2);
    {
        __hip_bfloat16 b = __float2bfloat16(Whh[(size_t)src * 512 + k]);
        Wbf[(size_t)c * 832 + k] = *(short*)&b;
    }
    if (k < 300) {
        __hip_bfloat16 b = __float2bfloat16(Wih[(size_t)src * 300 + k]);
        Wbf[(size_t)c * 832 + 512 + k] = *(short*)&b;
    } else if (k < 320) {
        Wbf[(size_t)c * 832 + 512 + k] = 0;
    }
    if (k == 0) bias_perm[c] = bih[src] + bhh[src];
}

// padded bf16 embedding table: embp[10000][320] (cols 300..319 = 0)
__global__ __launch_bounds__(256)
void embcvt_kernel(const float* __restrict__ qword, short* __restrict__ embp)
{
    int id = blockIdx.x * 256 + threadIdx.x;   // < 3,200,000
    if (id >= 3200000) return;
    int r = id / 320, c = id % 320;
    float v = (c < 300) ? qword[(size_t)r * 300 + c] : 0.f;
    __hip_bfloat16 b = __float2bfloat16(v);
    embp[id] = *(short*)&b;
}

// ---------------- LSTM step, 64x64, KT=64, glds + swizzle ----------------
__global__ __launch_bounds__(256)
void lstm_step6_kernel(const short* __restrict__ hF_in, const short* __restrict__ hB_in,
                       const short* __restrict__ WbfF, const short* __restrict__ WbfB,
                       const float* __restrict__ biasF, const float* __restrict__ biasB,
                       const short* __restrict__ embp, const int* __restrict__ toks,
                       int tF, int tB, int first,
                       short* __restrict__ hF_out, short* __restrict__ hB_out,
                       float* __restrict__ cF, float* __restrict__ cB)
{
    __shared__ short sA[2][64][64];
    __shared__ short sB[2][64][64];
    const int dir = blockIdx.z;
    const short* h_in = dir ? hB_in : hF_in;
    const short* Wbf  = dir ? WbfB : WbfF;
    const float* bias_perm = dir ? biasB : biasF;
    short* h_out  = dir ? hB_out : hF_out;
    float* cstate = dir ? cB : cF;
    const int tt = dir ? tB : tF;

    const int tid = threadIdx.x;
    const int m0 = blockIdx.y << 6;
    const int n0 = blockIdx.x << 6;
    const int lane = tid & 63, wave = tid >> 6;
    const int wr = (wave >> 1) << 5, wc = (wave & 1) << 5;
    const int l15 = lane & 15, lh = lane >> 4;
    const int lr = lane >> 3;
    const int sc = (lane & 7) ^ lr;

    f32x4 acc[2][2];
#pragma unroll
    for (int m = 0; m < 2; ++m)
#pragma unroll
        for (int n = 0; n < 2; ++n) acc[m][n] = (f32x4){0.f, 0.f, 0.f, 0.f};

    auto stage = [&](int t, int buf) {
#pragma unroll
        for (int j = 0; j < 2; ++j) {
            const int r0 = (wave << 4) + (j << 3);
            const int grow = m0 + r0 + lr;
            const short* g;
            if (t < 8) {
                g = h_in + (size_t)grow * 512 + (t << 6) + (sc << 3);
            } else {
                const int ar = toks[grow * 10 + tt];
                g = embp + (size_t)ar * 320 + ((t - 8) << 6) + (sc << 3);
            }
            gload16(g, &sA[buf][r0][0]);
        }
#pragma unroll
        for (int j = 0; j < 2; ++j) {
            const int r0 = (wave << 4) + (j << 3);
            gload16(Wbf + (size_t)(n0 + r0 + lr) * 832 + (t << 6) + (sc << 3), &sB[buf][r0][0]);
        }
    };

    stage(0, 0);
    __syncthreads();
    for (int t = 0; t < 13; ++t) {
        const int cur = t & 1;
        if (t + 1 < 13) stage(t + 1, cur ^ 1);
#pragma unroll
        for (int kk = 0; kk < 2; ++kk) {
            const int rd = (((kk << 2) + lh) ^ (l15 & 7)) << 3;
            short8 af[2], bfv[2];
#pragma unroll
            for (int m = 0; m < 2; ++m)
                af[m] = *(const short8*)&sA[cur][wr + (m << 4) + l15][rd];
#pragma unroll
            for (int n = 0; n < 2; ++n)
                bfv[n] = *(const short8*)&sB[cur][wc + (n << 4) + l15][rd];
#pragma unroll
            for (int m = 0; m < 2; ++m)
#pragma unroll
                for (int n = 0; n < 2; ++n)
                    acc[m][n] = __builtin_amdgcn_mfma_f32_16x16x32_bf16(af[m], bfv[n], acc[m][n], 0, 0, 0);
        }
        __syncthreads();
    }

#pragma unroll
    for (int n = 0; n < 2; ++n) {
        const int ccol = n0 + wc + (n << 4) + l15;
        const float bb = bias_perm[ccol];
        const int u = ccol >> 2;
#pragma unroll
        for (int m = 0; m < 2; ++m) {
#pragma unroll
            for (int j = 0; j < 4; ++j) {
                const int r = m0 + wr + (m << 4) + (lh << 2) + j;
                float v = acc[m][n][j] + bb;
                const int base = lane & ~3;
                float gi = __shfl(v, base, 64);
                float gf = __shfl(v, base | 1, 64);
                float gg = __shfl(v, base | 2, 64);
                float go = __shfl(v, base | 3, 64);
                if ((lane & 3) == 0) {
                    float si = 1.f / (1.f + expf(-gi));
                    float sf = 1.f / (1.f + expf(-gf));
                    float so = 1.f / (1.f + expf(-go));
                    size_t idx = ((size_t)r << 9) + u;
                    float cold = first ? 0.f : cstate[idx];
                    float cv = sf * cold + si * tanhf(gg);
                    cstate[idx] = cv;
                    float hv = so * tanhf(cv);
                    __hip_bfloat16 b = __float2bfloat16(hv);
                    h_out[idx] = *(short*)&b;
                }
            }
        }
    }
}

// ---------------- LSTM step fallback (reg-staged, KT=64) ----------------
__global__ __launch_bounds__(256)
void lstm_step4_kernel(const short* __restrict__ hF_in, const short* __restrict__ hB_in,
                       const short* __restrict__ WbfF, const short* __restrict__ WbfB,
                       const float* __restrict__ biasF, const float* __restrict__ biasB,
                       const float* __restrict__ emb, const int* __restrict__ toks,
                       int tF, int tB, int first,
                       short* __restrict__ hF_out, short* __restrict__ hB_out,
                       float* __restrict__ cF, float* __restrict__ cB)
{
    __shared__ short sA[2][64][LSTR64];
    __shared__ short sB[2][64][LSTR64];
    const int dir = blockIdx.z;
    const short* h_in = dir ? hB_in : hF_in;
    const short* Wbf  = dir ? WbfB : WbfF;
    const float* bias_perm = dir ? biasB : biasF;
    short* h_out  = dir ? hB_out : hF_out;
    float* cstate = dir ? cB : cF;
    const int tt = dir ? tB : tF;

    const int tid = threadIdx.x;
    const int m0 = blockIdx.y << 6;
    const int n0 = blockIdx.x << 6;
    const int lane = tid & 63, wave = tid >> 6;
    const int wr = (wave >> 1) << 5, wc = (wave & 1) << 5;
    const int l15 = lane & 15, lh = lane >> 4;
    const int srow = tid >> 2, skq = (tid & 3) << 4;
    const int rgA = m0 + srow;
    const int ngW = n0 + srow;
    const int nt = 13;
    const int arow = toks[rgA * 10 + tt];

    f32x4 acc[2][2];
#pragma unroll
    for (int m = 0; m < 2; ++m)
#pragma unroll
        for (int n = 0; n < 2; ++n) acc[m][n] = (f32x4){0.f, 0.f, 0.f, 0.f};

    short8 aS0, aS1, wS0, wS1;
    auto loadA = [&](int t) {
        const int k0 = (t << 6) + skq;
        if (k0 + 16 <= 512) {
            if (first) { short8 z = {0,0,0,0,0,0,0,0}; aS0 = z; aS1 = z; }
            else {
                const short* p = h_in + (size_t)rgA * 512 + k0;
                aS0 = *(const short8*)p; aS1 = *(const short8*)(p + 8);
            }
        } else if (k0 >= 512 && k0 + 16 <= 812) {
            const float* p = emb + (size_t)arow * 300 + (k0 - 512);
            float4 v0 = *(const float4*)p, v1 = *(const float4*)(p + 4);
            float4 v2 = *(const float4*)(p + 8), v3 = *(const float4*)(p + 12);
            float t0[8] = {v0.x, v0.y, v0.z, v0.w, v1.x, v1.y, v1.z, v1.w};
            float t1[8] = {v2.x, v2.y, v2.z, v2.w, v3.x, v3.y, v3.z, v3.w};
            aS0 = cvt8(t0); aS1 = cvt8(t1);
        } else {
            float tmp[16];
#pragma unroll
            for (int e = 0; e < 16; ++e) {
                const int kg = k0 + e;
                float v = 0.f;
                if (kg < 512) v = first ? 0.f : bf2f(h_in[(size_t)rgA * 512 + kg]);
                else if (kg < 812) v = emb[(size_t)arow * 300 + (kg - 512)];
                tmp[e] = v;
            }
            aS0 = cvt8(tmp); aS1 = cvt8(tmp + 8);
        }
    };
    auto loadW = [&](int t) {
        const short* p = Wbf + (size_t)ngW * 832 + (t << 6) + skq;
        wS0 = *(const short8*)p; wS1 = *(const short8*)(p + 8);
    };
    auto writeS = [&](int buf) {
        *(short8*)&sA[buf][srow][skq] = aS0;
        *(short8*)&sA[buf][srow][skq + 8] = aS1;
        *(short8*)&sB[buf][srow][skq] = wS0;
        *(short8*)&sB[buf][srow][skq + 8] = wS1;
    };

    loadA(0); loadW(0); writeS(0);
    __syncthreads();
    for (int t = 0; t < nt; ++t) {
        const int cur = t & 1;
        if (t + 1 < nt) { loadA(t + 1); loadW(t + 1); }
#pragma unroll
        for (int kk = 0; kk < 2; ++kk) {
            short8 af[2], bfv[2];
#pragma unroll
            for (int m = 0; m < 2; ++m)
                af[m] = *(const short8*)&sA[cur][wr + (m << 4) + l15][(kk << 5) + (lh << 3)];
#pragma unroll
            for (int n = 0; n < 2; ++n)
                bfv[n] = *(const short8*)&sB[cur][wc + (n << 4) + l15][(kk << 5) + (lh << 3)];
#pragma unroll
            for (int m = 0; m < 2; ++m)
#pragma unroll
                for (int n = 0; n < 2; ++n)
                    acc[m][n] = __builtin_amdgcn_mfma_f32_16x16x32_bf16(af[m], bfv[n], acc[m][n], 0, 0, 0);
        }
        if (t + 1 < nt) writeS(cur ^ 1);
        __syncthreads();
    }

#pragma unroll
    for (int n = 0; n < 2; ++n) {
        const int ccol = n0 + wc + (n << 4) + l15;
        const float bb = bias_perm[ccol];
        const int u = ccol >> 2;
#pragma unroll
        for (int m = 0; m < 2; ++m) {
#pragma unroll
            for (int j = 0; j < 4; ++j) {
                const int r = m0 + wr + (m << 4) + (lh << 2) + j;
                float v = acc[m][n][j] + bb;
                const int base = lane & ~3;
                float gi = __shfl(v, base, 64);
                float gf = __shfl(v, base | 1, 64);
                float gg = __shfl(v, base | 2, 64);
                float go = __shfl(v, base | 3, 64);
                if ((lane & 3) == 0) {
                    float si = 1.f / (1.f + expf(-gi));
                    float sf = 1.f / (1.f + expf(-gf));
                    float so = 1.f / (1.f + expf(-go));
                    size_t idx = ((size_t)r << 9) + u;
                    float cold = first ? 0.f : cstate[idx];
                    float cv = sf * cold + si * tanhf(gg);
                    cstate[idx] = cv;
                    float hv = so * tanhf(cv);
                    __hip_bfloat16 b = __float2bfloat16(hv);
                    h_out[idx] = *(short*)&b;
                }
            }
        }
    }
}

// img fp32 -> bf16
__global__ __launch_bounds__(256)
void imgcvt_kernel(const float* __restrict__ img, short* __restrict__ out)
{
    size_t i = ((size_t)blockIdx.x * 256 + threadIdx.x) * 8;
    float4 a = *(const float4*)(img + i), b = *(const float4*)(img + i + 4);
    float t[8] = {a.x, a.y, a.z, a.w, b.x, b.y, b.z, b.w};
    *(short8*)(out + i) = cvt8(t);
}

// softmax over 49 per n from 8-way partials, then v_emb[n,h] = sum_k att[k]*img[n,k,h]
__global__ __launch_bounds__(256)
void attn_vemb_kernel(const float* __restrict__ partial, const float* __restrict__ img,
                      const short* __restrict__ imgb, float* __restrict__ v_emb)
{
    __shared__ float satt[49];
    const int n = blockIdx.x;
    const int tid = threadIdx.x;
    if (tid < 64) {
        float v = -1e30f;
        if (tid < 49) {
            const float* pp = partial + ((size_t)n * 49 + tid) * 8;
            v = ((pp[0] + pp[1]) + (pp[2] + pp[3])) + ((pp[4] + pp[5]) + (pp[6] + pp[7]));
        }
        float m = v;
#pragma unroll
        for (int off = 32; off; off >>= 1) m = fmaxf(m, __shfl_xor(m, off, 64));
        float e = (tid < 49) ? expf(v - m) : 0.f;
        float s = e;
#pragma unroll
        for (int off = 32; off; off >>= 1) s += __shfl_xor(s, off, 64);
        if (tid < 49) satt[tid] = e / s;
    }
    __syncthreads();
    float2 s2 = make_float2(0.f, 0.f);
    if (imgb) {
        const unsigned int* ip = (const unsigned int*)(imgb + (size_t)n * 49 * 512);
        for (int k = 0; k < 49; ++k) {
            unsigned int v = ip[k * 256 + tid];
            float a = satt[k];
            s2.x = fmaf(a, bf2f((short)(v & 0xffff)), s2.x);
            s2.y = fmaf(a, bf2f((short)(v >> 16)), s2.y);
        }
    } else {
        const float2* ip = (const float2*)(img + (size_t)n * 49 * 512);
        for (int k = 0; k < 49; ++k) {
            float2 v = ip[k * 256 + tid];
            float a = satt[k];
            s2.x = fmaf(a, v.x, s2.x);
            s2.y = fmaf(a, v.y, s2.y);
        }
    }
    ((float2*)(v_emb + (size_t)n * 512))[tid] = s2;
}

// g0[b,i,j,c] = relu(PQ[b*6+j, c] + PQ[b*6+i, 512+c] + b0[c]) -> bf16
__global__ __launch_bounds__(256)
void g0build_kernel(const float* __restrict__ PQ, const float* __restrict__ b0,
                    short* __restrict__ g0)
{
    int id = blockIdx.x * 256 + threadIdx.x;
    int cc = id & 511;
    int r = id >> 9;
    int j = r % 6;
    int t = r / 6;
    int i = t % 6;
    int b = t / 6;
    float v = PQ[(size_t)(b * 6 + j) * 1024 + cc] + PQ[(size_t)(b * 6 + i) * 1024 + 512 + cc] + b0[cc];
    v = fmaxf(v, 0.f);
    __hip_bfloat16 h = __float2bfloat16(v);
    g0[id] = *(short*)&h;
}

__global__ __launch_bounds__(256)
void gsum_kernel(const short* __restrict__ g, float* __restrict__ out)
{
    int id = blockIdx.x * 256 + threadIdx.x;
    int b = id >> 9, hh = id & 511;
    const short* p = g + (size_t)b * 36 * 512 + hh;
    float s = 0.f;
#pragma unroll
    for (int i = 0; i < 36; ++i) s += bf2f(p[i * 512]);
    out[id] = s;
}

__global__ __launch_bounds__(256)
void l2norm_kernel(const float* __restrict__ in, float* __restrict__ out)
{
    int b = blockIdx.x;
    int tid = threadIdx.x;
    float v0 = in[(size_t)b * 512 + tid];
    float v1 = in[(size_t)b * 512 + 256 + tid];
    float s = v0 * v0 + v1 * v1;
#pragma unroll
    for (int off = 32; off; off >>= 1) s += __shfl_down(s, off, 64);
    __shared__ float ps[4];
    if ((tid & 63) == 0) ps[tid >> 6] = s;
    __syncthreads();
    float tot = ps[0] + ps[1] + ps[2] + ps[3];
    float inv = 1.f / sqrtf(tot);
    out[(size_t)b * 512 + tid] = v0 * inv;
    out[(size_t)b * 512 + 256 + tid] = v1 * inv;
}

extern "C" void kernel_launch(void* const* d_in, const int* in_sizes, int n_in,
                              void* d_out, int out_size, void* d_ws, size_t ws_size,
                              hipStream_t stream)
{
    (void)in_sizes; (void)n_in; (void)out_size;
    const float* img    = (const float*)d_in[0];
    const int*   toks   = (const int*)d_in[1];
    const float* qword  = (const float*)d_in[2];
    const float* Wih_f  = (const float*)d_in[3];
    const float* Whh_f  = (const float*)d_in[4];
    const float* bih_f  = (const float*)d_in[5];
    const float* bhh_f  = (const float*)d_in[6];
    const float* Wih_b  = (const float*)d_in[7];
    const float* Whh_b  = (const float*)d_in[8];
    const float* bih_b  = (const float*)d_in[9];
    const float* bhh_b  = (const float*)d_in[10];
    const float* proj_W = (const float*)d_in[11];
    const float* proj_b = (const float*)d_in[12];
    const float* vatt_vW = (const float*)d_in[13];
    const float* vatt_vb = (const float*)d_in[14];
    const float* vatt_qW = (const float*)d_in[15];
    const float* vatt_qb = (const float*)d_in[16];
    const float* vatt_oW = (const float*)d_in[17];
    const float* qnet_W = (const float*)d_in[19];
    const float* qnet_b = (const float*)d_in[20];
    const float* vnet_W = (const float*)d_in[21];
    const float* vnet_b = (const float*)d_in[22];
    const float* cls_W1 = (const float*)d_in[23];
    const float* cls_b1 = (const float*)d_in[24];
    const float* cls_W2 = (const float*)d_in[25];
    const float* cls_b2 = (const float*)d_in[26];
    const float* g0_W   = (const float*)d_in[27];
    const float* g0_b   = (const float*)d_in[28];
    const float* g1_W   = (const float*)d_in[29];
    const float* g1_b   = (const float*)d_in[30];
    const float* g2_W   = (const float*)d_in[31];
    const float* g2_b   = (const float*)d_in[32];
    const float* g3_W   = (const float*)d_in[33];
    const float* g3_b   = (const float*)d_in[34];
    const float* f0_W   = (const float*)d_in[35];
    const float* f0_b   = (const float*)d_in[36];
    const float* f1_W   = (const float*)d_in[37];
    const float* f1_b   = (const float*)d_in[38];

    float* out_logits = (float*)d_out;                  // [1536,2001]
    float* out_rec    = (float*)d_out + 1536 * 2001;    // [256,512]

    const size_t FB = 786432;  // 1536*512
    float* zone = (float*)d_ws;
    float* gA    = zone;                        // 4718592
    float* gB    = zone + 4718592;              // 4718592
    float* hid1  = zone + 9437184;              // 1572864 (bf16)
    float* PQb   = zone + 11010048;             // 1572864 (P|Q fp32 [1536,1024])
    float* gsumb = zone + 12582912;             // 131072
    float* f0o   = zone + 12713984;             // 131072
    float* rectb = zone + 12845056;             // 131072
    float* p = zone + 12976128;
    auto alloc = [&](size_t nf) { float* q = p; p += nf; return q; };
    float* hP0   = alloc(FB);       // h_f (bf16 in slot)
    float* hP2   = alloc(FB);       // h_b
    float* joint = alloc(FB);       // bf16
    float* partial = alloc(602112); // 75264*8 fp32
    short* WbfF  = (short*)alloc(851968);   // [2048][832] bf16
    short* WbfB  = (short*)alloc(851968);
    float* biasF = alloc(2048);
    float* biasB = alloc(2048);
    const size_t TOPF = 17645568;
    short* wb = (short*)(zone + TOPF);
    short* projbf = wb;
    short* qWbf   = wb + 524288;
    short* vWbf   = wb + 786432;
    short* qnetbf = wb + 1048576;
    short* vnetbf = wb + 1310720;
    short* cls1bf = wb + 1572864;
    short* cls2bf = wb + 2097152;
    short* wpqbf  = wb + 4146176;
    short* g1bf   = wb + 4670464;
    short* g2bf   = wb + 4932608;
    short* g3bf   = wb + 5194752;
    short* f0bf   = wb + 5456896;
    short* f1bf   = wb + 5719040;
    const size_t WEND = TOPF + 2990592;
    const size_t IMGBF = 19267584;
    const size_t EMBPF = 1600000;
    const bool useimgbf = ws_size >= (WEND + IMGBF) * sizeof(float);
    const bool useglds  = ws_size >= (WEND + IMGBF + EMBPF) * sizeof(float);
    short* imgbf = (short*)(zone + WEND);
    short* embp  = (short*)(zone + WEND + IMGBF);
    // LSTM-phase aliases inside gA (gA only used post-LSTM)
    short* hP1 = (short*)gA;
    short* hP3 = (short*)(gA + FB);
    float* cF  = gA + 2 * FB;
    float* cB  = gA + 3 * FB;
    // post-LSTM aliases
    float* q_emb  = PQb;
    float* swq    = hid1;
    float* q_repr = gA;
    float* v_emb  = gA + FB;

    // reg-staged fallback GEMM (fp32 A or ragged N)
    auto gemm = [&](const float* A1, int lda1, int k1, const short* W1, int ldw1,
                    const float* A2, int lda2, int k2, const short* W2, int ldw2,
                    const float* b1, const float* mv, const float* mulp,
                    float* Cp, int ldc, int M, int N, int relu, int abits, int cbf) {
        dim3 g((N + 63) / 64, (M + 63) / 64);
        hipLaunchKernelGGL(mfma_gemm64_kernel, g, dim3(256), 0, stream,
                           A1, lda1, k1, W1, ldw1, A2, lda2, k2, W2, ldw2,
                           b1, mv, mulp, Cp, ldc, M, N, relu, abits, cbf);
    };
    // glds GEMM (bf16 A, tile-aligned)
    auto gemmg = [&](const short* A1, const short* A2, int lda, int k1,
                     const short* W, int ldw, const float* b1, const float* mv,
                     float* Cp, int ldc, int M, int N, int Ktot, int relu, int cbf) {
        dim3 g(N >> 6, M >> 6);
        hipLaunchKernelGGL(mfma_glds64_kernel, g, dim3(256), 0, stream,
                           A1, A2, lda, k1, W, ldw, b1, mv, Cp, ldc, Ktot, relu, cbf);
    };

    const int NR = 1536;
    // ---- one-time weight conversions ----
    hipLaunchKernelGGL(lstm_reorder_kernel, dim3(4096), dim3(256), 0, stream,
                       Wih_f, Whh_f, bih_f, bhh_f, WbfF, biasF);
    hipLaunchKernelGGL(lstm_reorder_kernel, dim3(4096), dim3(256), 0, stream,
                       Wih_b, Whh_b, bih_b, bhh_b, WbfB, biasB);
    hipLaunchKernelGGL(wcvt_kernel, dim3(2921), dim3(256), 0, stream,
                       proj_W, vatt_qW, vatt_vW, qnet_W, vnet_W, cls_W1, cls_W2,
                       g0_W, g1_W, g2_W, g3_W, f0_W, f1_W, wb);
    if (useimgbf)
        hipLaunchKernelGGL(imgcvt_kernel, dim3(18816), dim3(256), 0, stream, img, imgbf);

    // ---- bidirectional LSTM ----
    if (useglds) {
        hipLaunchKernelGGL(embcvt_kernel, dim3(12500), dim3(256), 0, stream, qword, embp);
        hipMemsetAsync(hP0, 0, FB * sizeof(short), stream);
        hipMemsetAsync(hP2, 0, FB * sizeof(short), stream);
        short *fi = (short*)hP0, *fo = hP1, *bi = (short*)hP2, *bo = hP3;
        for (int t = 0; t < 10; ++t) {
            hipLaunchKernelGGL(lstm_step6_kernel, dim3(32, 24, 2), dim3(256), 0, stream,
                               fi, bi, WbfF, WbfB, biasF, biasB, embp, toks, t, 9 - t,
                               (t == 0) ? 1 : 0, fo, bo, cF, cB);
            short* tmp = fi; fi = fo; fo = tmp;
            tmp = bi; bi = bo; bo = tmp;
        }
    } else {
        short *fi = (short*)hP0, *fo = hP1, *bi = (short*)hP2, *bo = hP3;
        for (int t = 0; t < 10; ++t) {
            hipLaunchKernelGGL(lstm_step4_kernel, dim3(32, 24, 2), dim3(256), 0, stream,
                               fi, bi, WbfF, WbfB, biasF, biasB, qword, toks, t, 9 - t,
                               (t == 0) ? 1 : 0, fo, bo, cF, cB);
            short* tmp = fi; fi = fo; fo = tmp;
            tmp = bi; bi = bo; bo = tmp;
        }
    }   // final h_f in hP0, h_b in hP2 (bf16)

    // q_emb(bf16) = [h_f|h_b] @ proj_W^T + proj_b
    gemmg((const short*)hP0, (const short*)hP2, 512, 512, projbf, 1024,
          proj_b, nullptr, q_emb, 512, NR, 512, 1024, 0, 1);
    // swq(fp32) = relu(q_emb @ qW^T + qb) * oW
    gemmg((const short*)q_emb, nullptr, 512, 512, qWbf, 512,
          vatt_qb, vatt_oW, swq, 512, NR, 512, 512, 1, 0);
    // attention logits -> 8-way partials (BM=128 glds + swizzle)
    if (useimgbf) {
        hipLaunchKernelGGL(attn_logits3_kernel, dim3(4704), dim3(256), 0, stream,
                           imgbf, vWbf, vatt_vb, swq, partial);
    } else {
        hipLaunchKernelGGL(HIP_KERNEL_NAME(mfma_gemm_t<128>), dim3(4704), dim3(256), 0, stream,
                           img, 512, 512, vWbf, 512,
                           (const float*)nullptr, 0, 0, (const short*)nullptr, 0,
                           vatt_vb, (const float*)nullptr, swq,
                           partial, 512, 75264, 512, 0, 1, 0, 0);
    }
    hipLaunchKernelGGL(attn_vemb_kernel, dim3(1536), dim3(256), 0, stream,
                       partial, img, useimgbf ? imgbf : (const short*)nullptr, v_emb);
    // joint(bf16) = relu(q_emb@qnet^T+b) * relu(v_emb@vnet^T+b)
    gemmg((const short*)q_emb, nullptr, 512, 512, qnetbf, 512,
          qnet_b, nullptr, q_repr, 512, NR, 512, 512, 1, 0);
    gemm(v_emb, 512, 512, vnetbf, 512, nullptr, 0, 0, nullptr, 0,
         vnet_b, nullptr, q_repr, joint, 512, NR, 512, 1, 0, 1);
    // classifier
    gemmg((const short*)joint, nullptr, 512, 512, cls1bf, 512,
          cls_b1, nullptr, hid1, 1024, NR, 1024, 512, 1, 1);
    gemm(hid1, 1024, 1024, cls2bf, 1024, nullptr, 0, 0, nullptr, 0,
         cls_b2, nullptr, nullptr, out_logits, 2001, NR, 2001, 0, 1, 0);
    // relation network: P|Q in one GEMM, then g-chain (glds128)
    gemmg((const short*)joint, nullptr, 512, 512, wpqbf, 512,
          nullptr, nullptr, PQb, 1024, NR, 1024, 512, 0, 0);
    hipLaunchKernelGGL(g0build_kernel, dim3(18432), dim3(256), 0, stream,
                       PQb, g0_b, (short*)gA);
    hipLaunchKernelGGL(mfma_glds128_kernel, dim3(8, 72), dim3(256), 0, stream,
                       (const short*)gA, 512, g1bf, 512, g1_b, gB, 512, 512, 1, 1);
    hipLaunchKernelGGL(mfma_glds128_kernel, dim3(8, 72), dim3(256), 0, stream,
                       (const short*)gB, 512, g2bf, 512, g2_b, gA, 512, 512, 1, 1);
    hipLaunchKernelGGL(mfma_glds128_kernel, dim3(8, 72), dim3(256), 0, stream,
                       (const short*)gA, 512, g3bf, 512, g3_b, gB, 512, 512, 1, 1);
    hipLaunchKernelGGL(gsum_kernel, dim3(512), dim3(256), 0, stream, (const short*)gB, gsumb);
    gemm(gsumb, 512, 512, f0bf, 512, nullptr, 0, 0, nullptr, 0,
         f0_b, nullptr, nullptr, f0o, 512, 256, 512, 1, 0, 0);
    gemm(f0o, 512, 512, f1bf, 512, nullptr, 0, 0, nullptr, 0,
         f1_b, nullptr, nullptr, rectb, 512, 256, 512, 0, 0, 0);
    hipLaunchKernelGGL(l2norm_kernel, dim3(256), dim3(256), 0, stream, rectb, out_rec);
}